// Round 1
// baseline (1755.013 us; speedup 1.0000x reference)
//
#include <hip/hip_runtime.h>
#include <math.h>

#define F_NODE 32
#define F_EDGE 8
#define HID 128

__device__ __forceinline__ float elu_f(float x) { return x > 0.f ? x : expf(x) - 1.f; }

// ---------------- copy (float4) ----------------
__global__ void copy_f4(const float* __restrict__ in, float* __restrict__ out, int n4) {
    int i = blockIdx.x * blockDim.x + threadIdx.x;
    if (i < n4) ((float4*)out)[i] = ((const float4*)in)[i];
}

// ---------------- conv1 edge message: 32 threads/edge ----------------
__global__ __launch_bounds__(256) void edge1_kernel(
    const float* __restrict__ x, const int* __restrict__ src, const int* __restrict__ dst,
    const float* __restrict__ ea, const float* __restrict__ We, const float* __restrict__ be,
    float* __restrict__ agg, int E)
{
    __shared__ float w_s[F_EDGE * F_NODE];
    __shared__ float be_s[F_NODE];
    int tid = threadIdx.x;
    if (tid < F_EDGE * F_NODE) w_s[tid] = We[tid];
    if (tid < F_NODE) be_s[tid] = be[tid];
    __syncthreads();
    int e = blockIdx.x * 8 + (tid >> 5);
    if (e >= E) return;
    int t = tid & 31;
    int s = src[e], d = dst[e];
    float sum = be_s[t] + x[(size_t)s * F_NODE + t];
#pragma unroll
    for (int k = 0; k < F_EDGE; ++k)
        sum = fmaf(ea[(size_t)e * F_EDGE + k], w_s[k * F_NODE + t], sum);
    sum = fmaxf(sum, 0.f);
    atomicAdd(&agg[(size_t)d * F_NODE + t], sum);
}

// ---------------- conv2 edge message: 128 threads/edge ----------------
__global__ __launch_bounds__(256) void edge2_kernel(
    const float* __restrict__ h, const int* __restrict__ src, const int* __restrict__ dst,
    const float* __restrict__ ea, const float* __restrict__ We, const float* __restrict__ be,
    float* __restrict__ agg, int E)
{
    __shared__ float w_s[F_EDGE * HID];
    __shared__ float be_s[HID];
    int tid = threadIdx.x;
    for (int i = tid; i < F_EDGE * HID; i += 256) w_s[i] = We[i];
    if (tid < HID) be_s[tid] = be[tid];
    __syncthreads();
    int e = blockIdx.x * 2 + (tid >> 7);
    if (e >= E) return;
    int t = tid & 127;
    int s = src[e], d = dst[e];
    float ea_r[F_EDGE];
#pragma unroll
    for (int k = 0; k < F_EDGE; ++k) ea_r[k] = ea[(size_t)e * F_EDGE + k];
    float sum = be_s[t] + h[(size_t)s * HID + t];
#pragma unroll
    for (int k = 0; k < F_EDGE; ++k)
        sum = fmaf(ea_r[k], w_s[k * HID + t], sum);
    sum = fmaxf(sum, 0.f);
    atomicAdd(&agg[(size_t)d * HID + t], sum);
}

// ---------------- fused 2-layer node MLP ----------------
// out = [outer_elu]( elu(in @ Wa + ba) @ Wb + bb ); optional duplicate store.
// 16 rows per block, 256 threads. Weights staged in LDS; inputs transposed in
// LDS ([K][16]) so each thread register-tiles 8 rows: per k -> 1 w read + 2
// float4 broadcast reads for 8 FMAs.
template <int K, bool OUTER_ELU, bool DUP>
__global__ __launch_bounds__(256, 2) void mlp_kernel(
    const float* __restrict__ in, const float* __restrict__ Wa, const float* __restrict__ ba,
    const float* __restrict__ Wb, const float* __restrict__ bb,
    float* __restrict__ out, float* __restrict__ out2, int nrows)
{
    __shared__ float w_s[HID * HID];   // 64 KB
    __shared__ float in_s[K * 16];     // [K][16]
    __shared__ float t1_s[HID * 16];   // [128][16]

    const int tid = threadIdx.x;
    const int row_base = blockIdx.x * 16;

    // stage inputs transposed
    if (K == 32) {
        int k = tid & 31, r = tid >> 5;  // r in 0..7
#pragma unroll
        for (int rr = 0; rr < 2; ++rr) {
            int r2 = r + rr * 8;
            float v = 0.f;
            if (row_base + r2 < nrows) v = in[(size_t)(row_base + r2) * K + k];
            in_s[k * 16 + r2] = v;
        }
    } else {
        int k = tid & 127, r = tid >> 7;  // r in 0..1
#pragma unroll
        for (int rr = 0; rr < 8; ++rr) {
            int r2 = r + rr * 2;
            float v = 0.f;
            if (row_base + r2 < nrows) v = in[(size_t)(row_base + r2) * K + k];
            in_s[k * 16 + r2] = v;
        }
    }
    // stage Wa
    for (int i = tid; i < K * HID; i += 256) w_s[i] = Wa[i];
    __syncthreads();

    const int j = tid & 127;
    const int rb = tid >> 7;  // 0/1 -> rows rb*8 .. rb*8+7

    float acc[8];
    {
        float b = ba[j];
#pragma unroll
        for (int r = 0; r < 8; ++r) acc[r] = b;
    }
#pragma unroll 4
    for (int k = 0; k < K; ++k) {
        float w = w_s[k * HID + j];
        float4 a0 = *(const float4*)&in_s[k * 16 + rb * 8];
        float4 a1 = *(const float4*)&in_s[k * 16 + rb * 8 + 4];
        acc[0] = fmaf(a0.x, w, acc[0]);
        acc[1] = fmaf(a0.y, w, acc[1]);
        acc[2] = fmaf(a0.z, w, acc[2]);
        acc[3] = fmaf(a0.w, w, acc[3]);
        acc[4] = fmaf(a1.x, w, acc[4]);
        acc[5] = fmaf(a1.y, w, acc[5]);
        acc[6] = fmaf(a1.z, w, acc[6]);
        acc[7] = fmaf(a1.w, w, acc[7]);
    }
    {
        float4 v0 = make_float4(elu_f(acc[0]), elu_f(acc[1]), elu_f(acc[2]), elu_f(acc[3]));
        float4 v1 = make_float4(elu_f(acc[4]), elu_f(acc[5]), elu_f(acc[6]), elu_f(acc[7]));
        *(float4*)&t1_s[j * 16 + rb * 8] = v0;
        *(float4*)&t1_s[j * 16 + rb * 8 + 4] = v1;
    }
    __syncthreads();
    // stage Wb (overwrite w_s)
    for (int i = tid; i < HID * HID; i += 256) w_s[i] = Wb[i];
    __syncthreads();

    {
        float b = bb[j];
#pragma unroll
        for (int r = 0; r < 8; ++r) acc[r] = b;
    }
#pragma unroll 4
    for (int k = 0; k < HID; ++k) {
        float w = w_s[k * HID + j];
        float4 a0 = *(const float4*)&t1_s[k * 16 + rb * 8];
        float4 a1 = *(const float4*)&t1_s[k * 16 + rb * 8 + 4];
        acc[0] = fmaf(a0.x, w, acc[0]);
        acc[1] = fmaf(a0.y, w, acc[1]);
        acc[2] = fmaf(a0.z, w, acc[2]);
        acc[3] = fmaf(a0.w, w, acc[3]);
        acc[4] = fmaf(a1.x, w, acc[4]);
        acc[5] = fmaf(a1.y, w, acc[5]);
        acc[6] = fmaf(a1.z, w, acc[6]);
        acc[7] = fmaf(a1.w, w, acc[7]);
    }
#pragma unroll
    for (int r = 0; r < 8; ++r) {
        int row = row_base + rb * 8 + r;
        if (row < nrows) {
            float v = acc[r];
            if (OUTER_ELU) v = elu_f(v);
            out[(size_t)row * HID + j] = v;
            if (DUP) out2[(size_t)row * HID + j] = v;
        }
    }
}

// ---------------- global add pool ----------------
__global__ void pool_kernel(const float* __restrict__ h, const int* __restrict__ batch,
                            float* __restrict__ hg, int total)
{
    int i = blockIdx.x * blockDim.x + threadIdx.x;
    if (i >= total) return;
    int n = i >> 7, f = i & 127;
    atomicAdd(&hg[(size_t)batch[n] * HID + f], h[i]);
}

// ---------------- head: relu(hg@Wl1+bl1)@Wl2+bl2 ----------------
__global__ __launch_bounds__(128) void head_kernel(
    const float* __restrict__ hg, const float* __restrict__ Wl1, const float* __restrict__ bl1,
    const float* __restrict__ Wl2, const float* __restrict__ bl2, float* __restrict__ out)
{
    __shared__ float row_s[HID];
    __shared__ float t_s[HID];
    int g = blockIdx.x;
    int j = threadIdx.x;
    row_s[j] = hg[(size_t)g * HID + j];
    __syncthreads();
    float s = bl1[j];
#pragma unroll 4
    for (int k = 0; k < HID; ++k) s = fmaf(row_s[k], Wl1[k * HID + j], s);
    t_s[j] = fmaxf(s, 0.f);
    __syncthreads();
    if (j < 12) {
        float o = bl2[j];
#pragma unroll 4
        for (int k = 0; k < HID; ++k) o = fmaf(t_s[k], Wl2[k * 12 + j], o);
        out[(size_t)g * 12 + j] = o;
    }
}

extern "C" void kernel_launch(void* const* d_in, const int* in_sizes, int n_in,
                              void* d_out, int out_size, void* d_ws, size_t ws_size,
                              hipStream_t stream)
{
    const float* x    = (const float*)d_in[0];
    const int*   ei   = (const int*)d_in[1];
    const float* ea   = (const float*)d_in[2];
    const int*   batch = (const int*)d_in[3];
    const float* We1 = (const float*)d_in[4];
    const float* be1 = (const float*)d_in[5];
    const float* W1a = (const float*)d_in[6];
    const float* b1a = (const float*)d_in[7];
    const float* W1b = (const float*)d_in[8];
    const float* b1b = (const float*)d_in[9];
    const float* We2 = (const float*)d_in[10];
    const float* be2 = (const float*)d_in[11];
    const float* W2a = (const float*)d_in[12];
    const float* b2a = (const float*)d_in[13];
    const float* W2b = (const float*)d_in[14];
    const float* b2b = (const float*)d_in[15];
    const float* Wl1 = (const float*)d_in[16];
    const float* bl1 = (const float*)d_in[17];
    const float* Wl2 = (const float*)d_in[18];
    const float* bl2 = (const float*)d_in[19];
    float* out = (float*)d_out;

    const int N = in_sizes[0] / F_NODE;
    const int E = in_sizes[1] / 2;
    const int G = out_size / 12;

    const int* srcp = ei;
    const int* dstp = ei + E;

    float* ws   = (float*)d_ws;
    float* agg1 = ws;                               // N*32
    float* h1   = agg1 + (size_t)N * F_NODE;        // N*128
    float* agg2 = h1 + (size_t)N * HID;             // N*128
    float* hg   = agg2 + (size_t)N * HID;           // G*128

    // agg1 = x
    int n4 = (N * F_NODE) / 4;
    hipLaunchKernelGGL(copy_f4, dim3((n4 + 255) / 256), dim3(256), 0, stream, x, agg1, n4);
    // hg = 0 (issued early; independent)
    hipMemsetAsync(hg, 0, (size_t)G * HID * sizeof(float), stream);

    // conv1 edge scatter
    hipLaunchKernelGGL(edge1_kernel, dim3((E + 7) / 8), dim3(256), 0, stream,
                       x, srcp, dstp, ea, We1, be1, agg1, E);
    // conv1 MLP (+elu), duplicate output into agg2 (init for conv2's h + agg)
    hipLaunchKernelGGL((mlp_kernel<F_NODE, true, true>), dim3((N + 15) / 16), dim3(256), 0, stream,
                       agg1, W1a, b1a, W1b, b1b, h1, agg2, N);
    // conv2 edge scatter (gathers h1, accumulates into agg2)
    hipLaunchKernelGGL(edge2_kernel, dim3((E + 1) / 2), dim3(256), 0, stream,
                       h1, srcp, dstp, ea, We2, be2, agg2, E);
    // conv2 MLP (+elu) -> h1 (reuse)
    hipLaunchKernelGGL((mlp_kernel<HID, true, false>), dim3((N + 15) / 16), dim3(256), 0, stream,
                       agg2, W2a, b2a, W2b, b2b, h1, (float*)nullptr, N);
    // global add pool
    hipLaunchKernelGGL(pool_kernel, dim3((N * HID + 255) / 256), dim3(256), 0, stream,
                       h1, batch, hg, N * HID);
    // head
    hipLaunchKernelGGL(head_kernel, dim3(G), dim3(128), 0, stream,
                       hg, Wl1, bl1, Wl2, bl2, out);
}

// Round 2
// 1006.736 us; speedup vs baseline: 1.7433x; 1.7433x over previous
//
#include <hip/hip_runtime.h>
#include <math.h>

#define F_NODE 32
#define F_EDGE 8
#define HID 128

__device__ __forceinline__ float elu_f(float x) { return x > 0.f ? x : expf(x) - 1.f; }

// ================= CSR build =================
__global__ void hist_kernel(const int* __restrict__ dst, int* __restrict__ cnt, int E) {
    int i = blockIdx.x * blockDim.x + threadIdx.x;
    if (i < E) atomicAdd(&cnt[dst[i]], 1);
}

// 256 threads, 4 elems/thread -> 1024 elems/block, exclusive scan
__global__ void scan1_kernel(const int* __restrict__ in, int* __restrict__ out,
                             int* __restrict__ part, int n) {
    __shared__ int s[256];
    int t = threadIdx.x;
    int base = blockIdx.x * 1024 + t * 4;
    int v0 = base + 0 < n ? in[base + 0] : 0;
    int v1 = base + 1 < n ? in[base + 1] : 0;
    int v2 = base + 2 < n ? in[base + 2] : 0;
    int v3 = base + 3 < n ? in[base + 3] : 0;
    int tot = v0 + v1 + v2 + v3;
    s[t] = tot;
    __syncthreads();
    for (int off = 1; off < 256; off <<= 1) {
        int val = (t >= off) ? s[t - off] : 0;
        __syncthreads();
        s[t] += val;
        __syncthreads();
    }
    int pre = s[t] - tot;
    if (base + 0 < n) out[base + 0] = pre;
    if (base + 1 < n) out[base + 1] = pre + v0;
    if (base + 2 < n) out[base + 2] = pre + v0 + v1;
    if (base + 3 < n) out[base + 3] = pre + v0 + v1 + v2;
    if (t == 255) part[blockIdx.x] = s[255];
}

__global__ void scan2_kernel(int* part, int nb) {
    __shared__ int s[256];
    int t = threadIdx.x;
    int v = t < nb ? part[t] : 0;
    s[t] = v;
    __syncthreads();
    for (int off = 1; off < 256; off <<= 1) {
        int val = (t >= off) ? s[t - off] : 0;
        __syncthreads();
        s[t] += val;
        __syncthreads();
    }
    if (t < nb) part[t] = s[t] - v;  // exclusive
}

__global__ void scan3_kernel(int* __restrict__ out, const int* __restrict__ part, int n, int total) {
    int i = blockIdx.x * blockDim.x + threadIdx.x;
    if (i < n) out[i] += part[i >> 10];
    if (i == 0) out[n] = total;
}

// cnt still holds per-node counts; consume it as a reverse cursor.
__global__ void fill_kernel(const int* __restrict__ dst, const int* __restrict__ off,
                            int* __restrict__ cnt, int* __restrict__ eid, int E) {
    int i = blockIdx.x * blockDim.x + threadIdx.x;
    if (i >= E) return;
    int d = dst[i];
    int old = atomicSub(&cnt[d], 1);
    eid[off[d] + old - 1] = i;
}

// ================= conv1 gather-aggregate =================
// one wave per node; lanes: f = lane&31, half = lane>>5 splits the edge list.
__global__ __launch_bounds__(256) void agg1_kernel(
    const float* __restrict__ x, const int* __restrict__ src, const float* __restrict__ ea,
    const float* __restrict__ We, const float* __restrict__ be,
    const int* __restrict__ off, const int* __restrict__ eid,
    float* __restrict__ agg, int N)
{
    int wave = (blockIdx.x * 256 + threadIdx.x) >> 6;
    if (wave >= N) return;
    int lane = threadIdx.x & 63;
    int f = lane & 31, half = lane >> 5;
    float w[F_EDGE];
#pragma unroll
    for (int k = 0; k < F_EDGE; ++k) w[k] = We[k * F_NODE + f];
    float b = be[f];
    int i0 = off[wave], i1 = off[wave + 1];
    float acc = 0.f;
    for (int i = i0 + half; i < i1; i += 2) {
        int e = eid[i];
        int s = src[e];
        float m = b + x[(size_t)s * F_NODE + f];
#pragma unroll
        for (int k = 0; k < F_EDGE; ++k) m = fmaf(ea[(size_t)e * F_EDGE + k], w[k], m);
        acc += fmaxf(m, 0.f);
    }
    acc += __shfl_xor(acc, 32, 64);
    if (half == 0) agg[(size_t)wave * F_NODE + f] = x[(size_t)wave * F_NODE + f] + acc;
}

// ================= conv2 gather-aggregate =================
// one wave per node; 2 features per lane (lane, lane+64).
__global__ __launch_bounds__(256) void agg2_kernel(
    const float* __restrict__ h, const int* __restrict__ src, const float* __restrict__ ea,
    const float* __restrict__ We, const float* __restrict__ be,
    const int* __restrict__ off, const int* __restrict__ eid,
    float* __restrict__ agg, int N)
{
    int wave = (blockIdx.x * 256 + threadIdx.x) >> 6;
    if (wave >= N) return;
    int lane = threadIdx.x & 63;
    float w0[F_EDGE], w1[F_EDGE];
#pragma unroll
    for (int k = 0; k < F_EDGE; ++k) {
        w0[k] = We[k * HID + lane];
        w1[k] = We[k * HID + 64 + lane];
    }
    float b0 = be[lane], b1 = be[64 + lane];
    int i0 = off[wave], i1 = off[wave + 1];
    float acc0 = 0.f, acc1 = 0.f;
    for (int i = i0; i < i1; ++i) {
        int e = eid[i];
        int s = src[e];
        const float* hr = h + (size_t)s * HID;
        float ear[F_EDGE];
#pragma unroll
        for (int k = 0; k < F_EDGE; ++k) ear[k] = ea[(size_t)e * F_EDGE + k];
        float m0 = b0 + hr[lane];
        float m1 = b1 + hr[64 + lane];
#pragma unroll
        for (int k = 0; k < F_EDGE; ++k) {
            m0 = fmaf(ear[k], w0[k], m0);
            m1 = fmaf(ear[k], w1[k], m1);
        }
        acc0 += fmaxf(m0, 0.f);
        acc1 += fmaxf(m1, 0.f);
    }
    agg[(size_t)wave * HID + lane]      = h[(size_t)wave * HID + lane] + acc0;
    agg[(size_t)wave * HID + 64 + lane] = h[(size_t)wave * HID + 64 + lane] + acc1;
}

// ================= fused 2-layer node MLP =================
template <int K, bool OUTER_ELU>
__global__ __launch_bounds__(256, 2) void mlp_kernel(
    const float* __restrict__ in, const float* __restrict__ Wa, const float* __restrict__ ba,
    const float* __restrict__ Wb, const float* __restrict__ bb,
    float* __restrict__ out, int nrows)
{
    __shared__ float w_s[HID * HID];   // 64 KB
    __shared__ float in_s[K * 16];     // [K][16]
    __shared__ float t1_s[HID * 16];   // [128][16]

    const int tid = threadIdx.x;
    const int row_base = blockIdx.x * 16;

    if (K == 32) {
        int k = tid & 31, r = tid >> 5;
#pragma unroll
        for (int rr = 0; rr < 2; ++rr) {
            int r2 = r + rr * 8;
            float v = 0.f;
            if (row_base + r2 < nrows) v = in[(size_t)(row_base + r2) * K + k];
            in_s[k * 16 + r2] = v;
        }
    } else {
        int k = tid & 127, r = tid >> 7;
#pragma unroll
        for (int rr = 0; rr < 8; ++rr) {
            int r2 = r + rr * 2;
            float v = 0.f;
            if (row_base + r2 < nrows) v = in[(size_t)(row_base + r2) * K + k];
            in_s[k * 16 + r2] = v;
        }
    }
    for (int i = tid; i < K * HID; i += 256) w_s[i] = Wa[i];
    __syncthreads();

    const int j = tid & 127;
    const int rb = tid >> 7;

    float acc[8];
    {
        float b = ba[j];
#pragma unroll
        for (int r = 0; r < 8; ++r) acc[r] = b;
    }
#pragma unroll 4
    for (int k = 0; k < K; ++k) {
        float w = w_s[k * HID + j];
        float4 a0 = *(const float4*)&in_s[k * 16 + rb * 8];
        float4 a1 = *(const float4*)&in_s[k * 16 + rb * 8 + 4];
        acc[0] = fmaf(a0.x, w, acc[0]);
        acc[1] = fmaf(a0.y, w, acc[1]);
        acc[2] = fmaf(a0.z, w, acc[2]);
        acc[3] = fmaf(a0.w, w, acc[3]);
        acc[4] = fmaf(a1.x, w, acc[4]);
        acc[5] = fmaf(a1.y, w, acc[5]);
        acc[6] = fmaf(a1.z, w, acc[6]);
        acc[7] = fmaf(a1.w, w, acc[7]);
    }
    {
        float4 v0 = make_float4(elu_f(acc[0]), elu_f(acc[1]), elu_f(acc[2]), elu_f(acc[3]));
        float4 v1 = make_float4(elu_f(acc[4]), elu_f(acc[5]), elu_f(acc[6]), elu_f(acc[7]));
        *(float4*)&t1_s[j * 16 + rb * 8] = v0;
        *(float4*)&t1_s[j * 16 + rb * 8 + 4] = v1;
    }
    __syncthreads();
    for (int i = tid; i < HID * HID; i += 256) w_s[i] = Wb[i];
    __syncthreads();

    {
        float b = bb[j];
#pragma unroll
        for (int r = 0; r < 8; ++r) acc[r] = b;
    }
#pragma unroll 4
    for (int k = 0; k < HID; ++k) {
        float w = w_s[k * HID + j];
        float4 a0 = *(const float4*)&t1_s[k * 16 + rb * 8];
        float4 a1 = *(const float4*)&t1_s[k * 16 + rb * 8 + 4];
        acc[0] = fmaf(a0.x, w, acc[0]);
        acc[1] = fmaf(a0.y, w, acc[1]);
        acc[2] = fmaf(a0.z, w, acc[2]);
        acc[3] = fmaf(a0.w, w, acc[3]);
        acc[4] = fmaf(a1.x, w, acc[4]);
        acc[5] = fmaf(a1.y, w, acc[5]);
        acc[6] = fmaf(a1.z, w, acc[6]);
        acc[7] = fmaf(a1.w, w, acc[7]);
    }
#pragma unroll
    for (int r = 0; r < 8; ++r) {
        int row = row_base + rb * 8 + r;
        if (row < nrows) {
            float v = acc[r];
            if (OUTER_ELU) v = elu_f(v);
            out[(size_t)row * HID + j] = v;
        }
    }
}

// ================= global add pool =================
__global__ void pool_kernel(const float* __restrict__ h, const int* __restrict__ batch,
                            float* __restrict__ hg, int total)
{
    int i = blockIdx.x * blockDim.x + threadIdx.x;
    if (i >= total) return;
    int n = i >> 7, f = i & 127;
    atomicAdd(&hg[(size_t)batch[n] * HID + f], h[i]);
}

// ================= head =================
__global__ __launch_bounds__(128) void head_kernel(
    const float* __restrict__ hg, const float* __restrict__ Wl1, const float* __restrict__ bl1,
    const float* __restrict__ Wl2, const float* __restrict__ bl2, float* __restrict__ out)
{
    __shared__ float row_s[HID];
    __shared__ float t_s[HID];
    int g = blockIdx.x;
    int j = threadIdx.x;
    row_s[j] = hg[(size_t)g * HID + j];
    __syncthreads();
    float s = bl1[j];
#pragma unroll 4
    for (int k = 0; k < HID; ++k) s = fmaf(row_s[k], Wl1[k * HID + j], s);
    t_s[j] = fmaxf(s, 0.f);
    __syncthreads();
    if (j < 12) {
        float o = bl2[j];
#pragma unroll 4
        for (int k = 0; k < HID; ++k) o = fmaf(t_s[k], Wl2[k * 12 + j], o);
        out[(size_t)g * 12 + j] = o;
    }
}

extern "C" void kernel_launch(void* const* d_in, const int* in_sizes, int n_in,
                              void* d_out, int out_size, void* d_ws, size_t ws_size,
                              hipStream_t stream)
{
    const float* x    = (const float*)d_in[0];
    const int*   ei   = (const int*)d_in[1];
    const float* ea   = (const float*)d_in[2];
    const int*   batch = (const int*)d_in[3];
    const float* We1 = (const float*)d_in[4];
    const float* be1 = (const float*)d_in[5];
    const float* W1a = (const float*)d_in[6];
    const float* b1a = (const float*)d_in[7];
    const float* W1b = (const float*)d_in[8];
    const float* b1b = (const float*)d_in[9];
    const float* We2 = (const float*)d_in[10];
    const float* be2 = (const float*)d_in[11];
    const float* W2a = (const float*)d_in[12];
    const float* b2a = (const float*)d_in[13];
    const float* W2b = (const float*)d_in[14];
    const float* b2b = (const float*)d_in[15];
    const float* Wl1 = (const float*)d_in[16];
    const float* bl1 = (const float*)d_in[17];
    const float* Wl2 = (const float*)d_in[18];
    const float* bl2 = (const float*)d_in[19];
    float* out = (float*)d_out;

    const int N = in_sizes[0] / F_NODE;
    const int E = in_sizes[1] / 2;
    const int G = out_size / 12;

    const int* srcp = ei;
    const int* dstp = ei + E;

    // ---- workspace layout ----
    char* wsb = (char*)d_ws;
    int* cnt  = (int*)wsb;                    wsb += (size_t)N * sizeof(int);
    int* off  = (int*)wsb;                    wsb += (size_t)(N + 1) * sizeof(int);
    int* part = (int*)wsb;                    wsb += 256 * sizeof(int);
    int* eid  = (int*)wsb;                    wsb += (size_t)E * sizeof(int);
    float* agg1 = (float*)wsb;                wsb += (size_t)N * F_NODE * sizeof(float);
    float* h1   = (float*)wsb;                wsb += (size_t)N * HID * sizeof(float);
    float* agg2 = (float*)wsb;                wsb += (size_t)N * HID * sizeof(float);
    float* hg   = (float*)wsb;                wsb += (size_t)G * HID * sizeof(float);

    // ---- CSR build ----
    hipMemsetAsync(cnt, 0, (size_t)N * sizeof(int), stream);
    hipMemsetAsync(hg, 0, (size_t)G * HID * sizeof(float), stream);
    hipLaunchKernelGGL(hist_kernel, dim3((E + 255) / 256), dim3(256), 0, stream, dstp, cnt, E);
    int nscan = (N + 1023) / 1024;
    hipLaunchKernelGGL(scan1_kernel, dim3(nscan), dim3(256), 0, stream, cnt, off, part, N);
    hipLaunchKernelGGL(scan2_kernel, dim3(1), dim3(256), 0, stream, part, nscan);
    hipLaunchKernelGGL(scan3_kernel, dim3((N + 255) / 256), dim3(256), 0, stream, off, part, N, E);
    hipLaunchKernelGGL(fill_kernel, dim3((E + 255) / 256), dim3(256), 0, stream, dstp, off, cnt, eid, E);

    // ---- conv1 ----
    hipLaunchKernelGGL(agg1_kernel, dim3((N + 3) / 4), dim3(256), 0, stream,
                       x, srcp, ea, We1, be1, off, eid, agg1, N);
    hipLaunchKernelGGL((mlp_kernel<F_NODE, true>), dim3((N + 15) / 16), dim3(256), 0, stream,
                       agg1, W1a, b1a, W1b, b1b, h1, N);

    // ---- conv2 ----
    hipLaunchKernelGGL(agg2_kernel, dim3((N + 3) / 4), dim3(256), 0, stream,
                       h1, srcp, ea, We2, be2, off, eid, agg2, N);
    hipLaunchKernelGGL((mlp_kernel<HID, true>), dim3((N + 15) / 16), dim3(256), 0, stream,
                       agg2, W2a, b2a, W2b, b2b, h1, N);

    // ---- pool + head ----
    hipLaunchKernelGGL(pool_kernel, dim3((N * HID + 255) / 256), dim3(256), 0, stream,
                       h1, batch, hg, N * HID);
    hipLaunchKernelGGL(head_kernel, dim3(G), dim3(128), 0, stream,
                       hg, Wl1, bl1, Wl2, bl2, out);
}

// Round 3
// 703.479 us; speedup vs baseline: 2.4948x; 1.4311x over previous
//
#include <hip/hip_runtime.h>
#include <math.h>

#define F_NODE 32
#define F_EDGE 8
#define HID 128

__device__ __forceinline__ float elu_f(float x) { return x > 0.f ? x : expf(x) - 1.f; }

// ================= CSR build =================
__global__ void hist_kernel(const int* __restrict__ dst, int* __restrict__ cnt, int E) {
    int i = blockIdx.x * blockDim.x + threadIdx.x;
    if (i < E) atomicAdd(&cnt[dst[i]], 1);
}

// 256 threads, 4 elems/thread -> 1024 elems/block, exclusive scan
__global__ void scan1_kernel(const int* __restrict__ in, int* __restrict__ out,
                             int* __restrict__ part, int n) {
    __shared__ int s[256];
    int t = threadIdx.x;
    int base = blockIdx.x * 1024 + t * 4;
    int v0 = base + 0 < n ? in[base + 0] : 0;
    int v1 = base + 1 < n ? in[base + 1] : 0;
    int v2 = base + 2 < n ? in[base + 2] : 0;
    int v3 = base + 3 < n ? in[base + 3] : 0;
    int tot = v0 + v1 + v2 + v3;
    s[t] = tot;
    __syncthreads();
    for (int off = 1; off < 256; off <<= 1) {
        int val = (t >= off) ? s[t - off] : 0;
        __syncthreads();
        s[t] += val;
        __syncthreads();
    }
    int pre = s[t] - tot;
    if (base + 0 < n) out[base + 0] = pre;
    if (base + 1 < n) out[base + 1] = pre + v0;
    if (base + 2 < n) out[base + 2] = pre + v0 + v1;
    if (base + 3 < n) out[base + 3] = pre + v0 + v1 + v2;
    if (t == 255) part[blockIdx.x] = s[255];
}

__global__ void scan2_kernel(int* part, int nb) {
    __shared__ int s[256];
    int t = threadIdx.x;
    int v = t < nb ? part[t] : 0;
    s[t] = v;
    __syncthreads();
    for (int off = 1; off < 256; off <<= 1) {
        int val = (t >= off) ? s[t - off] : 0;
        __syncthreads();
        s[t] += val;
        __syncthreads();
    }
    if (t < nb) part[t] = s[t] - v;  // exclusive
}

__global__ void scan3_kernel(int* __restrict__ out, const int* __restrict__ part, int n, int total) {
    int i = blockIdx.x * blockDim.x + threadIdx.x;
    if (i < n) out[i] += part[i >> 10];
    if (i == 0) out[n] = total;
}

// cnt holds per-node counts; consume as reverse cursor. pair = (edge_id, src)
__global__ void fill_kernel(const int* __restrict__ dst, const int* __restrict__ src,
                            const int* __restrict__ off, int* __restrict__ cnt,
                            int2* __restrict__ pair, int E) {
    int i = blockIdx.x * blockDim.x + threadIdx.x;
    if (i >= E) return;
    int d = dst[i];
    int old = atomicSub(&cnt[d], 1);
    pair[off[d] + old - 1] = make_int2(i, src[i]);
}

// ================= conv1 gather-aggregate =================
// one wave per node; f = lane&31 (feature), half = lane>>5 splits edges; unroll 2.
__global__ __launch_bounds__(256) void agg1_kernel(
    const float* __restrict__ x, const float* __restrict__ ea,
    const float* __restrict__ We, const float* __restrict__ be,
    const int* __restrict__ off, const int2* __restrict__ pair,
    float* __restrict__ agg, int N)
{
    int wave = (blockIdx.x * 256 + threadIdx.x) >> 6;
    if (wave >= N) return;
    int lane = threadIdx.x & 63;
    int f = lane & 31, half = lane >> 5;
    float w[F_EDGE];
#pragma unroll
    for (int k = 0; k < F_EDGE; ++k) w[k] = We[k * F_NODE + f];
    float b = be[f];
    int i0 = off[wave], i1 = off[wave + 1];
    float acc = 0.f;
    int i = i0 + half;
    for (; i + 2 < i1; i += 4) {
        int2 p0 = pair[i], p1 = pair[i + 2];
        const float* e0 = ea + (size_t)p0.x * F_EDGE;
        const float* e1 = ea + (size_t)p1.x * F_EDGE;
        float m = b + x[(size_t)p0.y * F_NODE + f];
        float n = b + x[(size_t)p1.y * F_NODE + f];
#pragma unroll
        for (int k = 0; k < F_EDGE; ++k) {
            m = fmaf(e0[k], w[k], m);
            n = fmaf(e1[k], w[k], n);
        }
        acc += fmaxf(m, 0.f) + fmaxf(n, 0.f);
    }
    for (; i < i1; i += 2) {
        int2 p0 = pair[i];
        const float* e0 = ea + (size_t)p0.x * F_EDGE;
        float m = b + x[(size_t)p0.y * F_NODE + f];
#pragma unroll
        for (int k = 0; k < F_EDGE; ++k) m = fmaf(e0[k], w[k], m);
        acc += fmaxf(m, 0.f);
    }
    acc += __shfl_xor(acc, 32, 64);
    if (half == 0) agg[(size_t)wave * F_NODE + f] = x[(size_t)wave * F_NODE + f] + acc;
}

// ================= conv2 gather-aggregate =================
// one wave per node; 2 features per lane; unroll 2 (independent chains).
__global__ __launch_bounds__(256) void agg2_kernel(
    const float* __restrict__ h, const float* __restrict__ ea,
    const float* __restrict__ We, const float* __restrict__ be,
    const int* __restrict__ off, const int2* __restrict__ pair,
    float* __restrict__ agg, int N)
{
    int wave = (blockIdx.x * 256 + threadIdx.x) >> 6;
    if (wave >= N) return;
    int lane = threadIdx.x & 63;
    float w0[F_EDGE], w1[F_EDGE];
#pragma unroll
    for (int k = 0; k < F_EDGE; ++k) {
        w0[k] = We[k * HID + lane];
        w1[k] = We[k * HID + 64 + lane];
    }
    float b0 = be[lane], b1 = be[64 + lane];
    int i0 = off[wave], i1 = off[wave + 1];
    float acc0 = 0.f, acc1 = 0.f;
    int i = i0;
    for (; i + 1 < i1; i += 2) {
        int2 p0 = pair[i], p1 = pair[i + 1];
        const float* h0 = h + (size_t)p0.y * HID;
        const float* h1r = h + (size_t)p1.y * HID;
        const float* e0 = ea + (size_t)p0.x * F_EDGE;
        const float* e1 = ea + (size_t)p1.x * F_EDGE;
        float m0 = b0 + h0[lane], m1 = b1 + h0[64 + lane];
        float n0 = b0 + h1r[lane], n1 = b1 + h1r[64 + lane];
#pragma unroll
        for (int k = 0; k < F_EDGE; ++k) {
            float c0 = e0[k], c1 = e1[k];
            m0 = fmaf(c0, w0[k], m0);
            m1 = fmaf(c0, w1[k], m1);
            n0 = fmaf(c1, w0[k], n0);
            n1 = fmaf(c1, w1[k], n1);
        }
        acc0 += fmaxf(m0, 0.f) + fmaxf(n0, 0.f);
        acc1 += fmaxf(m1, 0.f) + fmaxf(n1, 0.f);
    }
    if (i < i1) {
        int2 p0 = pair[i];
        const float* h0 = h + (size_t)p0.y * HID;
        const float* e0 = ea + (size_t)p0.x * F_EDGE;
        float m0 = b0 + h0[lane], m1 = b1 + h0[64 + lane];
#pragma unroll
        for (int k = 0; k < F_EDGE; ++k) {
            float c0 = e0[k];
            m0 = fmaf(c0, w0[k], m0);
            m1 = fmaf(c0, w1[k], m1);
        }
        acc0 += fmaxf(m0, 0.f);
        acc1 += fmaxf(m1, 0.f);
    }
    agg[(size_t)wave * HID + lane]      = h[(size_t)wave * HID + lane] + acc0;
    agg[(size_t)wave * HID + 64 + lane] = h[(size_t)wave * HID + 64 + lane] + acc1;
}

// ================= fused 2-layer node MLP =================
// 16 rows/block, 128 threads. Activations row-major in LDS (broadcast b64
// reads); weights streamed from L2 as coalesced float2. Thread = 8 rows x 2
// adjacent cols -> 32 FMA per k-pair vs 8 LDS-b64.
template <int K, bool OUTER_ELU>
__global__ __launch_bounds__(128) void mlp_kernel(
    const float* __restrict__ in, const float* __restrict__ Wa, const float* __restrict__ ba,
    const float* __restrict__ Wb, const float* __restrict__ bb,
    float* __restrict__ out, int nrows)
{
    constexpr int SA = K + 4;     // row stride (multiple of 4 -> float4-aligned)
    constexpr int ST = HID + 4;
    __shared__ float in_s[16 * SA];
    __shared__ float t1_s[16 * ST];

    const int tid = threadIdx.x;
    const int row_base = blockIdx.x * 16;

    // stage input rows (row-major): wave-local rows
    {
        const int r = tid >> 3;      // 0..15
        const int q0 = tid & 7;
        constexpr int QUADS = K / 4;
#pragma unroll
        for (int q = q0; q < QUADS; q += 8) {
            float4 v = *(const float4*)&in[(size_t)(row_base + r) * K + q * 4];
            *(float4*)&in_s[r * SA + q * 4] = v;
        }
    }
    __syncthreads();

    const int jp = tid & 63;
    const int rb = tid >> 6;       // 0/1 -> rows rb*8..rb*8+7
    const int j0 = 2 * jp;

    float acc0[8], acc1[8];
    {
        float2 bv = *(const float2*)&ba[j0];
#pragma unroll
        for (int r = 0; r < 8; ++r) { acc0[r] = bv.x; acc1[r] = bv.y; }
    }
#pragma unroll 4
    for (int k = 0; k < K; k += 2) {
        float2 wk0 = *(const float2*)&Wa[(size_t)k * HID + j0];
        float2 wk1 = *(const float2*)&Wa[(size_t)(k + 1) * HID + j0];
#pragma unroll
        for (int r = 0; r < 8; ++r) {
            float2 a = *(const float2*)&in_s[(rb * 8 + r) * SA + k];
            acc0[r] = fmaf(a.x, wk0.x, acc0[r]);
            acc0[r] = fmaf(a.y, wk1.x, acc0[r]);
            acc1[r] = fmaf(a.x, wk0.y, acc1[r]);
            acc1[r] = fmaf(a.y, wk1.y, acc1[r]);
        }
    }
#pragma unroll
    for (int r = 0; r < 8; ++r) {
        float2 v = make_float2(elu_f(acc0[r]), elu_f(acc1[r]));
        *(float2*)&t1_s[(rb * 8 + r) * ST + j0] = v;
    }
    __syncthreads();

    {
        float2 bv = *(const float2*)&bb[j0];
#pragma unroll
        for (int r = 0; r < 8; ++r) { acc0[r] = bv.x; acc1[r] = bv.y; }
    }
#pragma unroll 4
    for (int k = 0; k < HID; k += 2) {
        float2 wk0 = *(const float2*)&Wb[(size_t)k * HID + j0];
        float2 wk1 = *(const float2*)&Wb[(size_t)(k + 1) * HID + j0];
#pragma unroll
        for (int r = 0; r < 8; ++r) {
            float2 a = *(const float2*)&t1_s[(rb * 8 + r) * ST + k];
            acc0[r] = fmaf(a.x, wk0.x, acc0[r]);
            acc0[r] = fmaf(a.y, wk1.x, acc0[r]);
            acc1[r] = fmaf(a.x, wk0.y, acc1[r]);
            acc1[r] = fmaf(a.y, wk1.y, acc1[r]);
        }
    }
#pragma unroll
    for (int r = 0; r < 8; ++r) {
        int row = row_base + rb * 8 + r;
        if (row < nrows) {
            float2 v;
            v.x = OUTER_ELU ? elu_f(acc0[r]) : acc0[r];
            v.y = OUTER_ELU ? elu_f(acc1[r]) : acc1[r];
            *(float2*)&out[(size_t)row * HID + j0] = v;
        }
    }
}

// ================= global add pool (run-length, batch sorted) =================
__global__ __launch_bounds__(128) void pool_kernel(
    const float* __restrict__ h, const int* __restrict__ batch,
    float* __restrict__ hg, int N)
{
    int base = blockIdx.x * 64;
    if (base >= N) return;
    int j = threadIdx.x;
    int end = base + 64 < N ? base + 64 : N;
    int cur = batch[base];
    float acc = 0.f;
    for (int n = base; n < end; ++n) {
        int b = batch[n];
        if (b != cur) {
            atomicAdd(&hg[(size_t)cur * HID + j], acc);
            acc = 0.f;
            cur = b;
        }
        acc += h[(size_t)n * HID + j];
    }
    atomicAdd(&hg[(size_t)cur * HID + j], acc);
}

// ================= head =================
__global__ __launch_bounds__(128) void head_kernel(
    const float* __restrict__ hg, const float* __restrict__ Wl1, const float* __restrict__ bl1,
    const float* __restrict__ Wl2, const float* __restrict__ bl2, float* __restrict__ out)
{
    __shared__ float row_s[HID];
    __shared__ float t_s[HID];
    int g = blockIdx.x;
    int j = threadIdx.x;
    row_s[j] = hg[(size_t)g * HID + j];
    __syncthreads();
    float s = bl1[j];
#pragma unroll 4
    for (int k = 0; k < HID; ++k) s = fmaf(row_s[k], Wl1[k * HID + j], s);
    t_s[j] = fmaxf(s, 0.f);
    __syncthreads();
    if (j < 12) {
        float o = bl2[j];
#pragma unroll 4
        for (int k = 0; k < HID; ++k) o = fmaf(t_s[k], Wl2[k * 12 + j], o);
        out[(size_t)g * 12 + j] = o;
    }
}

extern "C" void kernel_launch(void* const* d_in, const int* in_sizes, int n_in,
                              void* d_out, int out_size, void* d_ws, size_t ws_size,
                              hipStream_t stream)
{
    const float* x    = (const float*)d_in[0];
    const int*   ei   = (const int*)d_in[1];
    const float* ea   = (const float*)d_in[2];
    const int*   batch = (const int*)d_in[3];
    const float* We1 = (const float*)d_in[4];
    const float* be1 = (const float*)d_in[5];
    const float* W1a = (const float*)d_in[6];
    const float* b1a = (const float*)d_in[7];
    const float* W1b = (const float*)d_in[8];
    const float* b1b = (const float*)d_in[9];
    const float* We2 = (const float*)d_in[10];
    const float* be2 = (const float*)d_in[11];
    const float* W2a = (const float*)d_in[12];
    const float* b2a = (const float*)d_in[13];
    const float* W2b = (const float*)d_in[14];
    const float* b2b = (const float*)d_in[15];
    const float* Wl1 = (const float*)d_in[16];
    const float* bl1 = (const float*)d_in[17];
    const float* Wl2 = (const float*)d_in[18];
    const float* bl2 = (const float*)d_in[19];
    float* out = (float*)d_out;

    const int N = in_sizes[0] / F_NODE;
    const int E = in_sizes[1] / 2;
    const int G = out_size / 12;

    const int* srcp = ei;
    const int* dstp = ei + E;

    // ---- workspace layout ----
    char* wsb = (char*)d_ws;
    int* cnt  = (int*)wsb;                    wsb += (size_t)N * sizeof(int);
    int* off  = (int*)wsb;                    wsb += (size_t)(N + 1) * sizeof(int);
    int* part = (int*)wsb;                    wsb += 256 * sizeof(int);
    int2* pair = (int2*)wsb;                  wsb += (size_t)E * sizeof(int2);
    float* agg1 = (float*)wsb;                wsb += (size_t)N * F_NODE * sizeof(float);
    float* h1   = (float*)wsb;                wsb += (size_t)N * HID * sizeof(float);
    float* agg2 = (float*)wsb;                wsb += (size_t)N * HID * sizeof(float);
    float* hg   = (float*)wsb;                wsb += (size_t)G * HID * sizeof(float);

    // ---- CSR build ----
    hipMemsetAsync(cnt, 0, (size_t)N * sizeof(int), stream);
    hipMemsetAsync(hg, 0, (size_t)G * HID * sizeof(float), stream);
    hipLaunchKernelGGL(hist_kernel, dim3((E + 255) / 256), dim3(256), 0, stream, dstp, cnt, E);
    int nscan = (N + 1023) / 1024;
    hipLaunchKernelGGL(scan1_kernel, dim3(nscan), dim3(256), 0, stream, cnt, off, part, N);
    hipLaunchKernelGGL(scan2_kernel, dim3(1), dim3(256), 0, stream, part, nscan);
    hipLaunchKernelGGL(scan3_kernel, dim3((N + 255) / 256), dim3(256), 0, stream, off, part, N, E);
    hipLaunchKernelGGL(fill_kernel, dim3((E + 255) / 256), dim3(256), 0, stream,
                       dstp, srcp, off, cnt, pair, E);

    // ---- conv1 ----
    hipLaunchKernelGGL(agg1_kernel, dim3((N + 3) / 4), dim3(256), 0, stream,
                       x, ea, We1, be1, off, pair, agg1, N);
    hipLaunchKernelGGL((mlp_kernel<F_NODE, true>), dim3((N + 15) / 16), dim3(128), 0, stream,
                       agg1, W1a, b1a, W1b, b1b, h1, N);

    // ---- conv2 ----
    hipLaunchKernelGGL(agg2_kernel, dim3((N + 3) / 4), dim3(256), 0, stream,
                       h1, ea, We2, be2, off, pair, agg2, N);
    hipLaunchKernelGGL((mlp_kernel<HID, true>), dim3((N + 15) / 16), dim3(128), 0, stream,
                       agg2, W2a, b2a, W2b, b2b, h1, N);

    // ---- pool + head ----
    hipLaunchKernelGGL(pool_kernel, dim3((N + 63) / 64), dim3(128), 0, stream,
                       h1, batch, hg, N);
    hipLaunchKernelGGL(head_kernel, dim3(G), dim3(128), 0, stream,
                       hg, Wl1, bl1, Wl2, bl2, out);
}

// Round 4
// 673.059 us; speedup vs baseline: 2.6075x; 1.0452x over previous
//
#include <hip/hip_runtime.h>
#include <math.h>

#define F_NODE 32
#define F_EDGE 8
#define HID 128

__device__ __forceinline__ float elu_f(float x) { return x > 0.f ? x : expf(x) - 1.f; }

// ---- bf16 pack/unpack helpers ----
__device__ __forceinline__ unsigned bf16rne(float f) {
    unsigned u = __float_as_uint(f);
    return (u + 0x7FFFu + ((u >> 16) & 1u)) >> 16;
}
__device__ __forceinline__ unsigned pack2(float lo, float hi) {
    return bf16rne(lo) | (bf16rne(hi) << 16);
}
__device__ __forceinline__ float bflo(unsigned u) { return __uint_as_float(u << 16); }
__device__ __forceinline__ float bfhi(unsigned u) { return __uint_as_float(u & 0xFFFF0000u); }

// ================= cast: x, ea -> packed bf16 tables =================
__global__ void cast_kernel(const float* __restrict__ x, const float* __restrict__ ea,
                            unsigned* __restrict__ xb, unsigned* __restrict__ eab,
                            int nx, int ne) {
    int i = blockIdx.x * 256 + threadIdx.x;
    if (i < nx) {
        float2 v = ((const float2*)x)[i];
        xb[i] = pack2(v.x, v.y);
    }
    int j = i - nx;
    if (j >= 0 && j < ne) {
        float2 v = ((const float2*)ea)[j];
        eab[j] = pack2(v.x, v.y);
    }
}

// ================= CSR build =================
__global__ void hist_kernel(const int* __restrict__ dst, int* __restrict__ cnt, int E) {
    int i = blockIdx.x * blockDim.x + threadIdx.x;
    if (i < E) atomicAdd(&cnt[dst[i]], 1);
}

__global__ void scan1_kernel(const int* __restrict__ in, int* __restrict__ out,
                             int* __restrict__ part, int n) {
    __shared__ int s[256];
    int t = threadIdx.x;
    int base = blockIdx.x * 1024 + t * 4;
    int v0 = base + 0 < n ? in[base + 0] : 0;
    int v1 = base + 1 < n ? in[base + 1] : 0;
    int v2 = base + 2 < n ? in[base + 2] : 0;
    int v3 = base + 3 < n ? in[base + 3] : 0;
    int tot = v0 + v1 + v2 + v3;
    s[t] = tot;
    __syncthreads();
    for (int off = 1; off < 256; off <<= 1) {
        int val = (t >= off) ? s[t - off] : 0;
        __syncthreads();
        s[t] += val;
        __syncthreads();
    }
    int pre = s[t] - tot;
    if (base + 0 < n) out[base + 0] = pre;
    if (base + 1 < n) out[base + 1] = pre + v0;
    if (base + 2 < n) out[base + 2] = pre + v0 + v1;
    if (base + 3 < n) out[base + 3] = pre + v0 + v1 + v2;
    if (t == 255) part[blockIdx.x] = s[255];
}

__global__ void scan2_kernel(int* part, int nb) {
    __shared__ int s[256];
    int t = threadIdx.x;
    int v = t < nb ? part[t] : 0;
    s[t] = v;
    __syncthreads();
    for (int off = 1; off < 256; off <<= 1) {
        int val = (t >= off) ? s[t - off] : 0;
        __syncthreads();
        s[t] += val;
        __syncthreads();
    }
    if (t < nb) part[t] = s[t] - v;  // exclusive
}

__global__ void scan3_kernel(int* __restrict__ out, const int* __restrict__ part, int n, int total) {
    int i = blockIdx.x * blockDim.x + threadIdx.x;
    if (i < n) out[i] += part[i >> 10];
    if (i == 0) out[n] = total;
}

__global__ void fill_kernel(const int* __restrict__ dst, const int* __restrict__ src,
                            const int* __restrict__ off, int* __restrict__ cnt,
                            int2* __restrict__ pair, int E) {
    int i = blockIdx.x * blockDim.x + threadIdx.x;
    if (i >= E) return;
    int d = dst[i];
    int old = atomicSub(&cnt[d], 1);
    pair[off[d] + old - 1] = make_int2(i, src[i]);
}

// ================= conv1 gather-aggregate (bf16 gathers) =================
// one wave per node; lane = fp (0..15 feature pair) + eg (0..3 edge group)
__global__ __launch_bounds__(256) void agg1_kernel(
    const float* __restrict__ x, const unsigned* __restrict__ xb,
    const uint4* __restrict__ eab,
    const float* __restrict__ We, const float* __restrict__ be,
    const int* __restrict__ off, const int2* __restrict__ pair,
    float* __restrict__ agg, int N)
{
    int wave = (blockIdx.x * 256 + threadIdx.x) >> 6;
    if (wave >= N) return;
    int lane = threadIdx.x & 63;
    int fp = lane & 15, eg = lane >> 4;
    int j0 = fp * 2;
    float w0[F_EDGE], w1[F_EDGE];
#pragma unroll
    for (int k = 0; k < F_EDGE; ++k) {
        w0[k] = We[k * F_NODE + j0];
        w1[k] = We[k * F_NODE + j0 + 1];
    }
    float b0 = be[j0], b1 = be[j0 + 1];
    int i0 = off[wave], i1 = off[wave + 1];
    float acc0 = 0.f, acc1 = 0.f;
    for (int i = i0; i < i1; i += 4) {
        int ii = i + eg;
        if (ii < i1) {
            int2 p = pair[ii];
            uint4 e = eab[p.x];
            unsigned u = xb[(size_t)p.y * 16 + fp];
            float m0 = b0 + bflo(u), m1 = b1 + bfhi(u);
            float c[8] = { bflo(e.x), bfhi(e.x), bflo(e.y), bfhi(e.y),
                           bflo(e.z), bfhi(e.z), bflo(e.w), bfhi(e.w) };
#pragma unroll
            for (int k = 0; k < F_EDGE; ++k) {
                m0 = fmaf(c[k], w0[k], m0);
                m1 = fmaf(c[k], w1[k], m1);
            }
            acc0 += fmaxf(m0, 0.f);
            acc1 += fmaxf(m1, 0.f);
        }
    }
    acc0 += __shfl_xor(acc0, 16, 64);
    acc0 += __shfl_xor(acc0, 32, 64);
    acc1 += __shfl_xor(acc1, 16, 64);
    acc1 += __shfl_xor(acc1, 32, 64);
    if (eg == 0) {
        float2 xo = *(const float2*)&x[(size_t)wave * F_NODE + j0];
        *(float2*)&agg[(size_t)wave * F_NODE + j0] = make_float2(xo.x + acc0, xo.y + acc1);
    }
}

// ================= conv2 gather-aggregate (bf16 gathers) =================
// one wave per node; lane owns adjacent feature pair j0 = 2*lane; unroll 2.
__global__ __launch_bounds__(256) void agg2_kernel(
    const float* __restrict__ h, const unsigned* __restrict__ hb,
    const uint4* __restrict__ eab,
    const float* __restrict__ We, const float* __restrict__ be,
    const int* __restrict__ off, const int2* __restrict__ pair,
    float* __restrict__ agg, int N)
{
    int wave = (blockIdx.x * 256 + threadIdx.x) >> 6;
    if (wave >= N) return;
    int lane = threadIdx.x & 63;
    int j0 = lane * 2;
    float w0[F_EDGE], w1[F_EDGE];
#pragma unroll
    for (int k = 0; k < F_EDGE; ++k) {
        w0[k] = We[k * HID + j0];
        w1[k] = We[k * HID + j0 + 1];
    }
    float b0 = be[j0], b1 = be[j0 + 1];
    int i0 = off[wave], i1 = off[wave + 1];
    float acc0 = 0.f, acc1 = 0.f;
    int i = i0;
    for (; i + 1 < i1; i += 2) {
        int2 p0 = pair[i], p1 = pair[i + 1];
        uint4 eA = eab[p0.x];
        uint4 eB = eab[p1.x];
        unsigned uA = hb[(size_t)p0.y * 64 + lane];
        unsigned uB = hb[(size_t)p1.y * 64 + lane];
        float m0 = b0 + bflo(uA), m1 = b1 + bfhi(uA);
        float n0 = b0 + bflo(uB), n1 = b1 + bfhi(uB);
        float a[8] = { bflo(eA.x), bfhi(eA.x), bflo(eA.y), bfhi(eA.y),
                       bflo(eA.z), bfhi(eA.z), bflo(eA.w), bfhi(eA.w) };
        float d[8] = { bflo(eB.x), bfhi(eB.x), bflo(eB.y), bfhi(eB.y),
                       bflo(eB.z), bfhi(eB.z), bflo(eB.w), bfhi(eB.w) };
#pragma unroll
        for (int k = 0; k < F_EDGE; ++k) {
            m0 = fmaf(a[k], w0[k], m0);
            m1 = fmaf(a[k], w1[k], m1);
            n0 = fmaf(d[k], w0[k], n0);
            n1 = fmaf(d[k], w1[k], n1);
        }
        acc0 += fmaxf(m0, 0.f) + fmaxf(n0, 0.f);
        acc1 += fmaxf(m1, 0.f) + fmaxf(n1, 0.f);
    }
    if (i < i1) {
        int2 p0 = pair[i];
        uint4 eA = eab[p0.x];
        unsigned uA = hb[(size_t)p0.y * 64 + lane];
        float m0 = b0 + bflo(uA), m1 = b1 + bfhi(uA);
        float a[8] = { bflo(eA.x), bfhi(eA.x), bflo(eA.y), bfhi(eA.y),
                       bflo(eA.z), bfhi(eA.z), bflo(eA.w), bfhi(eA.w) };
#pragma unroll
        for (int k = 0; k < F_EDGE; ++k) {
            m0 = fmaf(a[k], w0[k], m0);
            m1 = fmaf(a[k], w1[k], m1);
        }
        acc0 += fmaxf(m0, 0.f);
        acc1 += fmaxf(m1, 0.f);
    }
    float2 ho = *(const float2*)&h[(size_t)wave * HID + j0];
    *(float2*)&agg[(size_t)wave * HID + j0] = make_float2(ho.x + acc0, ho.y + acc1);
}

// ================= fused 2-layer node MLP =================
// 16 rows/block, 128 threads. Optional packed-bf16 duplicate output.
template <int K, bool OUTER_ELU, bool DUP_B16>
__global__ __launch_bounds__(128) void mlp_kernel(
    const float* __restrict__ in, const float* __restrict__ Wa, const float* __restrict__ ba,
    const float* __restrict__ Wb, const float* __restrict__ bb,
    float* __restrict__ out, unsigned* __restrict__ outb, int nrows)
{
    constexpr int SA = K + 4;
    constexpr int ST = HID + 4;
    __shared__ float in_s[16 * SA];
    __shared__ float t1_s[16 * ST];

    const int tid = threadIdx.x;
    const int row_base = blockIdx.x * 16;

    {
        const int r = tid >> 3;
        const int q0 = tid & 7;
        constexpr int QUADS = K / 4;
#pragma unroll
        for (int q = q0; q < QUADS; q += 8) {
            float4 v = *(const float4*)&in[(size_t)(row_base + r) * K + q * 4];
            *(float4*)&in_s[r * SA + q * 4] = v;
        }
    }
    __syncthreads();

    const int jp = tid & 63;
    const int rb = tid >> 6;
    const int j0 = 2 * jp;

    float acc0[8], acc1[8];
    {
        float2 bv = *(const float2*)&ba[j0];
#pragma unroll
        for (int r = 0; r < 8; ++r) { acc0[r] = bv.x; acc1[r] = bv.y; }
    }
#pragma unroll 4
    for (int k = 0; k < K; k += 2) {
        float2 wk0 = *(const float2*)&Wa[(size_t)k * HID + j0];
        float2 wk1 = *(const float2*)&Wa[(size_t)(k + 1) * HID + j0];
#pragma unroll
        for (int r = 0; r < 8; ++r) {
            float2 a = *(const float2*)&in_s[(rb * 8 + r) * SA + k];
            acc0[r] = fmaf(a.x, wk0.x, acc0[r]);
            acc0[r] = fmaf(a.y, wk1.x, acc0[r]);
            acc1[r] = fmaf(a.x, wk0.y, acc1[r]);
            acc1[r] = fmaf(a.y, wk1.y, acc1[r]);
        }
    }
#pragma unroll
    for (int r = 0; r < 8; ++r) {
        float2 v = make_float2(elu_f(acc0[r]), elu_f(acc1[r]));
        *(float2*)&t1_s[(rb * 8 + r) * ST + j0] = v;
    }
    __syncthreads();

    {
        float2 bv = *(const float2*)&bb[j0];
#pragma unroll
        for (int r = 0; r < 8; ++r) { acc0[r] = bv.x; acc1[r] = bv.y; }
    }
#pragma unroll 4
    for (int k = 0; k < HID; k += 2) {
        float2 wk0 = *(const float2*)&Wb[(size_t)k * HID + j0];
        float2 wk1 = *(const float2*)&Wb[(size_t)(k + 1) * HID + j0];
#pragma unroll
        for (int r = 0; r < 8; ++r) {
            float2 a = *(const float2*)&t1_s[(rb * 8 + r) * ST + k];
            acc0[r] = fmaf(a.x, wk0.x, acc0[r]);
            acc0[r] = fmaf(a.y, wk1.x, acc0[r]);
            acc1[r] = fmaf(a.x, wk0.y, acc1[r]);
            acc1[r] = fmaf(a.y, wk1.y, acc1[r]);
        }
    }
#pragma unroll
    for (int r = 0; r < 8; ++r) {
        int row = row_base + rb * 8 + r;
        if (row < nrows) {
            float2 v;
            v.x = OUTER_ELU ? elu_f(acc0[r]) : acc0[r];
            v.y = OUTER_ELU ? elu_f(acc1[r]) : acc1[r];
            *(float2*)&out[(size_t)row * HID + j0] = v;
            if (DUP_B16) outb[(size_t)row * 64 + jp] = pack2(v.x, v.y);
        }
    }
}

// ================= global add pool (run-length, batch sorted) =================
__global__ __launch_bounds__(128) void pool_kernel(
    const float* __restrict__ h, const int* __restrict__ batch,
    float* __restrict__ hg, int N)
{
    int base = blockIdx.x * 64;
    if (base >= N) return;
    int j = threadIdx.x;
    int end = base + 64 < N ? base + 64 : N;
    int cur = batch[base];
    float acc = 0.f;
    for (int n = base; n < end; ++n) {
        int b = batch[n];
        if (b != cur) {
            atomicAdd(&hg[(size_t)cur * HID + j], acc);
            acc = 0.f;
            cur = b;
        }
        acc += h[(size_t)n * HID + j];
    }
    atomicAdd(&hg[(size_t)cur * HID + j], acc);
}

// ================= head =================
__global__ __launch_bounds__(128) void head_kernel(
    const float* __restrict__ hg, const float* __restrict__ Wl1, const float* __restrict__ bl1,
    const float* __restrict__ Wl2, const float* __restrict__ bl2, float* __restrict__ out)
{
    __shared__ float row_s[HID];
    __shared__ float t_s[HID];
    int g = blockIdx.x;
    int j = threadIdx.x;
    row_s[j] = hg[(size_t)g * HID + j];
    __syncthreads();
    float s = bl1[j];
#pragma unroll 4
    for (int k = 0; k < HID; ++k) s = fmaf(row_s[k], Wl1[k * HID + j], s);
    t_s[j] = fmaxf(s, 0.f);
    __syncthreads();
    if (j < 12) {
        float o = bl2[j];
#pragma unroll 4
        for (int k = 0; k < HID; ++k) o = fmaf(t_s[k], Wl2[k * 12 + j], o);
        out[(size_t)g * 12 + j] = o;
    }
}

extern "C" void kernel_launch(void* const* d_in, const int* in_sizes, int n_in,
                              void* d_out, int out_size, void* d_ws, size_t ws_size,
                              hipStream_t stream)
{
    const float* x    = (const float*)d_in[0];
    const int*   ei   = (const int*)d_in[1];
    const float* ea   = (const float*)d_in[2];
    const int*   batch = (const int*)d_in[3];
    const float* We1 = (const float*)d_in[4];
    const float* be1 = (const float*)d_in[5];
    const float* W1a = (const float*)d_in[6];
    const float* b1a = (const float*)d_in[7];
    const float* W1b = (const float*)d_in[8];
    const float* b1b = (const float*)d_in[9];
    const float* We2 = (const float*)d_in[10];
    const float* be2 = (const float*)d_in[11];
    const float* W2a = (const float*)d_in[12];
    const float* b2a = (const float*)d_in[13];
    const float* W2b = (const float*)d_in[14];
    const float* b2b = (const float*)d_in[15];
    const float* Wl1 = (const float*)d_in[16];
    const float* bl1 = (const float*)d_in[17];
    const float* Wl2 = (const float*)d_in[18];
    const float* bl2 = (const float*)d_in[19];
    float* out = (float*)d_out;

    const int N = in_sizes[0] / F_NODE;
    const int E = in_sizes[1] / 2;
    const int G = out_size / 12;

    const int* srcp = ei;
    const int* dstp = ei + E;

    // ---- workspace layout ----
    char* wsb = (char*)d_ws;
    int* cnt  = (int*)wsb;                    wsb += (size_t)N * sizeof(int);
    int* off  = (int*)wsb;                    wsb += (size_t)(N + 1) * sizeof(int);
    int* part = (int*)wsb;                    wsb += 256 * sizeof(int);
    int2* pair = (int2*)wsb;                  wsb += (size_t)E * sizeof(int2);
    unsigned* xb = (unsigned*)wsb;            wsb += (size_t)N * 16 * sizeof(unsigned);
    unsigned* eab = (unsigned*)wsb;           wsb += (size_t)E * 4 * sizeof(unsigned);
    unsigned* h1b = (unsigned*)wsb;           wsb += (size_t)N * 64 * sizeof(unsigned);
    float* agg1 = (float*)wsb;                wsb += (size_t)N * F_NODE * sizeof(float);
    float* h1   = (float*)wsb;                wsb += (size_t)N * HID * sizeof(float);
    float* agg2 = (float*)wsb;                wsb += (size_t)N * HID * sizeof(float);
    float* hg   = (float*)wsb;                wsb += (size_t)G * HID * sizeof(float);

    // ---- prep: bf16 tables + CSR build ----
    hipMemsetAsync(cnt, 0, (size_t)N * sizeof(int), stream);
    hipMemsetAsync(hg, 0, (size_t)G * HID * sizeof(float), stream);
    {
        int nx = N * 16, ne = E * 4;
        hipLaunchKernelGGL(cast_kernel, dim3((nx + ne + 255) / 256), dim3(256), 0, stream,
                           x, ea, xb, eab, nx, ne);
    }
    hipLaunchKernelGGL(hist_kernel, dim3((E + 255) / 256), dim3(256), 0, stream, dstp, cnt, E);
    int nscan = (N + 1023) / 1024;
    hipLaunchKernelGGL(scan1_kernel, dim3(nscan), dim3(256), 0, stream, cnt, off, part, N);
    hipLaunchKernelGGL(scan2_kernel, dim3(1), dim3(256), 0, stream, part, nscan);
    hipLaunchKernelGGL(scan3_kernel, dim3((N + 255) / 256), dim3(256), 0, stream, off, part, N, E);
    hipLaunchKernelGGL(fill_kernel, dim3((E + 255) / 256), dim3(256), 0, stream,
                       dstp, srcp, off, cnt, pair, E);

    // ---- conv1 ----
    hipLaunchKernelGGL(agg1_kernel, dim3((N + 3) / 4), dim3(256), 0, stream,
                       x, xb, (const uint4*)eab, We1, be1, off, pair, agg1, N);
    hipLaunchKernelGGL((mlp_kernel<F_NODE, true, true>), dim3((N + 15) / 16), dim3(128), 0, stream,
                       agg1, W1a, b1a, W1b, b1b, h1, h1b, N);

    // ---- conv2 ----
    hipLaunchKernelGGL(agg2_kernel, dim3((N + 3) / 4), dim3(256), 0, stream,
                       h1, h1b, (const uint4*)eab, We2, be2, off, pair, agg2, N);
    hipLaunchKernelGGL((mlp_kernel<HID, true, false>), dim3((N + 15) / 16), dim3(128), 0, stream,
                       agg2, W2a, b2a, W2b, b2b, h1, (unsigned*)nullptr, N);

    // ---- pool + head ----
    hipLaunchKernelGGL(pool_kernel, dim3((N + 63) / 64), dim3(128), 0, stream,
                       h1, batch, hg, N);
    hipLaunchKernelGGL(head_kernel, dim3(G), dim3(128), 0, stream,
                       hg, Wl1, bl1, Wl2, bl2, out);
}

// Round 5
// 634.965 us; speedup vs baseline: 2.7640x; 1.0600x over previous
//
#include <hip/hip_runtime.h>
#include <math.h>

#define F_NODE 32
#define F_EDGE 8
#define HID 128

__device__ __forceinline__ float elu_f(float x) { return x > 0.f ? x : expf(x) - 1.f; }

// ---- bf16 pack/unpack helpers ----
__device__ __forceinline__ unsigned bf16rne(float f) {
    unsigned u = __float_as_uint(f);
    return (u + 0x7FFFu + ((u >> 16) & 1u)) >> 16;
}
__device__ __forceinline__ unsigned pack2(float lo, float hi) {
    return bf16rne(lo) | (bf16rne(hi) << 16);
}
__device__ __forceinline__ float bflo(unsigned u) { return __uint_as_float(u << 16); }
__device__ __forceinline__ float bfhi(unsigned u) { return __uint_as_float(u & 0xFFFF0000u); }

// ================= cast: x, ea -> packed bf16 tables =================
__global__ void cast_kernel(const float* __restrict__ x, const float* __restrict__ ea,
                            unsigned* __restrict__ xb, unsigned* __restrict__ eab,
                            int nx, int ne) {
    int i = blockIdx.x * 256 + threadIdx.x;
    if (i < nx) {
        float2 v = ((const float2*)x)[i];
        xb[i] = pack2(v.x, v.y);
    }
    int j = i - nx;
    if (j >= 0 && j < ne) {
        float2 v = ((const float2*)ea)[j];
        eab[j] = pack2(v.x, v.y);
    }
}

// ================= CSR build =================
__global__ void hist_kernel(const int* __restrict__ dst, int* __restrict__ cnt, int E) {
    int i = blockIdx.x * blockDim.x + threadIdx.x;
    if (i < E) atomicAdd(&cnt[dst[i]], 1);
}

__global__ void scan1_kernel(const int* __restrict__ in, int* __restrict__ out,
                             int* __restrict__ part, int n) {
    __shared__ int s[256];
    int t = threadIdx.x;
    int base = blockIdx.x * 1024 + t * 4;
    int v0 = base + 0 < n ? in[base + 0] : 0;
    int v1 = base + 1 < n ? in[base + 1] : 0;
    int v2 = base + 2 < n ? in[base + 2] : 0;
    int v3 = base + 3 < n ? in[base + 3] : 0;
    int tot = v0 + v1 + v2 + v3;
    s[t] = tot;
    __syncthreads();
    for (int off = 1; off < 256; off <<= 1) {
        int val = (t >= off) ? s[t - off] : 0;
        __syncthreads();
        s[t] += val;
        __syncthreads();
    }
    int pre = s[t] - tot;
    if (base + 0 < n) out[base + 0] = pre;
    if (base + 1 < n) out[base + 1] = pre + v0;
    if (base + 2 < n) out[base + 2] = pre + v0 + v1;
    if (base + 3 < n) out[base + 3] = pre + v0 + v1 + v2;
    if (t == 255) part[blockIdx.x] = s[255];
}

__global__ void scan2_kernel(int* part, int nb) {
    __shared__ int s[256];
    int t = threadIdx.x;
    int v = t < nb ? part[t] : 0;
    s[t] = v;
    __syncthreads();
    for (int off = 1; off < 256; off <<= 1) {
        int val = (t >= off) ? s[t - off] : 0;
        __syncthreads();
        s[t] += val;
        __syncthreads();
    }
    if (t < nb) part[t] = s[t] - v;  // exclusive
}

__global__ void scan3_kernel(int* __restrict__ out, const int* __restrict__ part, int n, int total) {
    int i = blockIdx.x * blockDim.x + threadIdx.x;
    if (i < n) out[i] += part[i >> 10];
    if (i == 0) out[n] = total;
}

__global__ void fill_kernel(const int* __restrict__ dst, const int* __restrict__ src,
                            const int* __restrict__ off, int* __restrict__ cnt,
                            int2* __restrict__ pair, int E) {
    int i = blockIdx.x * blockDim.x + threadIdx.x;
    if (i >= E) return;
    int d = dst[i];
    int old = atomicSub(&cnt[d], 1);
    pair[off[d] + old - 1] = make_int2(i, src[i]);
}

// ================= conv1 gather-aggregate (bf16 gathers) =================
// one wave per node; lane = fp (0..15 feature pair) + eg (0..3 edge group)
__global__ __launch_bounds__(256) void agg1_kernel(
    const float* __restrict__ x, const unsigned* __restrict__ xb,
    const uint4* __restrict__ eab,
    const float* __restrict__ We, const float* __restrict__ be,
    const int* __restrict__ off, const int2* __restrict__ pair,
    float* __restrict__ agg, int N)
{
    int wave = (blockIdx.x * 256 + threadIdx.x) >> 6;
    if (wave >= N) return;
    int lane = threadIdx.x & 63;
    int fp = lane & 15, eg = lane >> 4;
    int j0 = fp * 2;
    float w0[F_EDGE], w1[F_EDGE];
#pragma unroll
    for (int k = 0; k < F_EDGE; ++k) {
        w0[k] = We[k * F_NODE + j0];
        w1[k] = We[k * F_NODE + j0 + 1];
    }
    float b0 = be[j0], b1 = be[j0 + 1];
    int i0 = __builtin_amdgcn_readfirstlane(off[wave]);
    int i1 = __builtin_amdgcn_readfirstlane(off[wave + 1]);
    float acc0 = 0.f, acc1 = 0.f;
    for (int i = i0; i < i1; i += 4) {
        int ii = i + eg;
        if (ii < i1) {
            int2 p = pair[ii];
            uint4 e = eab[p.x];
            unsigned u = xb[(size_t)p.y * 16 + fp];
            float m0 = b0 + bflo(u), m1 = b1 + bfhi(u);
            float c[8] = { bflo(e.x), bfhi(e.x), bflo(e.y), bfhi(e.y),
                           bflo(e.z), bfhi(e.z), bflo(e.w), bfhi(e.w) };
#pragma unroll
            for (int k = 0; k < F_EDGE; ++k) {
                m0 = fmaf(c[k], w0[k], m0);
                m1 = fmaf(c[k], w1[k], m1);
            }
            acc0 += fmaxf(m0, 0.f);
            acc1 += fmaxf(m1, 0.f);
        }
    }
    acc0 += __shfl_xor(acc0, 16, 64);
    acc0 += __shfl_xor(acc0, 32, 64);
    acc1 += __shfl_xor(acc1, 16, 64);
    acc1 += __shfl_xor(acc1, 32, 64);
    if (eg == 0) {
        float2 xo = *(const float2*)&x[(size_t)wave * F_NODE + j0];
        *(float2*)&agg[(size_t)wave * F_NODE + j0] = make_float2(xo.x + acc0, xo.y + acc1);
    }
}

// ================= conv2 gather-aggregate (scalarized uniform path) =================
// one wave per node; lane owns adjacent feature pair j0 = 2*lane.
// Loop bounds forced to SGPR -> pair/eab loads are uniform (SMEM) and the
// edge-attr bf16 unpacks run on the SALU in parallel with the FMA stream.
__global__ __launch_bounds__(256) void agg2_kernel(
    const float* __restrict__ h, const unsigned* __restrict__ hb,
    const uint4* __restrict__ eab,
    const float* __restrict__ We, const float* __restrict__ be,
    const int* __restrict__ off, const int2* __restrict__ pair,
    float* __restrict__ agg, int N)
{
    int wave = (blockIdx.x * 256 + threadIdx.x) >> 6;
    if (wave >= N) return;
    int lane = threadIdx.x & 63;
    int j0 = lane * 2;
    float w0[F_EDGE], w1[F_EDGE];
#pragma unroll
    for (int k = 0; k < F_EDGE; ++k) {
        w0[k] = We[k * HID + j0];
        w1[k] = We[k * HID + j0 + 1];
    }
    float b0 = be[j0], b1 = be[j0 + 1];
    int i0 = __builtin_amdgcn_readfirstlane(off[wave]);
    int i1 = __builtin_amdgcn_readfirstlane(off[wave + 1]);
    float acc0 = 0.f, acc1 = 0.f;
    int i = i0;
    for (; i + 1 < i1; i += 2) {
        int2 p0 = pair[i], p1 = pair[i + 1];
        uint4 eA = eab[p0.x];
        uint4 eB = eab[p1.x];
        const unsigned* hA = hb + (size_t)p0.y * 64;
        const unsigned* hB = hb + (size_t)p1.y * 64;
        unsigned uA = hA[lane];
        unsigned uB = hB[lane];
        float m0 = b0 + bflo(uA), m1 = b1 + bfhi(uA);
        float n0 = b0 + bflo(uB), n1 = b1 + bfhi(uB);
        float a[8] = { bflo(eA.x), bfhi(eA.x), bflo(eA.y), bfhi(eA.y),
                       bflo(eA.z), bfhi(eA.z), bflo(eA.w), bfhi(eA.w) };
        float d[8] = { bflo(eB.x), bfhi(eB.x), bflo(eB.y), bfhi(eB.y),
                       bflo(eB.z), bfhi(eB.z), bflo(eB.w), bfhi(eB.w) };
#pragma unroll
        for (int k = 0; k < F_EDGE; ++k) {
            m0 = fmaf(a[k], w0[k], m0);
            m1 = fmaf(a[k], w1[k], m1);
            n0 = fmaf(d[k], w0[k], n0);
            n1 = fmaf(d[k], w1[k], n1);
        }
        acc0 += fmaxf(m0, 0.f) + fmaxf(n0, 0.f);
        acc1 += fmaxf(m1, 0.f) + fmaxf(n1, 0.f);
    }
    if (i < i1) {
        int2 p0 = pair[i];
        uint4 eA = eab[p0.x];
        const unsigned* hA = hb + (size_t)p0.y * 64;
        unsigned uA = hA[lane];
        float m0 = b0 + bflo(uA), m1 = b1 + bfhi(uA);
        float a[8] = { bflo(eA.x), bfhi(eA.x), bflo(eA.y), bfhi(eA.y),
                       bflo(eA.z), bfhi(eA.z), bflo(eA.w), bfhi(eA.w) };
#pragma unroll
        for (int k = 0; k < F_EDGE; ++k) {
            m0 = fmaf(a[k], w0[k], m0);
            m1 = fmaf(a[k], w1[k], m1);
        }
        acc0 += fmaxf(m0, 0.f);
        acc1 += fmaxf(m1, 0.f);
    }
    float2 ho = *(const float2*)&h[(size_t)wave * HID + j0];
    *(float2*)&agg[(size_t)wave * HID + j0] = make_float2(ho.x + acc0, ho.y + acc1);
}

// ================= fused 2-layer node MLP =================
// 32 rows/block, 256 threads. Thread = 8 rows x 2 adjacent cols; k-quad inner
// step: 8 ds_read_b128 + 4 global float2 per 64 FMA.
template <int K, bool OUTER_ELU, bool DUP_B16>
__global__ __launch_bounds__(256) void mlp_kernel(
    const float* __restrict__ in, const float* __restrict__ Wa, const float* __restrict__ ba,
    const float* __restrict__ Wb, const float* __restrict__ bb,
    float* __restrict__ out, unsigned* __restrict__ outb, int nrows)
{
    constexpr int SA = K + 4;
    constexpr int ST = HID + 4;
    __shared__ float in_s[32 * SA];
    __shared__ float t1_s[32 * ST];

    const int tid = threadIdx.x;
    const int row_base = blockIdx.x * 32;

    {
        const int r = tid >> 3;      // 0..31
        const int q0 = tid & 7;
        constexpr int QUADS = K / 4;
#pragma unroll
        for (int q = q0; q < QUADS; q += 8) {
            float4 v = make_float4(0.f, 0.f, 0.f, 0.f);
            if (row_base + r < nrows) v = *(const float4*)&in[(size_t)(row_base + r) * K + q * 4];
            *(float4*)&in_s[r * SA + q * 4] = v;
        }
    }
    __syncthreads();

    const int jp = tid & 63;
    const int rb = tid >> 6;       // 0..3 -> rows rb*8..rb*8+7
    const int j0 = 2 * jp;

    float acc0[8], acc1[8];
    {
        float2 bv = *(const float2*)&ba[j0];
#pragma unroll
        for (int r = 0; r < 8; ++r) { acc0[r] = bv.x; acc1[r] = bv.y; }
    }
#pragma unroll 2
    for (int k = 0; k < K; k += 4) {
        float2 wk0 = *(const float2*)&Wa[(size_t)k * HID + j0];
        float2 wk1 = *(const float2*)&Wa[(size_t)(k + 1) * HID + j0];
        float2 wk2 = *(const float2*)&Wa[(size_t)(k + 2) * HID + j0];
        float2 wk3 = *(const float2*)&Wa[(size_t)(k + 3) * HID + j0];
#pragma unroll
        for (int r = 0; r < 8; ++r) {
            float4 a = *(const float4*)&in_s[(rb * 8 + r) * SA + k];
            acc0[r] = fmaf(a.x, wk0.x, acc0[r]);
            acc0[r] = fmaf(a.y, wk1.x, acc0[r]);
            acc0[r] = fmaf(a.z, wk2.x, acc0[r]);
            acc0[r] = fmaf(a.w, wk3.x, acc0[r]);
            acc1[r] = fmaf(a.x, wk0.y, acc1[r]);
            acc1[r] = fmaf(a.y, wk1.y, acc1[r]);
            acc1[r] = fmaf(a.z, wk2.y, acc1[r]);
            acc1[r] = fmaf(a.w, wk3.y, acc1[r]);
        }
    }
#pragma unroll
    for (int r = 0; r < 8; ++r) {
        float2 v = make_float2(elu_f(acc0[r]), elu_f(acc1[r]));
        *(float2*)&t1_s[(rb * 8 + r) * ST + j0] = v;
    }
    __syncthreads();

    {
        float2 bv = *(const float2*)&bb[j0];
#pragma unroll
        for (int r = 0; r < 8; ++r) { acc0[r] = bv.x; acc1[r] = bv.y; }
    }
#pragma unroll 2
    for (int k = 0; k < HID; k += 4) {
        float2 wk0 = *(const float2*)&Wb[(size_t)k * HID + j0];
        float2 wk1 = *(const float2*)&Wb[(size_t)(k + 1) * HID + j0];
        float2 wk2 = *(const float2*)&Wb[(size_t)(k + 2) * HID + j0];
        float2 wk3 = *(const float2*)&Wb[(size_t)(k + 3) * HID + j0];
#pragma unroll
        for (int r = 0; r < 8; ++r) {
            float4 a = *(const float4*)&t1_s[(rb * 8 + r) * ST + k];
            acc0[r] = fmaf(a.x, wk0.x, acc0[r]);
            acc0[r] = fmaf(a.y, wk1.x, acc0[r]);
            acc0[r] = fmaf(a.z, wk2.x, acc0[r]);
            acc0[r] = fmaf(a.w, wk3.x, acc0[r]);
            acc1[r] = fmaf(a.x, wk0.y, acc1[r]);
            acc1[r] = fmaf(a.y, wk1.y, acc1[r]);
            acc1[r] = fmaf(a.z, wk2.y, acc1[r]);
            acc1[r] = fmaf(a.w, wk3.y, acc1[r]);
        }
    }
#pragma unroll
    for (int r = 0; r < 8; ++r) {
        int row = row_base + rb * 8 + r;
        if (row < nrows) {
            float2 v;
            v.x = OUTER_ELU ? elu_f(acc0[r]) : acc0[r];
            v.y = OUTER_ELU ? elu_f(acc1[r]) : acc1[r];
            *(float2*)&out[(size_t)row * HID + j0] = v;
            if (DUP_B16) outb[(size_t)row * 64 + jp] = pack2(v.x, v.y);
        }
    }
}

// ================= global add pool (run-length, batch sorted) =================
__global__ __launch_bounds__(128) void pool_kernel(
    const float* __restrict__ h, const int* __restrict__ batch,
    float* __restrict__ hg, int N)
{
    int base = blockIdx.x * 64;
    if (base >= N) return;
    int j = threadIdx.x;
    int end = base + 64 < N ? base + 64 : N;
    int cur = batch[base];
    float acc = 0.f;
    for (int n = base; n < end; ++n) {
        int b = batch[n];
        if (b != cur) {
            atomicAdd(&hg[(size_t)cur * HID + j], acc);
            acc = 0.f;
            cur = b;
        }
        acc += h[(size_t)n * HID + j];
    }
    atomicAdd(&hg[(size_t)cur * HID + j], acc);
}

// ================= head =================
__global__ __launch_bounds__(128) void head_kernel(
    const float* __restrict__ hg, const float* __restrict__ Wl1, const float* __restrict__ bl1,
    const float* __restrict__ Wl2, const float* __restrict__ bl2, float* __restrict__ out)
{
    __shared__ float row_s[HID];
    __shared__ float t_s[HID];
    int g = blockIdx.x;
    int j = threadIdx.x;
    row_s[j] = hg[(size_t)g * HID + j];
    __syncthreads();
    float s = bl1[j];
#pragma unroll 4
    for (int k = 0; k < HID; ++k) s = fmaf(row_s[k], Wl1[k * HID + j], s);
    t_s[j] = fmaxf(s, 0.f);
    __syncthreads();
    if (j < 12) {
        float o = bl2[j];
#pragma unroll 4
        for (int k = 0; k < HID; ++k) o = fmaf(t_s[k], Wl2[k * 12 + j], o);
        out[(size_t)g * 12 + j] = o;
    }
}

extern "C" void kernel_launch(void* const* d_in, const int* in_sizes, int n_in,
                              void* d_out, int out_size, void* d_ws, size_t ws_size,
                              hipStream_t stream)
{
    const float* x    = (const float*)d_in[0];
    const int*   ei   = (const int*)d_in[1];
    const float* ea   = (const float*)d_in[2];
    const int*   batch = (const int*)d_in[3];
    const float* We1 = (const float*)d_in[4];
    const float* be1 = (const float*)d_in[5];
    const float* W1a = (const float*)d_in[6];
    const float* b1a = (const float*)d_in[7];
    const float* W1b = (const float*)d_in[8];
    const float* b1b = (const float*)d_in[9];
    const float* We2 = (const float*)d_in[10];
    const float* be2 = (const float*)d_in[11];
    const float* W2a = (const float*)d_in[12];
    const float* b2a = (const float*)d_in[13];
    const float* W2b = (const float*)d_in[14];
    const float* b2b = (const float*)d_in[15];
    const float* Wl1 = (const float*)d_in[16];
    const float* bl1 = (const float*)d_in[17];
    const float* Wl2 = (const float*)d_in[18];
    const float* bl2 = (const float*)d_in[19];
    float* out = (float*)d_out;

    const int N = in_sizes[0] / F_NODE;
    const int E = in_sizes[1] / 2;
    const int G = out_size / 12;

    const int* srcp = ei;
    const int* dstp = ei + E;

    // ---- workspace layout ----
    char* wsb = (char*)d_ws;
    int* cnt  = (int*)wsb;                    wsb += (size_t)N * sizeof(int);
    int* off  = (int*)wsb;                    wsb += (size_t)(N + 1) * sizeof(int);
    int* part = (int*)wsb;                    wsb += 256 * sizeof(int);
    int2* pair = (int2*)wsb;                  wsb += (size_t)E * sizeof(int2);
    unsigned* xb = (unsigned*)wsb;            wsb += (size_t)N * 16 * sizeof(unsigned);
    unsigned* eab = (unsigned*)wsb;           wsb += (size_t)E * 4 * sizeof(unsigned);
    unsigned* h1b = (unsigned*)wsb;           wsb += (size_t)N * 64 * sizeof(unsigned);
    float* agg1 = (float*)wsb;                wsb += (size_t)N * F_NODE * sizeof(float);
    float* h1   = (float*)wsb;                wsb += (size_t)N * HID * sizeof(float);
    float* agg2 = (float*)wsb;                wsb += (size_t)N * HID * sizeof(float);
    float* hg   = (float*)wsb;                wsb += (size_t)G * HID * sizeof(float);

    // ---- prep: bf16 tables + CSR build ----
    hipMemsetAsync(cnt, 0, (size_t)N * sizeof(int), stream);
    hipMemsetAsync(hg, 0, (size_t)G * HID * sizeof(float), stream);
    {
        int nx = N * 16, ne = E * 4;
        hipLaunchKernelGGL(cast_kernel, dim3((nx + ne + 255) / 256), dim3(256), 0, stream,
                           x, ea, xb, eab, nx, ne);
    }
    hipLaunchKernelGGL(hist_kernel, dim3((E + 255) / 256), dim3(256), 0, stream, dstp, cnt, E);
    int nscan = (N + 1023) / 1024;
    hipLaunchKernelGGL(scan1_kernel, dim3(nscan), dim3(256), 0, stream, cnt, off, part, N);
    hipLaunchKernelGGL(scan2_kernel, dim3(1), dim3(256), 0, stream, part, nscan);
    hipLaunchKernelGGL(scan3_kernel, dim3((N + 255) / 256), dim3(256), 0, stream, off, part, N, E);
    hipLaunchKernelGGL(fill_kernel, dim3((E + 255) / 256), dim3(256), 0, stream,
                       dstp, srcp, off, cnt, pair, E);

    // ---- conv1 ----
    hipLaunchKernelGGL(agg1_kernel, dim3((N + 3) / 4), dim3(256), 0, stream,
                       x, xb, (const uint4*)eab, We1, be1, off, pair, agg1, N);
    hipLaunchKernelGGL((mlp_kernel<F_NODE, true, true>), dim3((N + 31) / 32), dim3(256), 0, stream,
                       agg1, W1a, b1a, W1b, b1b, h1, h1b, N);

    // ---- conv2 ----
    hipLaunchKernelGGL(agg2_kernel, dim3((N + 3) / 4), dim3(256), 0, stream,
                       h1, h1b, (const uint4*)eab, We2, be2, off, pair, agg2, N);
    hipLaunchKernelGGL((mlp_kernel<HID, true, false>), dim3((N + 31) / 32), dim3(256), 0, stream,
                       agg2, W2a, b2a, W2b, b2b, h1, (unsigned*)nullptr, N);

    // ---- pool + head ----
    hipLaunchKernelGGL(pool_kernel, dim3((N + 63) / 64), dim3(128), 0, stream,
                       h1, batch, hg, N);
    hipLaunchKernelGGL(head_kernel, dim3(G), dim3(128), 0, stream,
                       hg, Wl1, bl1, Wl2, bl2, out);
}

// Round 6
// 496.336 us; speedup vs baseline: 3.5359x; 1.2793x over previous
//
#include <hip/hip_runtime.h>
#include <math.h>

#define F_NODE 32
#define F_EDGE 8
#define HID 128

typedef __attribute__((ext_vector_type(8))) short bf16x8;
typedef __attribute__((ext_vector_type(4))) float f32x4;

__device__ __forceinline__ float elu_f(float x) { return x > 0.f ? x : expf(x) - 1.f; }

// ---- bf16 pack/unpack helpers ----
__device__ __forceinline__ unsigned bf16rne(float f) {
    unsigned u = __float_as_uint(f);
    return (u + 0x7FFFu + ((u >> 16) & 1u)) >> 16;
}
__device__ __forceinline__ unsigned pack2(float lo, float hi) {
    return bf16rne(lo) | (bf16rne(hi) << 16);
}
__device__ __forceinline__ float bflo(unsigned u) { return __uint_as_float(u << 16); }
__device__ __forceinline__ float bfhi(unsigned u) { return __uint_as_float(u & 0xFFFF0000u); }

__device__ __forceinline__ bf16x8 frag_from(uint4 v) {
    union { uint4 u; bf16x8 f; } x; x.u = v; return x.f;
}

// ================= cast: x, ea -> packed bf16 tables =================
__global__ void cast_kernel(const float* __restrict__ x, const float* __restrict__ ea,
                            unsigned* __restrict__ xb, unsigned* __restrict__ eab,
                            int nx, int ne) {
    int i = blockIdx.x * 256 + threadIdx.x;
    if (i < nx) {
        float2 v = ((const float2*)x)[i];
        xb[i] = pack2(v.x, v.y);
    }
    int j = i - nx;
    if (j >= 0 && j < ne) {
        float2 v = ((const float2*)ea)[j];
        eab[j] = pack2(v.x, v.y);
    }
}

// ================= weight pre-pack into MFMA B-fragment order =================
// P[(ct*KS + ks)*64 + lane] = uint4 of 8 bf16: W[ks*32 + (lane>>4)*8 + j][ct*16 + (lane&15)]
__global__ void wpack_kernel(const float* __restrict__ W1a, const float* __restrict__ W1b,
                             const float* __restrict__ W2a, const float* __restrict__ W2b,
                             uint4* __restrict__ P1a, uint4* __restrict__ P1b,
                             uint4* __restrict__ P2a, uint4* __restrict__ P2b)
{
    int i = blockIdx.x * 256 + threadIdx.x;
    const float* W; uint4* P; int KS; int f;
    if (i < 512)       { W = W1a; P = P1a; KS = 1; f = i; }
    else if (i < 2560) { W = W1b; P = P1b; KS = 4; f = i - 512; }
    else if (i < 4608) { W = W2a; P = P2a; KS = 4; f = i - 2560; }
    else if (i < 6656) { W = W2b; P = P2b; KS = 4; f = i - 4608; }
    else return;
    int lane = f & 63;
    int rem = f >> 6;
    int ks = rem % KS, ct = rem / KS;
    int col = ct * 16 + (lane & 15);
    int k0 = ks * 32 + (lane >> 4) * 8;
    float w[8];
#pragma unroll
    for (int j = 0; j < 8; ++j) w[j] = W[(size_t)(k0 + j) * HID + col];
    uint4 v;
    v.x = pack2(w[0], w[1]);
    v.y = pack2(w[2], w[3]);
    v.z = pack2(w[4], w[5]);
    v.w = pack2(w[6], w[7]);
    P[f] = v;
}

// ================= CSR build =================
__global__ void hist_kernel(const int* __restrict__ dst, int* __restrict__ cnt, int E) {
    int i = blockIdx.x * blockDim.x + threadIdx.x;
    if (i < E) atomicAdd(&cnt[dst[i]], 1);
}

__global__ void scan1_kernel(const int* __restrict__ in, int* __restrict__ out,
                             int* __restrict__ part, int n) {
    __shared__ int s[256];
    int t = threadIdx.x;
    int base = blockIdx.x * 1024 + t * 4;
    int v0 = base + 0 < n ? in[base + 0] : 0;
    int v1 = base + 1 < n ? in[base + 1] : 0;
    int v2 = base + 2 < n ? in[base + 2] : 0;
    int v3 = base + 3 < n ? in[base + 3] : 0;
    int tot = v0 + v1 + v2 + v3;
    s[t] = tot;
    __syncthreads();
    for (int off = 1; off < 256; off <<= 1) {
        int val = (t >= off) ? s[t - off] : 0;
        __syncthreads();
        s[t] += val;
        __syncthreads();
    }
    int pre = s[t] - tot;
    if (base + 0 < n) out[base + 0] = pre;
    if (base + 1 < n) out[base + 1] = pre + v0;
    if (base + 2 < n) out[base + 2] = pre + v0 + v1;
    if (base + 3 < n) out[base + 3] = pre + v0 + v1 + v2;
    if (t == 255) part[blockIdx.x] = s[255];
}

__global__ void scan2_kernel(int* part, int nb) {
    __shared__ int s[256];
    int t = threadIdx.x;
    int v = t < nb ? part[t] : 0;
    s[t] = v;
    __syncthreads();
    for (int off = 1; off < 256; off <<= 1) {
        int val = (t >= off) ? s[t - off] : 0;
        __syncthreads();
        s[t] += val;
        __syncthreads();
    }
    if (t < nb) part[t] = s[t] - v;  // exclusive
}

__global__ void scan3_kernel(int* __restrict__ out, const int* __restrict__ part, int n, int total) {
    int i = blockIdx.x * blockDim.x + threadIdx.x;
    if (i < n) out[i] += part[i >> 10];
    if (i == 0) out[n] = total;
}

__global__ void fill_kernel(const int* __restrict__ dst, const int* __restrict__ src,
                            const int* __restrict__ off, int* __restrict__ cnt,
                            int2* __restrict__ pair, int E) {
    int i = blockIdx.x * blockDim.x + threadIdx.x;
    if (i >= E) return;
    int d = dst[i];
    int old = atomicSub(&cnt[d], 1);
    pair[off[d] + old - 1] = make_int2(i, src[i]);
}

// ================= conv1 gather-aggregate (bf16 gathers, packed out) =================
__global__ __launch_bounds__(256) void agg1_kernel(
    const float* __restrict__ x, const unsigned* __restrict__ xb,
    const uint4* __restrict__ eab,
    const float* __restrict__ We, const float* __restrict__ be,
    const int* __restrict__ off, const int2* __restrict__ pair,
    unsigned* __restrict__ aggb, int N)
{
    int wave = (blockIdx.x * 256 + threadIdx.x) >> 6;
    if (wave >= N) return;
    int lane = threadIdx.x & 63;
    int fp = lane & 15, eg = lane >> 4;
    int j0 = fp * 2;
    float w0[F_EDGE], w1[F_EDGE];
#pragma unroll
    for (int k = 0; k < F_EDGE; ++k) {
        w0[k] = We[k * F_NODE + j0];
        w1[k] = We[k * F_NODE + j0 + 1];
    }
    float b0 = be[j0], b1 = be[j0 + 1];
    int i0 = __builtin_amdgcn_readfirstlane(off[wave]);
    int i1 = __builtin_amdgcn_readfirstlane(off[wave + 1]);
    float acc0 = 0.f, acc1 = 0.f;
    for (int i = i0; i < i1; i += 4) {
        int ii = i + eg;
        if (ii < i1) {
            int2 p = pair[ii];
            uint4 e = eab[p.x];
            unsigned u = xb[(size_t)p.y * 16 + fp];
            float m0 = b0 + bflo(u), m1 = b1 + bfhi(u);
            float c[8] = { bflo(e.x), bfhi(e.x), bflo(e.y), bfhi(e.y),
                           bflo(e.z), bfhi(e.z), bflo(e.w), bfhi(e.w) };
#pragma unroll
            for (int k = 0; k < F_EDGE; ++k) {
                m0 = fmaf(c[k], w0[k], m0);
                m1 = fmaf(c[k], w1[k], m1);
            }
            acc0 += fmaxf(m0, 0.f);
            acc1 += fmaxf(m1, 0.f);
        }
    }
    acc0 += __shfl_xor(acc0, 16, 64);
    acc0 += __shfl_xor(acc0, 32, 64);
    acc1 += __shfl_xor(acc1, 16, 64);
    acc1 += __shfl_xor(acc1, 32, 64);
    if (eg == 0) {
        float2 xo = *(const float2*)&x[(size_t)wave * F_NODE + j0];
        aggb[(size_t)wave * 16 + fp] = pack2(xo.x + acc0, xo.y + acc1);
    }
}

// ================= conv2 gather-aggregate (packed in/out) =================
__global__ __launch_bounds__(256) void agg2_kernel(
    const unsigned* __restrict__ hb,
    const uint4* __restrict__ eab,
    const float* __restrict__ We, const float* __restrict__ be,
    const int* __restrict__ off, const int2* __restrict__ pair,
    unsigned* __restrict__ aggb, int N)
{
    int wave = (blockIdx.x * 256 + threadIdx.x) >> 6;
    if (wave >= N) return;
    int lane = threadIdx.x & 63;
    int j0 = lane * 2;
    float w0[F_EDGE], w1[F_EDGE];
#pragma unroll
    for (int k = 0; k < F_EDGE; ++k) {
        w0[k] = We[k * HID + j0];
        w1[k] = We[k * HID + j0 + 1];
    }
    float b0 = be[j0], b1 = be[j0 + 1];
    int i0 = __builtin_amdgcn_readfirstlane(off[wave]);
    int i1 = __builtin_amdgcn_readfirstlane(off[wave + 1]);
    float acc0 = 0.f, acc1 = 0.f;
    int i = i0;
    for (; i + 1 < i1; i += 2) {
        int2 p0 = pair[i], p1 = pair[i + 1];
        uint4 eA = eab[p0.x];
        uint4 eB = eab[p1.x];
        unsigned uA = hb[(size_t)p0.y * 64 + lane];
        unsigned uB = hb[(size_t)p1.y * 64 + lane];
        float m0 = b0 + bflo(uA), m1 = b1 + bfhi(uA);
        float n0 = b0 + bflo(uB), n1 = b1 + bfhi(uB);
        float a[8] = { bflo(eA.x), bfhi(eA.x), bflo(eA.y), bfhi(eA.y),
                       bflo(eA.z), bfhi(eA.z), bflo(eA.w), bfhi(eA.w) };
        float d[8] = { bflo(eB.x), bfhi(eB.x), bflo(eB.y), bfhi(eB.y),
                       bflo(eB.z), bfhi(eB.z), bflo(eB.w), bfhi(eB.w) };
#pragma unroll
        for (int k = 0; k < F_EDGE; ++k) {
            m0 = fmaf(a[k], w0[k], m0);
            m1 = fmaf(a[k], w1[k], m1);
            n0 = fmaf(d[k], w0[k], n0);
            n1 = fmaf(d[k], w1[k], n1);
        }
        acc0 += fmaxf(m0, 0.f) + fmaxf(n0, 0.f);
        acc1 += fmaxf(m1, 0.f) + fmaxf(n1, 0.f);
    }
    if (i < i1) {
        int2 p0 = pair[i];
        uint4 eA = eab[p0.x];
        unsigned uA = hb[(size_t)p0.y * 64 + lane];
        float m0 = b0 + bflo(uA), m1 = b1 + bfhi(uA);
        float a[8] = { bflo(eA.x), bfhi(eA.x), bflo(eA.y), bfhi(eA.y),
                       bflo(eA.z), bfhi(eA.z), bflo(eA.w), bfhi(eA.w) };
#pragma unroll
        for (int k = 0; k < F_EDGE; ++k) {
            m0 = fmaf(a[k], w0[k], m0);
            m1 = fmaf(a[k], w1[k], m1);
        }
        acc0 += fmaxf(m0, 0.f);
        acc1 += fmaxf(m1, 0.f);
    }
    unsigned us = hb[(size_t)wave * 64 + lane];
    aggb[(size_t)wave * 64 + lane] = pack2(bflo(us) + acc0, bfhi(us) + acc1);
}

// ================= fused 2-layer node MLP via MFMA =================
// 32 rows/block, 256 threads = 4 waves. Wave w: row-block rb=w>>1, col-tiles
// cg=(w&1)*4 .. +4. mfma_f32_16x16x32_bf16: A row=lane&15, k=8*(lane>>4)+i;
// C col=lane&15, row=(lane>>4)*4+reg [m89].
__device__ __forceinline__ void put_tile_elu(short* t, f32x4 v, int rbase, int c, int stride) {
#pragma unroll
    for (int j = 0; j < 4; ++j)
        t[(rbase + j) * stride + c] = (short)bf16rne(elu_f(v[j]));
}

template <int K>
__global__ __launch_bounds__(256) void mlp_mfma_kernel(
    const uint4* __restrict__ inb,                       // [nrows][K/8] packed bf16
    const uint4* __restrict__ WaP, const float* __restrict__ ba,
    const uint4* __restrict__ WbP, const float* __restrict__ bb,
    uint4* __restrict__ outb, int nrows)                 // [nrows][16] packed bf16
{
    constexpr int KS_A = K / 32;
    constexpr int SA = K + 8;      // padded row stride (bf16): byte stride mult of 16, 2-way banks
    constexpr int ST = HID + 8;    // 136
    __shared__ __align__(16) short a_s[32 * SA];
    __shared__ __align__(16) short t_s[32 * ST];

    const int tid = threadIdx.x;
    const int row0 = blockIdx.x * 32;

    // stage packed input rows -> LDS bf16 [32][SA]
    constexpr int Q = K / 8;       // uint4 per row
    for (int idx = tid; idx < 32 * Q; idx += 256) {
        int r = idx / Q, q = idx % Q;
        uint4 v = make_uint4(0, 0, 0, 0);
        if (row0 + r < nrows) v = inb[(size_t)(row0 + r) * Q + q];
        *(uint4*)&a_s[r * SA + q * 8] = v;
    }
    __syncthreads();

    const int lane = tid & 63;
    const int w = tid >> 6;
    const int rb = w >> 1;
    const int cg = (w & 1) * 4;
    const int cf = lane & 15;
    const int g = lane >> 4;
    const int arow = rb * 16 + cf;

    // ---- layer A ----
    f32x4 acc0, acc1, acc2, acc3;
    {
        float c0 = ba[(cg + 0) * 16 + cf], c1 = ba[(cg + 1) * 16 + cf];
        float c2 = ba[(cg + 2) * 16 + cf], c3 = ba[(cg + 3) * 16 + cf];
        acc0 = (f32x4){c0, c0, c0, c0};
        acc1 = (f32x4){c1, c1, c1, c1};
        acc2 = (f32x4){c2, c2, c2, c2};
        acc3 = (f32x4){c3, c3, c3, c3};
    }
#pragma unroll
    for (int ks = 0; ks < KS_A; ++ks) {
        bf16x8 a = *(const bf16x8*)&a_s[arow * SA + ks * 32 + g * 8];
        acc0 = __builtin_amdgcn_mfma_f32_16x16x32_bf16(a, frag_from(WaP[((cg + 0) * KS_A + ks) * 64 + lane]), acc0, 0, 0, 0);
        acc1 = __builtin_amdgcn_mfma_f32_16x16x32_bf16(a, frag_from(WaP[((cg + 1) * KS_A + ks) * 64 + lane]), acc1, 0, 0, 0);
        acc2 = __builtin_amdgcn_mfma_f32_16x16x32_bf16(a, frag_from(WaP[((cg + 2) * KS_A + ks) * 64 + lane]), acc2, 0, 0, 0);
        acc3 = __builtin_amdgcn_mfma_f32_16x16x32_bf16(a, frag_from(WaP[((cg + 3) * KS_A + ks) * 64 + lane]), acc3, 0, 0, 0);
    }
    {
        int rbase = rb * 16 + g * 4;
        put_tile_elu(t_s, acc0, rbase, (cg + 0) * 16 + cf, ST);
        put_tile_elu(t_s, acc1, rbase, (cg + 1) * 16 + cf, ST);
        put_tile_elu(t_s, acc2, rbase, (cg + 2) * 16 + cf, ST);
        put_tile_elu(t_s, acc3, rbase, (cg + 3) * 16 + cf, ST);
    }
    __syncthreads();

    // ---- layer B (K = 128) ----
    {
        float c0 = bb[(cg + 0) * 16 + cf], c1 = bb[(cg + 1) * 16 + cf];
        float c2 = bb[(cg + 2) * 16 + cf], c3 = bb[(cg + 3) * 16 + cf];
        acc0 = (f32x4){c0, c0, c0, c0};
        acc1 = (f32x4){c1, c1, c1, c1};
        acc2 = (f32x4){c2, c2, c2, c2};
        acc3 = (f32x4){c3, c3, c3, c3};
    }
#pragma unroll
    for (int ks = 0; ks < 4; ++ks) {
        bf16x8 a = *(const bf16x8*)&t_s[arow * ST + ks * 32 + g * 8];
        acc0 = __builtin_amdgcn_mfma_f32_16x16x32_bf16(a, frag_from(WbP[((cg + 0) * 4 + ks) * 64 + lane]), acc0, 0, 0, 0);
        acc1 = __builtin_amdgcn_mfma_f32_16x16x32_bf16(a, frag_from(WbP[((cg + 1) * 4 + ks) * 64 + lane]), acc1, 0, 0, 0);
        acc2 = __builtin_amdgcn_mfma_f32_16x16x32_bf16(a, frag_from(WbP[((cg + 2) * 4 + ks) * 64 + lane]), acc2, 0, 0, 0);
        acc3 = __builtin_amdgcn_mfma_f32_16x16x32_bf16(a, frag_from(WbP[((cg + 3) * 4 + ks) * 64 + lane]), acc3, 0, 0, 0);
    }
    __syncthreads();   // all t_s reads done before overwrite
    {
        int rbase = rb * 16 + g * 4;
        put_tile_elu(t_s, acc0, rbase, (cg + 0) * 16 + cf, ST);
        put_tile_elu(t_s, acc1, rbase, (cg + 1) * 16 + cf, ST);
        put_tile_elu(t_s, acc2, rbase, (cg + 2) * 16 + cf, ST);
        put_tile_elu(t_s, acc3, rbase, (cg + 3) * 16 + cf, ST);
    }
    __syncthreads();

    // coalesced packed store: 32 rows x 16 uint4
    for (int idx = tid; idx < 32 * 16; idx += 256) {
        int r = idx >> 4, q = idx & 15;
        if (row0 + r < nrows)
            outb[(size_t)(row0 + r) * 16 + q] = *(const uint4*)&t_s[r * ST + q * 8];
    }
}

// ================= global add pool (run-length, batch sorted, packed in) ======
__global__ __launch_bounds__(64) void pool_kernel(
    const unsigned* __restrict__ hb, const int* __restrict__ batch,
    float* __restrict__ hg, int N)
{
    int base = blockIdx.x * 64;
    if (base >= N) return;
    int j = threadIdx.x;
    int end = base + 64 < N ? base + 64 : N;
    int cur = batch[base];
    float a0 = 0.f, a1 = 0.f;
    for (int n = base; n < end; ++n) {
        int b = batch[n];
        if (b != cur) {
            atomicAdd(&hg[(size_t)cur * HID + 2 * j], a0);
            atomicAdd(&hg[(size_t)cur * HID + 2 * j + 1], a1);
            a0 = a1 = 0.f;
            cur = b;
        }
        unsigned u = hb[(size_t)n * 64 + j];
        a0 += bflo(u);
        a1 += bfhi(u);
    }
    atomicAdd(&hg[(size_t)cur * HID + 2 * j], a0);
    atomicAdd(&hg[(size_t)cur * HID + 2 * j + 1], a1);
}

// ================= head =================
__global__ __launch_bounds__(128) void head_kernel(
    const float* __restrict__ hg, const float* __restrict__ Wl1, const float* __restrict__ bl1,
    const float* __restrict__ Wl2, const float* __restrict__ bl2, float* __restrict__ out)
{
    __shared__ float row_s[HID];
    __shared__ float t_s[HID];
    int g = blockIdx.x;
    int j = threadIdx.x;
    row_s[j] = hg[(size_t)g * HID + j];
    __syncthreads();
    float s = bl1[j];
#pragma unroll 4
    for (int k = 0; k < HID; ++k) s = fmaf(row_s[k], Wl1[k * HID + j], s);
    t_s[j] = fmaxf(s, 0.f);
    __syncthreads();
    if (j < 12) {
        float o = bl2[j];
#pragma unroll 4
        for (int k = 0; k < HID; ++k) o = fmaf(t_s[k], Wl2[k * 12 + j], o);
        out[(size_t)g * 12 + j] = o;
    }
}

extern "C" void kernel_launch(void* const* d_in, const int* in_sizes, int n_in,
                              void* d_out, int out_size, void* d_ws, size_t ws_size,
                              hipStream_t stream)
{
    const float* x    = (const float*)d_in[0];
    const int*   ei   = (const int*)d_in[1];
    const float* ea   = (const float*)d_in[2];
    const int*   batch = (const int*)d_in[3];
    const float* We1 = (const float*)d_in[4];
    const float* be1 = (const float*)d_in[5];
    const float* W1a = (const float*)d_in[6];
    const float* b1a = (const float*)d_in[7];
    const float* W1b = (const float*)d_in[8];
    const float* b1b = (const float*)d_in[9];
    const float* We2 = (const float*)d_in[10];
    const float* be2 = (const float*)d_in[11];
    const float* W2a = (const float*)d_in[12];
    const float* b2a = (const float*)d_in[13];
    const float* W2b = (const float*)d_in[14];
    const float* b2b = (const float*)d_in[15];
    const float* Wl1 = (const float*)d_in[16];
    const float* bl1 = (const float*)d_in[17];
    const float* Wl2 = (const float*)d_in[18];
    const float* bl2 = (const float*)d_in[19];
    float* out = (float*)d_out;

    const int N = in_sizes[0] / F_NODE;
    const int E = in_sizes[1] / 2;
    const int G = out_size / 12;

    const int* srcp = ei;
    const int* dstp = ei + E;

    // ---- workspace layout (16B aligned chunks) ----
    char* wsb = (char*)d_ws;
    auto alloc = [&](size_t bytes) -> char* {
        char* p = wsb;
        wsb += (bytes + 15) & ~(size_t)15;
        return p;
    };
    int* cnt   = (int*)alloc((size_t)N * 4);
    int* off   = (int*)alloc((size_t)(N + 1) * 4);
    int* part  = (int*)alloc(256 * 4);
    int2* pair = (int2*)alloc((size_t)E * 8);
    unsigned* xb   = (unsigned*)alloc((size_t)N * 16 * 4);
    unsigned* eab  = (unsigned*)alloc((size_t)E * 4 * 4);
    unsigned* agg1b = (unsigned*)alloc((size_t)N * 16 * 4);
    unsigned* h1b   = (unsigned*)alloc((size_t)N * 64 * 4);
    unsigned* agg2b = (unsigned*)alloc((size_t)N * 64 * 4);
    unsigned* h2b   = (unsigned*)alloc((size_t)N * 64 * 4);
    float* hg  = (float*)alloc((size_t)G * HID * 4);
    uint4* P1a = (uint4*)alloc(512 * 16);
    uint4* P1b = (uint4*)alloc(2048 * 16);
    uint4* P2a = (uint4*)alloc(2048 * 16);
    uint4* P2b = (uint4*)alloc(2048 * 16);

    // ---- prep: bf16 tables + packed weights + CSR build ----
    hipMemsetAsync(cnt, 0, (size_t)N * sizeof(int), stream);
    hipMemsetAsync(hg, 0, (size_t)G * HID * sizeof(float), stream);
    {
        int nx = N * 16, ne = E * 4;
        hipLaunchKernelGGL(cast_kernel, dim3((nx + ne + 255) / 256), dim3(256), 0, stream,
                           x, ea, xb, eab, nx, ne);
    }
    hipLaunchKernelGGL(wpack_kernel, dim3(26), dim3(256), 0, stream,
                       W1a, W1b, W2a, W2b, P1a, P1b, P2a, P2b);
    hipLaunchKernelGGL(hist_kernel, dim3((E + 255) / 256), dim3(256), 0, stream, dstp, cnt, E);
    int nscan = (N + 1023) / 1024;
    hipLaunchKernelGGL(scan1_kernel, dim3(nscan), dim3(256), 0, stream, cnt, off, part, N);
    hipLaunchKernelGGL(scan2_kernel, dim3(1), dim3(256), 0, stream, part, nscan);
    hipLaunchKernelGGL(scan3_kernel, dim3((N + 255) / 256), dim3(256), 0, stream, off, part, N, E);
    hipLaunchKernelGGL(fill_kernel, dim3((E + 255) / 256), dim3(256), 0, stream,
                       dstp, srcp, off, cnt, pair, E);

    // ---- conv1 ----
    hipLaunchKernelGGL(agg1_kernel, dim3((N + 3) / 4), dim3(256), 0, stream,
                       x, xb, (const uint4*)eab, We1, be1, off, pair, agg1b, N);
    hipLaunchKernelGGL((mlp_mfma_kernel<F_NODE>), dim3((N + 31) / 32), dim3(256), 0, stream,
                       (const uint4*)agg1b, P1a, b1a, P1b, b1b, (uint4*)h1b, N);

    // ---- conv2 ----
    hipLaunchKernelGGL(agg2_kernel, dim3((N + 3) / 4), dim3(256), 0, stream,
                       h1b, (const uint4*)eab, We2, be2, off, pair, agg2b, N);
    hipLaunchKernelGGL((mlp_mfma_kernel<HID>), dim3((N + 31) / 32), dim3(256), 0, stream,
                       (const uint4*)agg2b, P2a, b2a, P2b, b2b, (uint4*)h2b, N);

    // ---- pool + head ----
    hipLaunchKernelGGL(pool_kernel, dim3((N + 63) / 64), dim3(64), 0, stream,
                       h2b, batch, hg, N);
    hipLaunchKernelGGL(head_kernel, dim3(G), dim3(128), 0, stream,
                       hg, Wl1, bl1, Wl2, bl2, out);
}

// Round 8
// 473.198 us; speedup vs baseline: 3.7088x; 1.0489x over previous
//
#include <hip/hip_runtime.h>
#include <math.h>

#define F_NODE 32
#define F_EDGE 8
#define HID 128

typedef __attribute__((ext_vector_type(2))) _Float16 f16x2;
typedef __attribute__((ext_vector_type(8))) _Float16 f16x8;
typedef __attribute__((ext_vector_type(4))) float f32x4;

__device__ __forceinline__ float elu_f(float x) { return x > 0.f ? x : expf(x) - 1.f; }

__device__ __forceinline__ unsigned h2u(f16x2 h) { union { f16x2 h; unsigned u; } x; x.h = h; return x.u; }
__device__ __forceinline__ f16x2 u2h(unsigned u) { union { unsigned u; f16x2 h; } x; x.u = u; return x.h; }
__device__ __forceinline__ unsigned packh2(float lo, float hi) {
    f16x2 v; v.x = (_Float16)lo; v.y = (_Float16)hi; return h2u(v);
}
__device__ __forceinline__ unsigned short f2h_bits(float f) {
    _Float16 h = (_Float16)f; union { _Float16 h; unsigned short u; } x; x.h = h; return x.u;
}
__device__ __forceinline__ f16x8 frag_from(uint4 v) { union { uint4 u; f16x8 f; } x; x.u = v; return x.f; }

// ================= fused prep: cast x, dup-cast ea, pack weights, histogram =================
__global__ void prep_kernel(const float* __restrict__ x, const float* __restrict__ ea,
                            const int* __restrict__ dst,
                            unsigned* __restrict__ xh, unsigned* __restrict__ eadup,
                            const float* __restrict__ W1a, const float* __restrict__ W1b,
                            const float* __restrict__ W2a, const float* __restrict__ W2b,
                            uint4* __restrict__ P1a, uint4* __restrict__ P1b,
                            uint4* __restrict__ P2a, uint4* __restrict__ P2b,
                            int* __restrict__ cnt, int nx, int ne2, int E)
{
    int i = blockIdx.x * 256 + threadIdx.x;
    if (i < nx) {                       // x -> f16 pairs
        float2 v = ((const float2*)x)[i];
        xh[i] = packh2(v.x, v.y);
        return;
    }
    i -= nx;
    if (i < ne2) {                      // ea float2 -> two duplicated f16x2
        float2 v = ((const float2*)ea)[i];
        eadup[i * 2]     = packh2(v.x, v.x);
        eadup[i * 2 + 1] = packh2(v.y, v.y);
        return;
    }
    i -= ne2;
    if (i < 6656) {                     // weight pack (f16 B-fragments)
        const float* W; uint4* P; int KS; int f = i;
        if (f < 512)       { W = W1a; P = P1a; KS = 1; }
        else if (f < 2560) { W = W1b; P = P1b; KS = 4; f -= 512; }
        else if (f < 4608) { W = W2a; P = P2a; KS = 4; f -= 2560; }
        else               { W = W2b; P = P2b; KS = 4; f -= 4608; }
        int lane = f & 63;
        int rem = f >> 6;
        int ks = rem % KS, ct = rem / KS;
        int col = ct * 16 + (lane & 15);
        int k0 = ks * 32 + (lane >> 4) * 8;
        float w[8];
#pragma unroll
        for (int j = 0; j < 8; ++j) w[j] = W[(size_t)(k0 + j) * HID + col];
        uint4 v;
        v.x = packh2(w[0], w[1]);
        v.y = packh2(w[2], w[3]);
        v.z = packh2(w[4], w[5]);
        v.w = packh2(w[6], w[7]);
        P[f] = v;
        return;
    }
    i -= 6656;
    if (i < E) atomicAdd(&cnt[dst[i]], 1);
}

// ================= CSR build =================
__global__ void scan1_kernel(const int* __restrict__ in, int* __restrict__ out,
                             int* __restrict__ part, int n) {
    __shared__ int s[256];
    int t = threadIdx.x;
    int base = blockIdx.x * 1024 + t * 4;
    int v0 = base + 0 < n ? in[base + 0] : 0;
    int v1 = base + 1 < n ? in[base + 1] : 0;
    int v2 = base + 2 < n ? in[base + 2] : 0;
    int v3 = base + 3 < n ? in[base + 3] : 0;
    int tot = v0 + v1 + v2 + v3;
    s[t] = tot;
    __syncthreads();
    for (int off = 1; off < 256; off <<= 1) {
        int val = (t >= off) ? s[t - off] : 0;
        __syncthreads();
        s[t] += val;
        __syncthreads();
    }
    int pre = s[t] - tot;
    if (base + 0 < n) out[base + 0] = pre;
    if (base + 1 < n) out[base + 1] = pre + v0;
    if (base + 2 < n) out[base + 2] = pre + v0 + v1;
    if (base + 3 < n) out[base + 3] = pre + v0 + v1 + v2;
    if (t == 255) part[blockIdx.x] = s[255];
}

__global__ void scan2_kernel(int* part, int nb) {
    __shared__ int s[256];
    int t = threadIdx.x;
    int v = t < nb ? part[t] : 0;
    s[t] = v;
    __syncthreads();
    for (int off = 1; off < 256; off <<= 1) {
        int val = (t >= off) ? s[t - off] : 0;
        __syncthreads();
        s[t] += val;
        __syncthreads();
    }
    if (t < nb) part[t] = s[t] - v;  // exclusive
}

__global__ void scan3_kernel(int* __restrict__ out, const int* __restrict__ part, int n, int total) {
    int i = blockIdx.x * blockDim.x + threadIdx.x;
    if (i < n) out[i] += part[i >> 10];
    if (i == 0) out[n] = total;
}

__global__ void fill_kernel(const int* __restrict__ dst, const int* __restrict__ src,
                            const int* __restrict__ off, int* __restrict__ cnt,
                            int2* __restrict__ pair, int E) {
    int i = blockIdx.x * blockDim.x + threadIdx.x;
    if (i >= E) return;
    int d = dst[i];
    int old = atomicSub(&cnt[d], 1);
    pair[off[d] + old - 1] = make_int2(i, src[i]);
}

// ================= conv1 gather-aggregate (f16 packed math) =================
// one wave per node; lane = fp (0..15 feature pair) + eg (0..3 edge group)
__global__ __launch_bounds__(256) void agg1_kernel(
    const float* __restrict__ x, const unsigned* __restrict__ xh,
    const unsigned* __restrict__ eadup,
    const float* __restrict__ We, const float* __restrict__ be,
    const int* __restrict__ off, const int2* __restrict__ pair,
    unsigned* __restrict__ aggh, int N)
{
    int wave = (blockIdx.x * 256 + threadIdx.x) >> 6;
    if (wave >= N) return;
    int lane = threadIdx.x & 63;
    int fp = lane & 15, eg = lane >> 4;
    int j0 = fp * 2;
    f16x2 w2[F_EDGE];
#pragma unroll
    for (int k = 0; k < F_EDGE; ++k)
        w2[k] = u2h(packh2(We[k * F_NODE + j0], We[k * F_NODE + j0 + 1]));
    f16x2 bias2 = u2h(packh2(be[j0], be[j0 + 1]));
    f16x2 zero2 = u2h(0u);
    int i0 = __builtin_amdgcn_readfirstlane(off[wave]);
    int i1 = __builtin_amdgcn_readfirstlane(off[wave + 1]);
    float acc0 = 0.f, acc1 = 0.f;
    for (int i = i0; i < i1; i += 4) {
        int ii = i + eg;
        if (ii < i1) {
            int2 p = pair[ii];
            const unsigned* ep = eadup + (size_t)p.x * 8;
            f16x2 m = bias2 + u2h(xh[(size_t)p.y * 16 + fp]);
#pragma unroll
            for (int k = 0; k < F_EDGE; ++k)
                m = u2h(ep[k]) * w2[k] + m;
            m = __builtin_elementwise_max(m, zero2);
            acc0 += (float)m.x;
            acc1 += (float)m.y;
        }
    }
    acc0 += __shfl_xor(acc0, 16, 64);
    acc0 += __shfl_xor(acc0, 32, 64);
    acc1 += __shfl_xor(acc1, 16, 64);
    acc1 += __shfl_xor(acc1, 32, 64);
    if (eg == 0) {
        float2 xo = *(const float2*)&x[(size_t)wave * F_NODE + j0];
        aggh[(size_t)wave * 16 + fp] = packh2(xo.x + acc0, xo.y + acc1);
    }
}

// ================= conv2 gather-aggregate (f16 packed math) =================
__global__ __launch_bounds__(256) void agg2_kernel(
    const unsigned* __restrict__ hh,
    const unsigned* __restrict__ eadup,
    const float* __restrict__ We, const float* __restrict__ be,
    const int* __restrict__ off, const int2* __restrict__ pair,
    unsigned* __restrict__ aggh, int N)
{
    int wave = (blockIdx.x * 256 + threadIdx.x) >> 6;
    if (wave >= N) return;
    int lane = threadIdx.x & 63;
    int j0 = lane * 2;
    f16x2 w2[F_EDGE];
#pragma unroll
    for (int k = 0; k < F_EDGE; ++k)
        w2[k] = u2h(packh2(We[k * HID + j0], We[k * HID + j0 + 1]));
    f16x2 bias2 = u2h(packh2(be[j0], be[j0 + 1]));
    f16x2 zero2 = u2h(0u);
    int i0 = __builtin_amdgcn_readfirstlane(off[wave]);
    int i1 = __builtin_amdgcn_readfirstlane(off[wave + 1]);
    float acc0 = 0.f, acc1 = 0.f;
    int i = i0;
    for (; i + 1 < i1; i += 2) {
        int2 p0 = pair[i], p1 = pair[i + 1];
        const unsigned* eA = eadup + (size_t)p0.x * 8;
        const unsigned* eB = eadup + (size_t)p1.x * 8;
        f16x2 mA = bias2 + u2h(hh[(size_t)p0.y * 64 + lane]);
        f16x2 mB = bias2 + u2h(hh[(size_t)p1.y * 64 + lane]);
#pragma unroll
        for (int k = 0; k < F_EDGE; ++k) {
            mA = u2h(eA[k]) * w2[k] + mA;
            mB = u2h(eB[k]) * w2[k] + mB;
        }
        f16x2 s = __builtin_elementwise_max(mA, zero2) + __builtin_elementwise_max(mB, zero2);
        acc0 += (float)s.x;
        acc1 += (float)s.y;
    }
    if (i < i1) {
        int2 p0 = pair[i];
        const unsigned* eA = eadup + (size_t)p0.x * 8;
        f16x2 mA = bias2 + u2h(hh[(size_t)p0.y * 64 + lane]);
#pragma unroll
        for (int k = 0; k < F_EDGE; ++k)
            mA = u2h(eA[k]) * w2[k] + mA;
        mA = __builtin_elementwise_max(mA, zero2);
        acc0 += (float)mA.x;
        acc1 += (float)mA.y;
    }
    f16x2 self = u2h(hh[(size_t)wave * 64 + lane]);
    aggh[(size_t)wave * 64 + lane] = packh2((float)self.x + acc0, (float)self.y + acc1);
}

// ================= fused 2-layer node MLP via f16 MFMA =================
// 32 rows/block, 256 threads = 4 waves. Wave w: row-block rb=w>>1, col-tiles
// cg=(w&1)*4. A frag: row=lane&15, k=8*(lane>>4)+i. C: col=lane&15, row=(lane>>4)*4+reg.
__device__ __forceinline__ void put_tile_elu_h(unsigned short* t, f32x4 v, int rbase, int c, int stride) {
#pragma unroll
    for (int j = 0; j < 4; ++j)
        t[(rbase + j) * stride + c] = f2h_bits(elu_f(v[j]));
}

template <int K, bool POOL>
__global__ __launch_bounds__(256) void mlp_mfma_kernel(
    const uint4* __restrict__ inb,                       // [nrows][K/8] packed f16
    const uint4* __restrict__ WaP, const float* __restrict__ ba,
    const uint4* __restrict__ WbP, const float* __restrict__ bb,
    uint4* __restrict__ outb,                            // !POOL: [nrows][16] packed f16
    const int* __restrict__ batch, float* __restrict__ hg,  // POOL
    int nrows)
{
    constexpr int KS_A = K / 32;
    constexpr int SA = K + 8;
    constexpr int ST = HID + 8;    // 136
    constexpr int STF = HID + 4;   // 132
    __shared__ __align__(16) unsigned short a_s[32 * SA];
    __shared__ __align__(16) unsigned short t_s[32 * ST];
    __shared__ float p_s[POOL ? 32 * STF : 1];
    __shared__ int batch_s[POOL ? 32 : 1];

    const int tid = threadIdx.x;
    const int row0 = blockIdx.x * 32;

    constexpr int Q = K / 8;       // uint4 per row
    for (int idx = tid; idx < 32 * Q; idx += 256) {
        int r = idx / Q, q = idx % Q;
        uint4 v = make_uint4(0, 0, 0, 0);
        if (row0 + r < nrows) v = inb[(size_t)(row0 + r) * Q + q];
        *(uint4*)&a_s[r * SA + q * 8] = v;
    }
    if (POOL && tid < 32)
        batch_s[tid] = (row0 + tid < nrows) ? batch[row0 + tid] : -1;
    __syncthreads();

    const int lane = tid & 63;
    const int w = tid >> 6;
    const int rb = w >> 1;
    const int cg = (w & 1) * 4;
    const int cf = lane & 15;
    const int g = lane >> 4;
    const int arow = rb * 16 + cf;

    // ---- layer A ----
    f32x4 acc0, acc1, acc2, acc3;
    {
        float c0 = ba[(cg + 0) * 16 + cf], c1 = ba[(cg + 1) * 16 + cf];
        float c2 = ba[(cg + 2) * 16 + cf], c3 = ba[(cg + 3) * 16 + cf];
        acc0 = (f32x4){c0, c0, c0, c0};
        acc1 = (f32x4){c1, c1, c1, c1};
        acc2 = (f32x4){c2, c2, c2, c2};
        acc3 = (f32x4){c3, c3, c3, c3};
    }
#pragma unroll
    for (int ks = 0; ks < KS_A; ++ks) {
        f16x8 a = *(const f16x8*)&a_s[arow * SA + ks * 32 + g * 8];
        acc0 = __builtin_amdgcn_mfma_f32_16x16x32_f16(a, frag_from(WaP[((cg + 0) * KS_A + ks) * 64 + lane]), acc0, 0, 0, 0);
        acc1 = __builtin_amdgcn_mfma_f32_16x16x32_f16(a, frag_from(WaP[((cg + 1) * KS_A + ks) * 64 + lane]), acc1, 0, 0, 0);
        acc2 = __builtin_amdgcn_mfma_f32_16x16x32_f16(a, frag_from(WaP[((cg + 2) * KS_A + ks) * 64 + lane]), acc2, 0, 0, 0);
        acc3 = __builtin_amdgcn_mfma_f32_16x16x32_f16(a, frag_from(WaP[((cg + 3) * KS_A + ks) * 64 + lane]), acc3, 0, 0, 0);
    }
    {
        int rbase = rb * 16 + g * 4;
        put_tile_elu_h(t_s, acc0, rbase, (cg + 0) * 16 + cf, ST);
        put_tile_elu_h(t_s, acc1, rbase, (cg + 1) * 16 + cf, ST);
        put_tile_elu_h(t_s, acc2, rbase, (cg + 2) * 16 + cf, ST);
        put_tile_elu_h(t_s, acc3, rbase, (cg + 3) * 16 + cf, ST);
    }
    __syncthreads();

    // ---- layer B (K = 128) ----
    {
        float c0 = bb[(cg + 0) * 16 + cf], c1 = bb[(cg + 1) * 16 + cf];
        float c2 = bb[(cg + 2) * 16 + cf], c3 = bb[(cg + 3) * 16 + cf];
        acc0 = (f32x4){c0, c0, c0, c0};
        acc1 = (f32x4){c1, c1, c1, c1};
        acc2 = (f32x4){c2, c2, c2, c2};
        acc3 = (f32x4){c3, c3, c3, c3};
    }
#pragma unroll
    for (int ks = 0; ks < 4; ++ks) {
        f16x8 a = *(const f16x8*)&t_s[arow * ST + ks * 32 + g * 8];
        acc0 = __builtin_amdgcn_mfma_f32_16x16x32_f16(a, frag_from(WbP[((cg + 0) * 4 + ks) * 64 + lane]), acc0, 0, 0, 0);
        acc1 = __builtin_amdgcn_mfma_f32_16x16x32_f16(a, frag_from(WbP[((cg + 1) * 4 + ks) * 64 + lane]), acc1, 0, 0, 0);
        acc2 = __builtin_amdgcn_mfma_f32_16x16x32_f16(a, frag_from(WbP[((cg + 2) * 4 + ks) * 64 + lane]), acc2, 0, 0, 0);
        acc3 = __builtin_amdgcn_mfma_f32_16x16x32_f16(a, frag_from(WbP[((cg + 3) * 4 + ks) * 64 + lane]), acc3, 0, 0, 0);
    }

    if (POOL) {
        // write f32 elu'd outputs to p_s, then run-length pool into hg
        int rbase = rb * 16 + g * 4;
#pragma unroll
        for (int j = 0; j < 4; ++j) {
            p_s[(rbase + j) * STF + (cg + 0) * 16 + cf] = elu_f(acc0[j]);
            p_s[(rbase + j) * STF + (cg + 1) * 16 + cf] = elu_f(acc1[j]);
            p_s[(rbase + j) * STF + (cg + 2) * 16 + cf] = elu_f(acc2[j]);
            p_s[(rbase + j) * STF + (cg + 3) * 16 + cf] = elu_f(acc3[j]);
        }
        __syncthreads();
        int f = tid & 127, grp = tid >> 7;
        float acc = 0.f;
        int cur = -1;
#pragma unroll 4
        for (int r = 0; r < 16; ++r) {
            int rr = grp * 16 + r;
            int b = batch_s[rr];
            if (b >= 0) {
                if (b != cur) {
                    if (cur >= 0) atomicAdd(&hg[(size_t)cur * HID + f], acc);
                    acc = 0.f;
                    cur = b;
                }
                acc += p_s[rr * STF + f];
            }
        }
        if (cur >= 0) atomicAdd(&hg[(size_t)cur * HID + f], acc);
    } else {
        __syncthreads();   // all t_s reads done before overwrite
        int rbase = rb * 16 + g * 4;
        put_tile_elu_h(t_s, acc0, rbase, (cg + 0) * 16 + cf, ST);
        put_tile_elu_h(t_s, acc1, rbase, (cg + 1) * 16 + cf, ST);
        put_tile_elu_h(t_s, acc2, rbase, (cg + 2) * 16 + cf, ST);
        put_tile_elu_h(t_s, acc3, rbase, (cg + 3) * 16 + cf, ST);
        __syncthreads();
        for (int idx = tid; idx < 32 * 16; idx += 256) {
            int r = idx >> 4, q = idx & 15;
            if (row0 + r < nrows)
                outb[(size_t)(row0 + r) * 16 + q] = *(const uint4*)&t_s[r * ST + q * 8];
        }
    }
}

// ================= head =================
__global__ __launch_bounds__(128) void head_kernel(
    const float* __restrict__ hg, const float* __restrict__ Wl1, const float* __restrict__ bl1,
    const float* __restrict__ Wl2, const float* __restrict__ bl2, float* __restrict__ out)
{
    __shared__ float row_s[HID];
    __shared__ float t_s[HID];
    int g = blockIdx.x;
    int j = threadIdx.x;
    row_s[j] = hg[(size_t)g * HID + j];
    __syncthreads();
    float s = bl1[j];
#pragma unroll 4
    for (int k = 0; k < HID; ++k) s = fmaf(row_s[k], Wl1[k * HID + j], s);
    t_s[j] = fmaxf(s, 0.f);
    __syncthreads();
    if (j < 12) {
        float o = bl2[j];
#pragma unroll 4
        for (int k = 0; k < HID; ++k) o = fmaf(t_s[k], Wl2[k * 12 + j], o);
        out[(size_t)g * 12 + j] = o;
    }
}

extern "C" void kernel_launch(void* const* d_in, const int* in_sizes, int n_in,
                              void* d_out, int out_size, void* d_ws, size_t ws_size,
                              hipStream_t stream)
{
    const float* x    = (const float*)d_in[0];
    const int*   ei   = (const int*)d_in[1];
    const float* ea   = (const float*)d_in[2];
    const int*   batch = (const int*)d_in[3];
    const float* We1 = (const float*)d_in[4];
    const float* be1 = (const float*)d_in[5];
    const float* W1a = (const float*)d_in[6];
    const float* b1a = (const float*)d_in[7];
    const float* W1b = (const float*)d_in[8];
    const float* b1b = (const float*)d_in[9];
    const float* We2 = (const float*)d_in[10];
    const float* be2 = (const float*)d_in[11];
    const float* W2a = (const float*)d_in[12];
    const float* b2a = (const float*)d_in[13];
    const float* W2b = (const float*)d_in[14];
    const float* b2b = (const float*)d_in[15];
    const float* Wl1 = (const float*)d_in[16];
    const float* bl1 = (const float*)d_in[17];
    const float* Wl2 = (const float*)d_in[18];
    const float* bl2 = (const float*)d_in[19];
    float* out = (float*)d_out;

    const int N = in_sizes[0] / F_NODE;
    const int E = in_sizes[1] / 2;
    const int G = out_size / 12;

    const int* srcp = ei;
    const int* dstp = ei + E;

    // ---- workspace layout ----
    char* wsb = (char*)d_ws;
    auto alloc = [&](size_t bytes) -> char* {
        char* p = wsb;
        wsb += (bytes + 15) & ~(size_t)15;
        return p;
    };
    int* cnt   = (int*)alloc((size_t)N * 4);
    int* off   = (int*)alloc((size_t)(N + 1) * 4);
    int* part  = (int*)alloc(256 * 4);
    int2* pair = (int2*)alloc((size_t)E * 8);
    unsigned* xh    = (unsigned*)alloc((size_t)N * 16 * 4);
    unsigned* eadup = (unsigned*)alloc((size_t)E * 8 * 4);
    unsigned* agg1h = (unsigned*)alloc((size_t)N * 16 * 4);
    unsigned* h1h   = (unsigned*)alloc((size_t)N * 64 * 4);
    unsigned* agg2h = (unsigned*)alloc((size_t)N * 64 * 4);
    float* hg  = (float*)alloc((size_t)G * HID * 4);
    uint4* P1a = (uint4*)alloc(512 * 16);
    uint4* P1b = (uint4*)alloc(2048 * 16);
    uint4* P2a = (uint4*)alloc(2048 * 16);
    uint4* P2b = (uint4*)alloc(2048 * 16);

    (void)hipMemsetAsync(cnt, 0, (size_t)N * sizeof(int), stream);
    (void)hipMemsetAsync(hg, 0, (size_t)G * HID * sizeof(float), stream);

    // ---- fused prep: cast + wpack + hist ----
    {
        int nx = N * 16, ne2 = E * 4;
        long long total = (long long)nx + ne2 + 6656 + E;
        hipLaunchKernelGGL(prep_kernel, dim3((unsigned)((total + 255) / 256)), dim3(256), 0, stream,
                           x, ea, dstp, xh, eadup, W1a, W1b, W2a, W2b,
                           P1a, P1b, P2a, P2b, cnt, nx, ne2, E);
    }
    int nscan = (N + 1023) / 1024;
    hipLaunchKernelGGL(scan1_kernel, dim3(nscan), dim3(256), 0, stream, cnt, off, part, N);
    hipLaunchKernelGGL(scan2_kernel, dim3(1), dim3(256), 0, stream, part, nscan);
    hipLaunchKernelGGL(scan3_kernel, dim3((N + 255) / 256), dim3(256), 0, stream, off, part, N, E);
    hipLaunchKernelGGL(fill_kernel, dim3((E + 255) / 256), dim3(256), 0, stream,
                       dstp, srcp, off, cnt, pair, E);

    // ---- conv1 ----
    hipLaunchKernelGGL(agg1_kernel, dim3((N + 3) / 4), dim3(256), 0, stream,
                       x, xh, eadup, We1, be1, off, pair, agg1h, N);
    hipLaunchKernelGGL((mlp_mfma_kernel<F_NODE, false>), dim3((N + 31) / 32), dim3(256), 0, stream,
                       (const uint4*)agg1h, P1a, b1a, P1b, b1b, (uint4*)h1h,
                       (const int*)nullptr, (float*)nullptr, N);

    // ---- conv2 ----
    hipLaunchKernelGGL(agg2_kernel, dim3((N + 3) / 4), dim3(256), 0, stream,
                       h1h, eadup, We2, be2, off, pair, agg2h, N);
    // mlp2 with fused global-add-pool epilogue (h2 never hits HBM)
    hipLaunchKernelGGL((mlp_mfma_kernel<HID, true>), dim3((N + 31) / 32), dim3(256), 0, stream,
                       (const uint4*)agg2h, P2a, b2a, P2b, b2b, (uint4*)nullptr,
                       batch, hg, N);

    // ---- head ----
    hipLaunchKernelGGL(head_kernel, dim3(G), dim3(128), 0, stream,
                       hg, Wl1, bl1, Wl2, bl2, out);
}

// Round 9
// 428.794 us; speedup vs baseline: 4.0929x; 1.1036x over previous
//
#include <hip/hip_runtime.h>
#include <math.h>

#define F_NODE 32
#define F_EDGE 8
#define HID 128

typedef __attribute__((ext_vector_type(2))) _Float16 f16x2;
typedef __attribute__((ext_vector_type(8))) _Float16 f16x8;
typedef __attribute__((ext_vector_type(4))) float f32x4;

__device__ __forceinline__ float elu_f(float x) { return x > 0.f ? x : expf(x) - 1.f; }

__device__ __forceinline__ unsigned h2u(f16x2 h) { union { f16x2 h; unsigned u; } x; x.h = h; return x.u; }
__device__ __forceinline__ f16x2 u2h(unsigned u) { union { unsigned u; f16x2 h; } x; x.u = u; return x.h; }
__device__ __forceinline__ unsigned packh2(float lo, float hi) {
    f16x2 v; v.x = (_Float16)lo; v.y = (_Float16)hi; return h2u(v);
}
__device__ __forceinline__ unsigned short f2h_bits(float f) {
    _Float16 h = (_Float16)f; union { _Float16 h; unsigned short u; } x; x.h = h; return x.u;
}
__device__ __forceinline__ f16x8 frag_from(uint4 v) { union { uint4 u; f16x8 f; } x; x.u = v; return x.f; }
__device__ __forceinline__ f16x2 duph(f16x8 v, int k) { f16x2 d; d.x = v[k]; d.y = v[k]; return d; }

// ================= fused prep: cast x, cast ea, pack weights, histogram =================
__global__ void prep_kernel(const float* __restrict__ x, const float* __restrict__ ea,
                            const int* __restrict__ dst,
                            unsigned* __restrict__ xh, unsigned* __restrict__ eab,
                            const float* __restrict__ W1a, const float* __restrict__ W1b,
                            const float* __restrict__ W2a, const float* __restrict__ W2b,
                            const float* __restrict__ Wl1, const float* __restrict__ Wl2,
                            uint4* __restrict__ P1a, uint4* __restrict__ P1b,
                            uint4* __restrict__ P2a, uint4* __restrict__ P2b,
                            uint4* __restrict__ P3a, uint4* __restrict__ P3b,
                            int* __restrict__ cnt, int nx, int ne2, int E)
{
    int i = blockIdx.x * 256 + threadIdx.x;
    if (i < nx) {                       // x -> f16 pairs
        float2 v = ((const float2*)x)[i];
        xh[i] = packh2(v.x, v.y);
        return;
    }
    i -= nx;
    if (i < ne2) {                      // ea float2 -> one f16 pair (16B/edge total)
        float2 v = ((const float2*)ea)[i];
        eab[i] = packh2(v.x, v.y);
        return;
    }
    i -= ne2;
    if (i < 8960) {                     // weight pack (f16 B-fragments)
        int f = i;
        if (f >= 8704) {                // P3b: Wl2 [128][12] -> 16 cols padded
            f -= 8704;                  // 256 entries: KS=4, CT=1
            int lane = f & 63;
            int ks = f >> 6;
            int col = lane & 15;
            int k0 = ks * 32 + (lane >> 4) * 8;
            float w[8];
#pragma unroll
            for (int j = 0; j < 8; ++j) w[j] = col < 12 ? Wl2[(size_t)(k0 + j) * 12 + col] : 0.f;
            uint4 v;
            v.x = packh2(w[0], w[1]);
            v.y = packh2(w[2], w[3]);
            v.z = packh2(w[4], w[5]);
            v.w = packh2(w[6], w[7]);
            P3b[f] = v;
            return;
        }
        const float* W; uint4* P; int KS;
        if (f < 512)       { W = W1a; P = P1a; KS = 1; }
        else if (f < 2560) { W = W1b; P = P1b; KS = 4; f -= 512; }
        else if (f < 4608) { W = W2a; P = P2a; KS = 4; f -= 2560; }
        else if (f < 6656) { W = W2b; P = P2b; KS = 4; f -= 4608; }
        else               { W = Wl1; P = P3a; KS = 4; f -= 6656; }
        int lane = f & 63;
        int rem = f >> 6;
        int ks = rem % KS, ct = rem / KS;
        int col = ct * 16 + (lane & 15);
        int k0 = ks * 32 + (lane >> 4) * 8;
        float w[8];
#pragma unroll
        for (int j = 0; j < 8; ++j) w[j] = W[(size_t)(k0 + j) * HID + col];
        uint4 v;
        v.x = packh2(w[0], w[1]);
        v.y = packh2(w[2], w[3]);
        v.z = packh2(w[4], w[5]);
        v.w = packh2(w[6], w[7]);
        P[f] = v;
        return;
    }
    i -= 8960;
    if (i < E) atomicAdd(&cnt[dst[i]], 1);
}

// ================= CSR build =================
__global__ void scan1_kernel(const int* __restrict__ in, int* __restrict__ out,
                             int* __restrict__ part, int n) {
    __shared__ int s[256];
    int t = threadIdx.x;
    int base = blockIdx.x * 1024 + t * 4;
    int v0 = base + 0 < n ? in[base + 0] : 0;
    int v1 = base + 1 < n ? in[base + 1] : 0;
    int v2 = base + 2 < n ? in[base + 2] : 0;
    int v3 = base + 3 < n ? in[base + 3] : 0;
    int tot = v0 + v1 + v2 + v3;
    s[t] = tot;
    __syncthreads();
    for (int off = 1; off < 256; off <<= 1) {
        int val = (t >= off) ? s[t - off] : 0;
        __syncthreads();
        s[t] += val;
        __syncthreads();
    }
    int pre = s[t] - tot;
    if (base + 0 < n) out[base + 0] = pre;
    if (base + 1 < n) out[base + 1] = pre + v0;
    if (base + 2 < n) out[base + 2] = pre + v0 + v1;
    if (base + 3 < n) out[base + 3] = pre + v0 + v1 + v2;
    if (t == 255) part[blockIdx.x] = s[255];
}

__global__ void scan2_kernel(int* part, int nb) {
    __shared__ int s[256];
    int t = threadIdx.x;
    int v = t < nb ? part[t] : 0;
    s[t] = v;
    __syncthreads();
    for (int off = 1; off < 256; off <<= 1) {
        int val = (t >= off) ? s[t - off] : 0;
        __syncthreads();
        s[t] += val;
        __syncthreads();
    }
    if (t < nb) part[t] = s[t] - v;  // exclusive
}

__global__ void scan3_kernel(int* __restrict__ out, const int* __restrict__ part, int n, int total) {
    int i = blockIdx.x * blockDim.x + threadIdx.x;
    if (i < n) out[i] += part[i >> 10];
    if (i == 0) out[n] = total;
}

__global__ void fill_kernel(const int* __restrict__ dst, const int* __restrict__ src,
                            const int* __restrict__ off, int* __restrict__ cnt,
                            int2* __restrict__ pair, int E) {
    int i = blockIdx.x * blockDim.x + threadIdx.x;
    if (i >= E) return;
    int d = dst[i];
    int old = atomicSub(&cnt[d], 1);
    pair[off[d] + old - 1] = make_int2(i, src[i]);
}

// ================= conv1 gather-aggregate =================
// one wave per node; lane = fp (0..15 feature pair) + eg (0..3 edge group)
__global__ __launch_bounds__(256) void agg1_kernel(
    const float* __restrict__ x, const unsigned* __restrict__ xh,
    const uint4* __restrict__ eab4,
    const float* __restrict__ We, const float* __restrict__ be,
    const int* __restrict__ off, const int2* __restrict__ pair,
    unsigned* __restrict__ aggh, int N)
{
    int wave = (blockIdx.x * 256 + threadIdx.x) >> 6;
    if (wave >= N) return;
    int lane = threadIdx.x & 63;
    int fp = lane & 15, eg = lane >> 4;
    int j0 = fp * 2;
    f16x2 w2[F_EDGE];
#pragma unroll
    for (int k = 0; k < F_EDGE; ++k)
        w2[k] = u2h(packh2(We[k * F_NODE + j0], We[k * F_NODE + j0 + 1]));
    f16x2 bias2 = u2h(packh2(be[j0], be[j0 + 1]));
    f16x2 zero2 = u2h(0u);
    int i0 = __builtin_amdgcn_readfirstlane(off[wave]);
    int i1 = __builtin_amdgcn_readfirstlane(off[wave + 1]);
    float acc0 = 0.f, acc1 = 0.f;
    for (int i = i0; i < i1; i += 4) {
        int ii = i + eg;
        if (ii < i1) {
            int2 p = pair[ii];
            f16x8 ev = frag_from(eab4[p.x]);
            f16x2 m = bias2 + u2h(xh[(size_t)p.y * 16 + fp]);
#pragma unroll
            for (int k = 0; k < F_EDGE; ++k)
                m = duph(ev, k) * w2[k] + m;
            m = __builtin_elementwise_max(m, zero2);
            acc0 += (float)m.x;
            acc1 += (float)m.y;
        }
    }
    acc0 += __shfl_xor(acc0, 16, 64);
    acc0 += __shfl_xor(acc0, 32, 64);
    acc1 += __shfl_xor(acc1, 16, 64);
    acc1 += __shfl_xor(acc1, 32, 64);
    if (eg == 0) {
        float2 xo = *(const float2*)&x[(size_t)wave * F_NODE + j0];
        aggh[(size_t)wave * 16 + fp] = packh2(xo.x + acc0, xo.y + acc1);
    }
}

// ================= conv2 gather-aggregate (unroll 4, 4 gathers in flight) =====
__global__ __launch_bounds__(256) void agg2_kernel(
    const unsigned* __restrict__ hh,
    const uint4* __restrict__ eab4,
    const float* __restrict__ We, const float* __restrict__ be,
    const int* __restrict__ off, const int2* __restrict__ pair,
    unsigned* __restrict__ aggh, int N)
{
    int wave = (blockIdx.x * 256 + threadIdx.x) >> 6;
    if (wave >= N) return;
    int lane = threadIdx.x & 63;
    int j0 = lane * 2;
    f16x2 w2[F_EDGE];
#pragma unroll
    for (int k = 0; k < F_EDGE; ++k)
        w2[k] = u2h(packh2(We[k * HID + j0], We[k * HID + j0 + 1]));
    f16x2 bias2 = u2h(packh2(be[j0], be[j0 + 1]));
    f16x2 zero2 = u2h(0u);
    int i0 = __builtin_amdgcn_readfirstlane(off[wave]);
    int i1 = __builtin_amdgcn_readfirstlane(off[wave + 1]);
    float acc0 = 0.f, acc1 = 0.f;
    int i = i0;
    for (; i + 3 < i1; i += 4) {
        int2 p0 = pair[i], p1 = pair[i + 1], p2 = pair[i + 2], p3 = pair[i + 3];
        unsigned u0 = hh[(size_t)p0.y * 64 + lane];
        unsigned u1 = hh[(size_t)p1.y * 64 + lane];
        unsigned u2 = hh[(size_t)p2.y * 64 + lane];
        unsigned u3 = hh[(size_t)p3.y * 64 + lane];
        f16x8 e0 = frag_from(eab4[p0.x]);
        f16x8 e1 = frag_from(eab4[p1.x]);
        f16x8 e2 = frag_from(eab4[p2.x]);
        f16x8 e3 = frag_from(eab4[p3.x]);
        f16x2 m0 = bias2 + u2h(u0);
        f16x2 m1 = bias2 + u2h(u1);
        f16x2 m2 = bias2 + u2h(u2);
        f16x2 m3 = bias2 + u2h(u3);
#pragma unroll
        for (int k = 0; k < F_EDGE; ++k) {
            m0 = duph(e0, k) * w2[k] + m0;
            m1 = duph(e1, k) * w2[k] + m1;
            m2 = duph(e2, k) * w2[k] + m2;
            m3 = duph(e3, k) * w2[k] + m3;
        }
        f16x2 s01 = __builtin_elementwise_max(m0, zero2) + __builtin_elementwise_max(m1, zero2);
        f16x2 s23 = __builtin_elementwise_max(m2, zero2) + __builtin_elementwise_max(m3, zero2);
        acc0 += (float)s01.x + (float)s23.x;
        acc1 += (float)s01.y + (float)s23.y;
    }
    for (; i < i1; ++i) {
        int2 p0 = pair[i];
        f16x8 e0 = frag_from(eab4[p0.x]);
        f16x2 m0 = bias2 + u2h(hh[(size_t)p0.y * 64 + lane]);
#pragma unroll
        for (int k = 0; k < F_EDGE; ++k)
            m0 = duph(e0, k) * w2[k] + m0;
        m0 = __builtin_elementwise_max(m0, zero2);
        acc0 += (float)m0.x;
        acc1 += (float)m0.y;
    }
    f16x2 self = u2h(hh[(size_t)wave * 64 + lane]);
    aggh[(size_t)wave * 64 + lane] = packh2((float)self.x + acc0, (float)self.y + acc1);
}

// ================= fused 2-layer node MLP via f16 MFMA =================
__device__ __forceinline__ void put_tile_elu_h(unsigned short* t, f32x4 v, int rbase, int c, int stride) {
#pragma unroll
    for (int j = 0; j < 4; ++j)
        t[(rbase + j) * stride + c] = f2h_bits(elu_f(v[j]));
}
__device__ __forceinline__ void put_tile_relu_h(unsigned short* t, f32x4 v, int rbase, int c, int stride) {
#pragma unroll
    for (int j = 0; j < 4; ++j)
        t[(rbase + j) * stride + c] = f2h_bits(fmaxf(v[j], 0.f));
}

template <int K, bool POOL>
__global__ __launch_bounds__(256) void mlp_mfma_kernel(
    const uint4* __restrict__ inb,                       // [nrows][K/8] packed f16
    const uint4* __restrict__ WaP, const float* __restrict__ ba,
    const uint4* __restrict__ WbP, const float* __restrict__ bb,
    uint4* __restrict__ outb,                            // !POOL: [nrows][16] packed f16
    const int* __restrict__ batch, float* __restrict__ hg,  // POOL
    int nrows)
{
    constexpr int KS_A = K / 32;
    constexpr int SA = K + 8;
    constexpr int ST = HID + 8;    // 136
    constexpr int STF = HID + 4;   // 132
    __shared__ __align__(16) unsigned short a_s[32 * SA];
    __shared__ __align__(16) unsigned short t_s[32 * ST];
    __shared__ float p_s[POOL ? 32 * STF : 1];
    __shared__ int batch_s[POOL ? 32 : 1];

    const int tid = threadIdx.x;
    const int row0 = blockIdx.x * 32;

    constexpr int Q = K / 8;       // uint4 per row
    for (int idx = tid; idx < 32 * Q; idx += 256) {
        int r = idx / Q, q = idx % Q;
        uint4 v = make_uint4(0, 0, 0, 0);
        if (row0 + r < nrows) v = inb[(size_t)(row0 + r) * Q + q];
        *(uint4*)&a_s[r * SA + q * 8] = v;
    }
    if (POOL && tid < 32)
        batch_s[tid] = (row0 + tid < nrows) ? batch[row0 + tid] : -1;
    __syncthreads();

    const int lane = tid & 63;
    const int w = tid >> 6;
    const int rb = w >> 1;
    const int cg = (w & 1) * 4;
    const int cf = lane & 15;
    const int g = lane >> 4;
    const int arow = rb * 16 + cf;

    // ---- layer A ----
    f32x4 acc0, acc1, acc2, acc3;
    {
        float c0 = ba[(cg + 0) * 16 + cf], c1 = ba[(cg + 1) * 16 + cf];
        float c2 = ba[(cg + 2) * 16 + cf], c3 = ba[(cg + 3) * 16 + cf];
        acc0 = (f32x4){c0, c0, c0, c0};
        acc1 = (f32x4){c1, c1, c1, c1};
        acc2 = (f32x4){c2, c2, c2, c2};
        acc3 = (f32x4){c3, c3, c3, c3};
    }
#pragma unroll
    for (int ks = 0; ks < KS_A; ++ks) {
        f16x8 a = *(const f16x8*)&a_s[arow * SA + ks * 32 + g * 8];
        acc0 = __builtin_amdgcn_mfma_f32_16x16x32_f16(a, frag_from(WaP[((cg + 0) * KS_A + ks) * 64 + lane]), acc0, 0, 0, 0);
        acc1 = __builtin_amdgcn_mfma_f32_16x16x32_f16(a, frag_from(WaP[((cg + 1) * KS_A + ks) * 64 + lane]), acc1, 0, 0, 0);
        acc2 = __builtin_amdgcn_mfma_f32_16x16x32_f16(a, frag_from(WaP[((cg + 2) * KS_A + ks) * 64 + lane]), acc2, 0, 0, 0);
        acc3 = __builtin_amdgcn_mfma_f32_16x16x32_f16(a, frag_from(WaP[((cg + 3) * KS_A + ks) * 64 + lane]), acc3, 0, 0, 0);
    }
    {
        int rbase = rb * 16 + g * 4;
        put_tile_elu_h(t_s, acc0, rbase, (cg + 0) * 16 + cf, ST);
        put_tile_elu_h(t_s, acc1, rbase, (cg + 1) * 16 + cf, ST);
        put_tile_elu_h(t_s, acc2, rbase, (cg + 2) * 16 + cf, ST);
        put_tile_elu_h(t_s, acc3, rbase, (cg + 3) * 16 + cf, ST);
    }
    __syncthreads();

    // ---- layer B (K = 128) ----
    {
        float c0 = bb[(cg + 0) * 16 + cf], c1 = bb[(cg + 1) * 16 + cf];
        float c2 = bb[(cg + 2) * 16 + cf], c3 = bb[(cg + 3) * 16 + cf];
        acc0 = (f32x4){c0, c0, c0, c0};
        acc1 = (f32x4){c1, c1, c1, c1};
        acc2 = (f32x4){c2, c2, c2, c2};
        acc3 = (f32x4){c3, c3, c3, c3};
    }
#pragma unroll
    for (int ks = 0; ks < 4; ++ks) {
        f16x8 a = *(const f16x8*)&t_s[arow * ST + ks * 32 + g * 8];
        acc0 = __builtin_amdgcn_mfma_f32_16x16x32_f16(a, frag_from(WbP[((cg + 0) * 4 + ks) * 64 + lane]), acc0, 0, 0, 0);
        acc1 = __builtin_amdgcn_mfma_f32_16x16x32_f16(a, frag_from(WbP[((cg + 1) * 4 + ks) * 64 + lane]), acc1, 0, 0, 0);
        acc2 = __builtin_amdgcn_mfma_f32_16x16x32_f16(a, frag_from(WbP[((cg + 2) * 4 + ks) * 64 + lane]), acc2, 0, 0, 0);
        acc3 = __builtin_amdgcn_mfma_f32_16x16x32_f16(a, frag_from(WbP[((cg + 3) * 4 + ks) * 64 + lane]), acc3, 0, 0, 0);
    }

    if (POOL) {
        int rbase = rb * 16 + g * 4;
#pragma unroll
        for (int j = 0; j < 4; ++j) {
            p_s[(rbase + j) * STF + (cg + 0) * 16 + cf] = elu_f(acc0[j]);
            p_s[(rbase + j) * STF + (cg + 1) * 16 + cf] = elu_f(acc1[j]);
            p_s[(rbase + j) * STF + (cg + 2) * 16 + cf] = elu_f(acc2[j]);
            p_s[(rbase + j) * STF + (cg + 3) * 16 + cf] = elu_f(acc3[j]);
        }
        __syncthreads();
        int f = tid & 127, grp = tid >> 7;
        float acc = 0.f;
        int cur = -1;
#pragma unroll 4
        for (int r = 0; r < 16; ++r) {
            int rr = grp * 16 + r;
            int b = batch_s[rr];
            if (b >= 0) {
                if (b != cur) {
                    if (cur >= 0) atomicAdd(&hg[(size_t)cur * HID + f], acc);
                    acc = 0.f;
                    cur = b;
                }
                acc += p_s[rr * STF + f];
            }
        }
        if (cur >= 0) atomicAdd(&hg[(size_t)cur * HID + f], acc);
    } else {
        __syncthreads();   // all t_s reads done before overwrite
        int rbase = rb * 16 + g * 4;
        put_tile_elu_h(t_s, acc0, rbase, (cg + 0) * 16 + cf, ST);
        put_tile_elu_h(t_s, acc1, rbase, (cg + 1) * 16 + cf, ST);
        put_tile_elu_h(t_s, acc2, rbase, (cg + 2) * 16 + cf, ST);
        put_tile_elu_h(t_s, acc3, rbase, (cg + 3) * 16 + cf, ST);
        __syncthreads();
        for (int idx = tid; idx < 32 * 16; idx += 256) {
            int r = idx >> 4, q = idx & 15;
            if (row0 + r < nrows)
                outb[(size_t)(row0 + r) * 16 + q] = *(const uint4*)&t_s[r * ST + q * 8];
        }
    }
}

// ================= head via MFMA: relu(hg@Wl1+bl1)@Wl2+bl2 =================
__global__ __launch_bounds__(256) void head_mfma_kernel(
    const float* __restrict__ hg,
    const uint4* __restrict__ Wl1P, const float* __restrict__ bl1,
    const uint4* __restrict__ Wl2P, const float* __restrict__ bl2,
    float* __restrict__ out, int G)
{
    constexpr int ST = HID + 8;
    __shared__ __align__(16) unsigned short a_s[32 * ST];
    __shared__ __align__(16) unsigned short t_s[32 * ST];

    const int tid = threadIdx.x;
    const int row0 = blockIdx.x * 32;

    for (int idx = tid; idx < 32 * HID; idx += 256) {
        int r = idx >> 7, c = idx & 127;
        float v = (row0 + r < G) ? hg[(size_t)(row0 + r) * HID + c] : 0.f;
        a_s[r * ST + c] = f2h_bits(v);
    }
    __syncthreads();

    const int lane = tid & 63;
    const int w = tid >> 6;
    const int rb = w >> 1;
    const int cg = (w & 1) * 4;
    const int cf = lane & 15;
    const int g = lane >> 4;
    const int arow = rb * 16 + cf;

    // layer 1: [32x128] @ [128x128] + bl1, relu
    f32x4 acc0, acc1, acc2, acc3;
    {
        float c0 = bl1[(cg + 0) * 16 + cf], c1 = bl1[(cg + 1) * 16 + cf];
        float c2 = bl1[(cg + 2) * 16 + cf], c3 = bl1[(cg + 3) * 16 + cf];
        acc0 = (f32x4){c0, c0, c0, c0};
        acc1 = (f32x4){c1, c1, c1, c1};
        acc2 = (f32x4){c2, c2, c2, c2};
        acc3 = (f32x4){c3, c3, c3, c3};
    }
#pragma unroll
    for (int ks = 0; ks < 4; ++ks) {
        f16x8 a = *(const f16x8*)&a_s[arow * ST + ks * 32 + g * 8];
        acc0 = __builtin_amdgcn_mfma_f32_16x16x32_f16(a, frag_from(Wl1P[((cg + 0) * 4 + ks) * 64 + lane]), acc0, 0, 0, 0);
        acc1 = __builtin_amdgcn_mfma_f32_16x16x32_f16(a, frag_from(Wl1P[((cg + 1) * 4 + ks) * 64 + lane]), acc1, 0, 0, 0);
        acc2 = __builtin_amdgcn_mfma_f32_16x16x32_f16(a, frag_from(Wl1P[((cg + 2) * 4 + ks) * 64 + lane]), acc2, 0, 0, 0);
        acc3 = __builtin_amdgcn_mfma_f32_16x16x32_f16(a, frag_from(Wl1P[((cg + 3) * 4 + ks) * 64 + lane]), acc3, 0, 0, 0);
    }
    {
        int rbase = rb * 16 + g * 4;
        put_tile_relu_h(t_s, acc0, rbase, (cg + 0) * 16 + cf, ST);
        put_tile_relu_h(t_s, acc1, rbase, (cg + 1) * 16 + cf, ST);
        put_tile_relu_h(t_s, acc2, rbase, (cg + 2) * 16 + cf, ST);
        put_tile_relu_h(t_s, acc3, rbase, (cg + 3) * 16 + cf, ST);
    }
    __syncthreads();

    // layer 2: [32x128] @ [128x16(12)] + bl2 -> out (waves with cg==0 only)
    if ((w & 1) == 0) {
        float c0 = cf < 12 ? bl2[cf] : 0.f;
        f32x4 acc = (f32x4){c0, c0, c0, c0};
#pragma unroll
        for (int ks = 0; ks < 4; ++ks) {
            f16x8 a = *(const f16x8*)&t_s[arow * ST + ks * 32 + g * 8];
            acc = __builtin_amdgcn_mfma_f32_16x16x32_f16(a, frag_from(Wl2P[ks * 64 + lane]), acc, 0, 0, 0);
        }
        if (cf < 12) {
            int rbase = rb * 16 + g * 4;
#pragma unroll
            for (int j = 0; j < 4; ++j) {
                int row = row0 + rbase + j;
                if (row < G) out[(size_t)row * 12 + cf] = acc[j];
            }
        }
    }
}

extern "C" void kernel_launch(void* const* d_in, const int* in_sizes, int n_in,
                              void* d_out, int out_size, void* d_ws, size_t ws_size,
                              hipStream_t stream)
{
    const float* x    = (const float*)d_in[0];
    const int*   ei   = (const int*)d_in[1];
    const float* ea   = (const float*)d_in[2];
    const int*   batch = (const int*)d_in[3];
    const float* We1 = (const float*)d_in[4];
    const float* be1 = (const float*)d_in[5];
    const float* W1a = (const float*)d_in[6];
    const float* b1a = (const float*)d_in[7];
    const float* W1b = (const float*)d_in[8];
    const float* b1b = (const float*)d_in[9];
    const float* We2 = (const float*)d_in[10];
    const float* be2 = (const float*)d_in[11];
    const float* W2a = (const float*)d_in[12];
    const float* b2a = (const float*)d_in[13];
    const float* W2b = (const float*)d_in[14];
    const float* b2b = (const float*)d_in[15];
    const float* Wl1 = (const float*)d_in[16];
    const float* bl1 = (const float*)d_in[17];
    const float* Wl2 = (const float*)d_in[18];
    const float* bl2 = (const float*)d_in[19];
    float* out = (float*)d_out;

    const int N = in_sizes[0] / F_NODE;
    const int E = in_sizes[1] / 2;
    const int G = out_size / 12;

    const int* srcp = ei;
    const int* dstp = ei + E;

    // ---- workspace layout ----
    char* wsb = (char*)d_ws;
    auto alloc = [&](size_t bytes) -> char* {
        char* p = wsb;
        wsb += (bytes + 15) & ~(size_t)15;
        return p;
    };
    int* cnt   = (int*)alloc((size_t)N * 4);
    int* off   = (int*)alloc((size_t)(N + 1) * 4);
    int* part  = (int*)alloc(256 * 4);
    int2* pair = (int2*)alloc((size_t)E * 8);
    unsigned* xh   = (unsigned*)alloc((size_t)N * 16 * 4);
    unsigned* eab  = (unsigned*)alloc((size_t)E * 4 * 4);
    unsigned* agg1h = (unsigned*)alloc((size_t)N * 16 * 4);
    unsigned* h1h   = (unsigned*)alloc((size_t)N * 64 * 4);
    unsigned* agg2h = (unsigned*)alloc((size_t)N * 64 * 4);
    float* hg  = (float*)alloc((size_t)G * HID * 4);
    uint4* P1a = (uint4*)alloc(512 * 16);
    uint4* P1b = (uint4*)alloc(2048 * 16);
    uint4* P2a = (uint4*)alloc(2048 * 16);
    uint4* P2b = (uint4*)alloc(2048 * 16);
    uint4* P3a = (uint4*)alloc(2048 * 16);
    uint4* P3b = (uint4*)alloc(256 * 16);

    (void)hipMemsetAsync(cnt, 0, (size_t)N * sizeof(int), stream);
    (void)hipMemsetAsync(hg, 0, (size_t)G * HID * sizeof(float), stream);

    // ---- fused prep: cast + wpack + hist ----
    {
        int nx = N * 16, ne2 = E * 4;
        long long total = (long long)nx + ne2 + 8960 + E;
        hipLaunchKernelGGL(prep_kernel, dim3((unsigned)((total + 255) / 256)), dim3(256), 0, stream,
                           x, ea, dstp, xh, eab, W1a, W1b, W2a, W2b, Wl1, Wl2,
                           P1a, P1b, P2a, P2b, P3a, P3b, cnt, nx, ne2, E);
    }
    int nscan = (N + 1023) / 1024;
    hipLaunchKernelGGL(scan1_kernel, dim3(nscan), dim3(256), 0, stream, cnt, off, part, N);
    hipLaunchKernelGGL(scan2_kernel, dim3(1), dim3(256), 0, stream, part, nscan);
    hipLaunchKernelGGL(scan3_kernel, dim3((N + 255) / 256), dim3(256), 0, stream, off, part, N, E);
    hipLaunchKernelGGL(fill_kernel, dim3((E + 255) / 256), dim3(256), 0, stream,
                       dstp, srcp, off, cnt, pair, E);

    // ---- conv1 ----
    hipLaunchKernelGGL(agg1_kernel, dim3((N + 3) / 4), dim3(256), 0, stream,
                       x, xh, (const uint4*)eab, We1, be1, off, pair, agg1h, N);
    hipLaunchKernelGGL((mlp_mfma_kernel<F_NODE, false>), dim3((N + 31) / 32), dim3(256), 0, stream,
                       (const uint4*)agg1h, P1a, b1a, P1b, b1b, (uint4*)h1h,
                       (const int*)nullptr, (float*)nullptr, N);

    // ---- conv2 ----
    hipLaunchKernelGGL(agg2_kernel, dim3((N + 3) / 4), dim3(256), 0, stream,
                       h1h, (const uint4*)eab, We2, be2, off, pair, agg2h, N);
    hipLaunchKernelGGL((mlp_mfma_kernel<HID, true>), dim3((N + 31) / 32), dim3(256), 0, stream,
                       (const uint4*)agg2h, P2a, b2a, P2b, b2b, (uint4*)nullptr,
                       batch, hg, N);

    // ---- head (MFMA) ----
    hipLaunchKernelGGL(head_mfma_kernel, dim3((G + 31) / 32), dim3(256), 0, stream,
                       hg, P3a, bl1, P3b, bl2, out, G);
}

// Round 10
// 375.253 us; speedup vs baseline: 4.6769x; 1.1427x over previous
//
#include <hip/hip_runtime.h>
#include <math.h>

#define F_NODE 32
#define F_EDGE 8
#define HID 128
#define CAPB 6144      // pass-B LDS stage capacity (edges); bucket mean=4096, 32 sigma margin

typedef __attribute__((ext_vector_type(2))) _Float16 f16x2;
typedef __attribute__((ext_vector_type(8))) _Float16 f16x8;
typedef __attribute__((ext_vector_type(4))) float f32x4;

__device__ __forceinline__ float elu_f(float x) { return x > 0.f ? x : expf(x) - 1.f; }

__device__ __forceinline__ unsigned h2u(f16x2 h) { union { f16x2 h; unsigned u; } x; x.h = h; return x.u; }
__device__ __forceinline__ f16x2 u2h(unsigned u) { union { unsigned u; f16x2 h; } x; x.u = u; return x.h; }
__device__ __forceinline__ unsigned packh2(float lo, float hi) {
    f16x2 v; v.x = (_Float16)lo; v.y = (_Float16)hi; return h2u(v);
}
__device__ __forceinline__ unsigned short f2h_bits(float f) {
    _Float16 h = (_Float16)f; union { _Float16 h; unsigned short u; } x; x.h = h; return x.u;
}
__device__ __forceinline__ f16x8 frag_from(uint4 v) { union { uint4 u; f16x8 f; } x; x.u = v; return x.f; }
__device__ __forceinline__ f16x2 duph(f16x8 v, int k) { f16x2 d; d.x = v[k]; d.y = v[k]; return d; }

// ================= fused prep: cast x, cast ea, pack weights, histogram =================
__global__ void prep_kernel(const float* __restrict__ x, const float* __restrict__ ea,
                            const int* __restrict__ dst,
                            unsigned* __restrict__ xh, unsigned* __restrict__ eab,
                            const float* __restrict__ W1a, const float* __restrict__ W1b,
                            const float* __restrict__ W2a, const float* __restrict__ W2b,
                            const float* __restrict__ Wl1, const float* __restrict__ Wl2,
                            uint4* __restrict__ P1a, uint4* __restrict__ P1b,
                            uint4* __restrict__ P2a, uint4* __restrict__ P2b,
                            uint4* __restrict__ P3a, uint4* __restrict__ P3b,
                            int* __restrict__ cnt, int nx, int ne2, int E)
{
    int i = blockIdx.x * 256 + threadIdx.x;
    if (i < nx) {                       // x -> f16 pairs
        float2 v = ((const float2*)x)[i];
        xh[i] = packh2(v.x, v.y);
        return;
    }
    i -= nx;
    if (i < ne2) {                      // ea float2 -> one f16 pair
        float2 v = ((const float2*)ea)[i];
        eab[i] = packh2(v.x, v.y);
        return;
    }
    i -= ne2;
    if (i < 8960) {                     // weight pack (f16 B-fragments)
        int f = i;
        if (f >= 8704) {                // P3b: Wl2 [128][12] -> 16 cols padded
            f -= 8704;
            int lane = f & 63;
            int ks = f >> 6;
            int col = lane & 15;
            int k0 = ks * 32 + (lane >> 4) * 8;
            float w[8];
#pragma unroll
            for (int j = 0; j < 8; ++j) w[j] = col < 12 ? Wl2[(size_t)(k0 + j) * 12 + col] : 0.f;
            uint4 v;
            v.x = packh2(w[0], w[1]);
            v.y = packh2(w[2], w[3]);
            v.z = packh2(w[4], w[5]);
            v.w = packh2(w[6], w[7]);
            P3b[f] = v;
            return;
        }
        const float* W; uint4* P; int KS;
        if (f < 512)       { W = W1a; P = P1a; KS = 1; }
        else if (f < 2560) { W = W1b; P = P1b; KS = 4; f -= 512; }
        else if (f < 4608) { W = W2a; P = P2a; KS = 4; f -= 2560; }
        else if (f < 6656) { W = W2b; P = P2b; KS = 4; f -= 4608; }
        else               { W = Wl1; P = P3a; KS = 4; f -= 6656; }
        int lane = f & 63;
        int rem = f >> 6;
        int ks = rem % KS, ct = rem / KS;
        int col = ct * 16 + (lane & 15);
        int k0 = ks * 32 + (lane >> 4) * 8;
        float w[8];
#pragma unroll
        for (int j = 0; j < 8; ++j) w[j] = W[(size_t)(k0 + j) * HID + col];
        uint4 v;
        v.x = packh2(w[0], w[1]);
        v.y = packh2(w[2], w[3]);
        v.z = packh2(w[4], w[5]);
        v.w = packh2(w[6], w[7]);
        P[f] = v;
        return;
    }
    i -= 8960;
    if (i < E) atomicAdd(&cnt[dst[i]], 1);
}

// ================= CSR build: scans =================
__global__ void scan1_kernel(const int* __restrict__ in, int* __restrict__ out,
                             int* __restrict__ part, int n) {
    __shared__ int s[256];
    int t = threadIdx.x;
    int base = blockIdx.x * 1024 + t * 4;
    int v0 = base + 0 < n ? in[base + 0] : 0;
    int v1 = base + 1 < n ? in[base + 1] : 0;
    int v2 = base + 2 < n ? in[base + 2] : 0;
    int v3 = base + 3 < n ? in[base + 3] : 0;
    int tot = v0 + v1 + v2 + v3;
    s[t] = tot;
    __syncthreads();
    for (int off = 1; off < 256; off <<= 1) {
        int val = (t >= off) ? s[t - off] : 0;
        __syncthreads();
        s[t] += val;
        __syncthreads();
    }
    int pre = s[t] - tot;
    if (base + 0 < n) out[base + 0] = pre;
    if (base + 1 < n) out[base + 1] = pre + v0;
    if (base + 2 < n) out[base + 2] = pre + v0 + v1;
    if (base + 3 < n) out[base + 3] = pre + v0 + v1 + v2;
    if (t == 255) part[blockIdx.x] = s[255];
}

__global__ void scan2_kernel(int* part, int nb) {
    __shared__ int s[256];
    int t = threadIdx.x;
    int v = t < nb ? part[t] : 0;
    s[t] = v;
    __syncthreads();
    for (int off = 1; off < 256; off <<= 1) {
        int val = (t >= off) ? s[t - off] : 0;
        __syncthreads();
        s[t] += val;
        __syncthreads();
    }
    if (t < nb) part[t] = s[t] - v;  // exclusive
}

// finalize off; also seed coarse bucket cursors (curB) and fine cursors (curFine)
__global__ void scan3_kernel(int* __restrict__ out, const int* __restrict__ part,
                             int* __restrict__ curB, int* __restrict__ curFine,
                             int n, int total) {
    int i = blockIdx.x * blockDim.x + threadIdx.x;
    if (i < n) {
        int v = out[i] + part[i >> 10];
        out[i] = v;
        curFine[i] = v;
        if ((i & 255) == 0) curB[i >> 8] = v;
    }
    if (i == 0) out[n] = total;
}

// ================= pass A: coarse bin into 256-node buckets =================
// record: (e | dloc<<22, src) ; dloc = dst & 255, bucket = dst >> 8
__global__ __launch_bounds__(256) void binA_kernel(
    const int* __restrict__ dst, const int* __restrict__ src,
    int* __restrict__ curB, int2* __restrict__ tmp, int E, int NB)
{
    __shared__ int hist[512];
    __shared__ int basev[512];
    const int tid = threadIdx.x;
    const int base = blockIdx.x * 4096;
    for (int i = tid; i < NB; i += 256) hist[i] = 0;
    __syncthreads();
    int d[16];
#pragma unroll
    for (int k = 0; k < 16; ++k) {
        int e = base + k * 256 + tid;
        d[k] = (e < E) ? dst[e] : -1;
        if (d[k] >= 0) atomicAdd(&hist[d[k] >> 8], 1);
    }
    __syncthreads();
    for (int i = tid; i < NB; i += 256) {
        int c = hist[i];
        basev[i] = c > 0 ? atomicAdd(&curB[i], c) : 0;
        hist[i] = 0;
    }
    __syncthreads();
#pragma unroll
    for (int k = 0; k < 16; ++k) {
        int e = base + k * 256 + tid;
        if (d[k] >= 0) {
            int b = d[k] >> 8;
            int r = atomicAdd(&hist[b], 1);
            tmp[basev[b] + r] = make_int2(e | ((d[k] & 255) << 22), src[e]);
        }
    }
}

// ================= pass B: fine sort within bucket via LDS, coalesced writeout =================
__global__ __launch_bounds__(256) void binB_kernel(
    const int2* __restrict__ tmp, const int* __restrict__ off,
    int* __restrict__ curFine, int2* __restrict__ pair, int N)
{
    __shared__ int ldsCur[256];
    __shared__ int2 stage[CAPB];   // 48 KB
    const int b = blockIdx.x;
    const int tid = threadIdx.x;
    const int node0 = b << 8;
    const int nend = min(node0 + 256, N);
    const int base = off[node0];
    const int end = off[nend];
    const int S = end - base;
    if (S <= CAPB) {
        int node = node0 + tid;
        ldsCur[tid] = (node < nend ? off[node] : end) - base;
        __syncthreads();
        for (int j = tid; j < S; j += 256) {
            int2 rec = tmp[base + j];
            int dloc = ((unsigned)rec.x) >> 22;
            int slot = atomicAdd(&ldsCur[dloc], 1);
            stage[slot] = make_int2(rec.x & 0x3FFFFF, rec.y);
        }
        __syncthreads();
        for (int j = tid; j < S; j += 256)
            pair[base + j] = stage[j];
    } else {                       // overflow fallback (statistically never)
        for (int j = tid; j < S; j += 256) {
            int2 rec = tmp[base + j];
            int dloc = ((unsigned)rec.x) >> 22;
            int pos = atomicAdd(&curFine[node0 + dloc], 1);
            pair[pos] = make_int2(rec.x & 0x3FFFFF, rec.y);
        }
    }
}

// ================= conv1 gather-aggregate =================
__global__ __launch_bounds__(256) void agg1_kernel(
    const float* __restrict__ x, const unsigned* __restrict__ xh,
    const uint4* __restrict__ eab4,
    const float* __restrict__ We, const float* __restrict__ be,
    const int* __restrict__ off, const int2* __restrict__ pair,
    unsigned* __restrict__ aggh, int N)
{
    int wave = (blockIdx.x * 256 + threadIdx.x) >> 6;
    if (wave >= N) return;
    int lane = threadIdx.x & 63;
    int fp = lane & 15, eg = lane >> 4;
    int j0 = fp * 2;
    f16x2 w2[F_EDGE];
#pragma unroll
    for (int k = 0; k < F_EDGE; ++k)
        w2[k] = u2h(packh2(We[k * F_NODE + j0], We[k * F_NODE + j0 + 1]));
    f16x2 bias2 = u2h(packh2(be[j0], be[j0 + 1]));
    f16x2 zero2 = u2h(0u);
    int i0 = __builtin_amdgcn_readfirstlane(off[wave]);
    int i1 = __builtin_amdgcn_readfirstlane(off[wave + 1]);
    float acc0 = 0.f, acc1 = 0.f;
    for (int i = i0; i < i1; i += 4) {
        int ii = i + eg;
        if (ii < i1) {
            int2 p = pair[ii];
            f16x8 ev = frag_from(eab4[p.x]);
            f16x2 m = bias2 + u2h(xh[(size_t)p.y * 16 + fp]);
#pragma unroll
            for (int k = 0; k < F_EDGE; ++k)
                m = duph(ev, k) * w2[k] + m;
            m = __builtin_elementwise_max(m, zero2);
            acc0 += (float)m.x;
            acc1 += (float)m.y;
        }
    }
    acc0 += __shfl_xor(acc0, 16, 64);
    acc0 += __shfl_xor(acc0, 32, 64);
    acc1 += __shfl_xor(acc1, 16, 64);
    acc1 += __shfl_xor(acc1, 32, 64);
    if (eg == 0) {
        float2 xo = *(const float2*)&x[(size_t)wave * F_NODE + j0];
        aggh[(size_t)wave * 16 + fp] = packh2(xo.x + acc0, xo.y + acc1);
    }
}

// ================= conv2 gather-aggregate (unroll 8) =================
__global__ __launch_bounds__(256) void agg2_kernel(
    const unsigned* __restrict__ hh,
    const uint4* __restrict__ eab4,
    const float* __restrict__ We, const float* __restrict__ be,
    const int* __restrict__ off, const int2* __restrict__ pair,
    unsigned* __restrict__ aggh, int N)
{
    int wave = (blockIdx.x * 256 + threadIdx.x) >> 6;
    if (wave >= N) return;
    int lane = threadIdx.x & 63;
    int j0 = lane * 2;
    f16x2 w2[F_EDGE];
#pragma unroll
    for (int k = 0; k < F_EDGE; ++k)
        w2[k] = u2h(packh2(We[k * HID + j0], We[k * HID + j0 + 1]));
    f16x2 bias2 = u2h(packh2(be[j0], be[j0 + 1]));
    f16x2 zero2 = u2h(0u);
    int i0 = __builtin_amdgcn_readfirstlane(off[wave]);
    int i1 = __builtin_amdgcn_readfirstlane(off[wave + 1]);
    float acc0 = 0.f, acc1 = 0.f;
    int i = i0;
    for (; i + 7 < i1; i += 8) {
        int2 p[8];
        unsigned u[8];
        f16x8 ev[8];
#pragma unroll
        for (int k = 0; k < 8; ++k) p[k] = pair[i + k];
#pragma unroll
        for (int k = 0; k < 8; ++k) u[k] = hh[(size_t)p[k].y * 64 + lane];
#pragma unroll
        for (int k = 0; k < 8; ++k) ev[k] = frag_from(eab4[p[k].x]);
        f16x2 m[8];
#pragma unroll
        for (int k = 0; k < 8; ++k) m[k] = bias2 + u2h(u[k]);
#pragma unroll
        for (int kk = 0; kk < F_EDGE; ++kk) {
#pragma unroll
            for (int k = 0; k < 8; ++k)
                m[k] = duph(ev[k], kk) * w2[kk] + m[k];
        }
        f16x2 s = __builtin_elementwise_max(m[0], zero2);
#pragma unroll
        for (int k = 1; k < 8; ++k) s = s + __builtin_elementwise_max(m[k], zero2);
        acc0 += (float)s.x;
        acc1 += (float)s.y;
    }
    for (; i < i1; ++i) {
        int2 p0 = pair[i];
        f16x8 e0 = frag_from(eab4[p0.x]);
        f16x2 m0 = bias2 + u2h(hh[(size_t)p0.y * 64 + lane]);
#pragma unroll
        for (int k = 0; k < F_EDGE; ++k)
            m0 = duph(e0, k) * w2[k] + m0;
        m0 = __builtin_elementwise_max(m0, zero2);
        acc0 += (float)m0.x;
        acc1 += (float)m0.y;
    }
    f16x2 self = u2h(hh[(size_t)wave * 64 + lane]);
    aggh[(size_t)wave * 64 + lane] = packh2((float)self.x + acc0, (float)self.y + acc1);
}

// ================= fused 2-layer node MLP via f16 MFMA =================
__device__ __forceinline__ void put_tile_elu_h(unsigned short* t, f32x4 v, int rbase, int c, int stride) {
#pragma unroll
    for (int j = 0; j < 4; ++j)
        t[(rbase + j) * stride + c] = f2h_bits(elu_f(v[j]));
}
__device__ __forceinline__ void put_tile_relu_h(unsigned short* t, f32x4 v, int rbase, int c, int stride) {
#pragma unroll
    for (int j = 0; j < 4; ++j)
        t[(rbase + j) * stride + c] = f2h_bits(fmaxf(v[j], 0.f));
}

template <int K, bool POOL>
__global__ __launch_bounds__(256) void mlp_mfma_kernel(
    const uint4* __restrict__ inb,
    const uint4* __restrict__ WaP, const float* __restrict__ ba,
    const uint4* __restrict__ WbP, const float* __restrict__ bb,
    uint4* __restrict__ outb,
    const int* __restrict__ batch, float* __restrict__ hg,
    int nrows)
{
    constexpr int KS_A = K / 32;
    constexpr int SA = K + 8;
    constexpr int ST = HID + 8;
    constexpr int STF = HID + 4;
    __shared__ __align__(16) unsigned short a_s[32 * SA];
    __shared__ __align__(16) unsigned short t_s[32 * ST];
    __shared__ float p_s[POOL ? 32 * STF : 1];
    __shared__ int batch_s[POOL ? 32 : 1];

    const int tid = threadIdx.x;
    const int row0 = blockIdx.x * 32;

    constexpr int Q = K / 8;
    for (int idx = tid; idx < 32 * Q; idx += 256) {
        int r = idx / Q, q = idx % Q;
        uint4 v = make_uint4(0, 0, 0, 0);
        if (row0 + r < nrows) v = inb[(size_t)(row0 + r) * Q + q];
        *(uint4*)&a_s[r * SA + q * 8] = v;
    }
    if (POOL && tid < 32)
        batch_s[tid] = (row0 + tid < nrows) ? batch[row0 + tid] : -1;
    __syncthreads();

    const int lane = tid & 63;
    const int w = tid >> 6;
    const int rb = w >> 1;
    const int cg = (w & 1) * 4;
    const int cf = lane & 15;
    const int g = lane >> 4;
    const int arow = rb * 16 + cf;

    f32x4 acc0, acc1, acc2, acc3;
    {
        float c0 = ba[(cg + 0) * 16 + cf], c1 = ba[(cg + 1) * 16 + cf];
        float c2 = ba[(cg + 2) * 16 + cf], c3 = ba[(cg + 3) * 16 + cf];
        acc0 = (f32x4){c0, c0, c0, c0};
        acc1 = (f32x4){c1, c1, c1, c1};
        acc2 = (f32x4){c2, c2, c2, c2};
        acc3 = (f32x4){c3, c3, c3, c3};
    }
#pragma unroll
    for (int ks = 0; ks < KS_A; ++ks) {
        f16x8 a = *(const f16x8*)&a_s[arow * SA + ks * 32 + g * 8];
        acc0 = __builtin_amdgcn_mfma_f32_16x16x32_f16(a, frag_from(WaP[((cg + 0) * KS_A + ks) * 64 + lane]), acc0, 0, 0, 0);
        acc1 = __builtin_amdgcn_mfma_f32_16x16x32_f16(a, frag_from(WaP[((cg + 1) * KS_A + ks) * 64 + lane]), acc1, 0, 0, 0);
        acc2 = __builtin_amdgcn_mfma_f32_16x16x32_f16(a, frag_from(WaP[((cg + 2) * KS_A + ks) * 64 + lane]), acc2, 0, 0, 0);
        acc3 = __builtin_amdgcn_mfma_f32_16x16x32_f16(a, frag_from(WaP[((cg + 3) * KS_A + ks) * 64 + lane]), acc3, 0, 0, 0);
    }
    {
        int rbase = rb * 16 + g * 4;
        put_tile_elu_h(t_s, acc0, rbase, (cg + 0) * 16 + cf, ST);
        put_tile_elu_h(t_s, acc1, rbase, (cg + 1) * 16 + cf, ST);
        put_tile_elu_h(t_s, acc2, rbase, (cg + 2) * 16 + cf, ST);
        put_tile_elu_h(t_s, acc3, rbase, (cg + 3) * 16 + cf, ST);
    }
    __syncthreads();

    {
        float c0 = bb[(cg + 0) * 16 + cf], c1 = bb[(cg + 1) * 16 + cf];
        float c2 = bb[(cg + 2) * 16 + cf], c3 = bb[(cg + 3) * 16 + cf];
        acc0 = (f32x4){c0, c0, c0, c0};
        acc1 = (f32x4){c1, c1, c1, c1};
        acc2 = (f32x4){c2, c2, c2, c2};
        acc3 = (f32x4){c3, c3, c3, c3};
    }
#pragma unroll
    for (int ks = 0; ks < 4; ++ks) {
        f16x8 a = *(const f16x8*)&t_s[arow * ST + ks * 32 + g * 8];
        acc0 = __builtin_amdgcn_mfma_f32_16x16x32_f16(a, frag_from(WbP[((cg + 0) * 4 + ks) * 64 + lane]), acc0, 0, 0, 0);
        acc1 = __builtin_amdgcn_mfma_f32_16x16x32_f16(a, frag_from(WbP[((cg + 1) * 4 + ks) * 64 + lane]), acc1, 0, 0, 0);
        acc2 = __builtin_amdgcn_mfma_f32_16x16x32_f16(a, frag_from(WbP[((cg + 2) * 4 + ks) * 64 + lane]), acc2, 0, 0, 0);
        acc3 = __builtin_amdgcn_mfma_f32_16x16x32_f16(a, frag_from(WbP[((cg + 3) * 4 + ks) * 64 + lane]), acc3, 0, 0, 0);
    }

    if (POOL) {
        int rbase = rb * 16 + g * 4;
#pragma unroll
        for (int j = 0; j < 4; ++j) {
            p_s[(rbase + j) * STF + (cg + 0) * 16 + cf] = elu_f(acc0[j]);
            p_s[(rbase + j) * STF + (cg + 1) * 16 + cf] = elu_f(acc1[j]);
            p_s[(rbase + j) * STF + (cg + 2) * 16 + cf] = elu_f(acc2[j]);
            p_s[(rbase + j) * STF + (cg + 3) * 16 + cf] = elu_f(acc3[j]);
        }
        __syncthreads();
        int f = tid & 127, grp = tid >> 7;
        float acc = 0.f;
        int cur = -1;
#pragma unroll 4
        for (int r = 0; r < 16; ++r) {
            int rr = grp * 16 + r;
            int b = batch_s[rr];
            if (b >= 0) {
                if (b != cur) {
                    if (cur >= 0) atomicAdd(&hg[(size_t)cur * HID + f], acc);
                    acc = 0.f;
                    cur = b;
                }
                acc += p_s[rr * STF + f];
            }
        }
        if (cur >= 0) atomicAdd(&hg[(size_t)cur * HID + f], acc);
    } else {
        __syncthreads();
        int rbase = rb * 16 + g * 4;
        put_tile_elu_h(t_s, acc0, rbase, (cg + 0) * 16 + cf, ST);
        put_tile_elu_h(t_s, acc1, rbase, (cg + 1) * 16 + cf, ST);
        put_tile_elu_h(t_s, acc2, rbase, (cg + 2) * 16 + cf, ST);
        put_tile_elu_h(t_s, acc3, rbase, (cg + 3) * 16 + cf, ST);
        __syncthreads();
        for (int idx = tid; idx < 32 * 16; idx += 256) {
            int r = idx >> 4, q = idx & 15;
            if (row0 + r < nrows)
                outb[(size_t)(row0 + r) * 16 + q] = *(const uint4*)&t_s[r * ST + q * 8];
        }
    }
}

// ================= head via MFMA =================
__global__ __launch_bounds__(256) void head_mfma_kernel(
    const float* __restrict__ hg,
    const uint4* __restrict__ Wl1P, const float* __restrict__ bl1,
    const uint4* __restrict__ Wl2P, const float* __restrict__ bl2,
    float* __restrict__ out, int G)
{
    constexpr int ST = HID + 8;
    __shared__ __align__(16) unsigned short a_s[32 * ST];
    __shared__ __align__(16) unsigned short t_s[32 * ST];

    const int tid = threadIdx.x;
    const int row0 = blockIdx.x * 32;

    for (int idx = tid; idx < 32 * HID; idx += 256) {
        int r = idx >> 7, c = idx & 127;
        float v = (row0 + r < G) ? hg[(size_t)(row0 + r) * HID + c] : 0.f;
        a_s[r * ST + c] = f2h_bits(v);
    }
    __syncthreads();

    const int lane = tid & 63;
    const int w = tid >> 6;
    const int rb = w >> 1;
    const int cg = (w & 1) * 4;
    const int cf = lane & 15;
    const int g = lane >> 4;
    const int arow = rb * 16 + cf;

    f32x4 acc0, acc1, acc2, acc3;
    {
        float c0 = bl1[(cg + 0) * 16 + cf], c1 = bl1[(cg + 1) * 16 + cf];
        float c2 = bl1[(cg + 2) * 16 + cf], c3 = bl1[(cg + 3) * 16 + cf];
        acc0 = (f32x4){c0, c0, c0, c0};
        acc1 = (f32x4){c1, c1, c1, c1};
        acc2 = (f32x4){c2, c2, c2, c2};
        acc3 = (f32x4){c3, c3, c3, c3};
    }
#pragma unroll
    for (int ks = 0; ks < 4; ++ks) {
        f16x8 a = *(const f16x8*)&a_s[arow * ST + ks * 32 + g * 8];
        acc0 = __builtin_amdgcn_mfma_f32_16x16x32_f16(a, frag_from(Wl1P[((cg + 0) * 4 + ks) * 64 + lane]), acc0, 0, 0, 0);
        acc1 = __builtin_amdgcn_mfma_f32_16x16x32_f16(a, frag_from(Wl1P[((cg + 1) * 4 + ks) * 64 + lane]), acc1, 0, 0, 0);
        acc2 = __builtin_amdgcn_mfma_f32_16x16x32_f16(a, frag_from(Wl1P[((cg + 2) * 4 + ks) * 64 + lane]), acc2, 0, 0, 0);
        acc3 = __builtin_amdgcn_mfma_f32_16x16x32_f16(a, frag_from(Wl1P[((cg + 3) * 4 + ks) * 64 + lane]), acc3, 0, 0, 0);
    }
    {
        int rbase = rb * 16 + g * 4;
        put_tile_relu_h(t_s, acc0, rbase, (cg + 0) * 16 + cf, ST);
        put_tile_relu_h(t_s, acc1, rbase, (cg + 1) * 16 + cf, ST);
        put_tile_relu_h(t_s, acc2, rbase, (cg + 2) * 16 + cf, ST);
        put_tile_relu_h(t_s, acc3, rbase, (cg + 3) * 16 + cf, ST);
    }
    __syncthreads();

    if ((w & 1) == 0) {
        float c0 = cf < 12 ? bl2[cf] : 0.f;
        f32x4 acc = (f32x4){c0, c0, c0, c0};
#pragma unroll
        for (int ks = 0; ks < 4; ++ks) {
            f16x8 a = *(const f16x8*)&t_s[arow * ST + ks * 32 + g * 8];
            acc = __builtin_amdgcn_mfma_f32_16x16x32_f16(a, frag_from(Wl2P[ks * 64 + lane]), acc, 0, 0, 0);
        }
        if (cf < 12) {
            int rbase = rb * 16 + g * 4;
#pragma unroll
            for (int j = 0; j < 4; ++j) {
                int row = row0 + rbase + j;
                if (row < G) out[(size_t)row * 12 + cf] = acc[j];
            }
        }
    }
}

extern "C" void kernel_launch(void* const* d_in, const int* in_sizes, int n_in,
                              void* d_out, int out_size, void* d_ws, size_t ws_size,
                              hipStream_t stream)
{
    const float* x    = (const float*)d_in[0];
    const int*   ei   = (const int*)d_in[1];
    const float* ea   = (const float*)d_in[2];
    const int*   batch = (const int*)d_in[3];
    const float* We1 = (const float*)d_in[4];
    const float* be1 = (const float*)d_in[5];
    const float* W1a = (const float*)d_in[6];
    const float* b1a = (const float*)d_in[7];
    const float* W1b = (const float*)d_in[8];
    const float* b1b = (const float*)d_in[9];
    const float* We2 = (const float*)d_in[10];
    const float* be2 = (const float*)d_in[11];
    const float* W2a = (const float*)d_in[12];
    const float* b2a = (const float*)d_in[13];
    const float* W2b = (const float*)d_in[14];
    const float* b2b = (const float*)d_in[15];
    const float* Wl1 = (const float*)d_in[16];
    const float* bl1 = (const float*)d_in[17];
    const float* Wl2 = (const float*)d_in[18];
    const float* bl2 = (const float*)d_in[19];
    float* out = (float*)d_out;

    const int N = in_sizes[0] / F_NODE;
    const int E = in_sizes[1] / 2;
    const int G = out_size / 12;
    const int NB = (N + 255) >> 8;   // coarse buckets (256 nodes each), <= 512

    const int* srcp = ei;
    const int* dstp = ei + E;

    // ---- workspace layout ----
    char* wsb = (char*)d_ws;
    auto alloc = [&](size_t bytes) -> char* {
        char* p = wsb;
        wsb += (bytes + 15) & ~(size_t)15;
        return p;
    };
    int* cnt     = (int*)alloc((size_t)N * 4);
    int* off     = (int*)alloc((size_t)(N + 1) * 4);
    int* part    = (int*)alloc(256 * 4);
    int* curB    = (int*)alloc(512 * 4);
    int* curFine = (int*)alloc((size_t)N * 4);
    int2* tmp    = (int2*)alloc((size_t)E * 8);
    int2* pair   = (int2*)alloc((size_t)E * 8);
    unsigned* xh   = (unsigned*)alloc((size_t)N * 16 * 4);
    unsigned* eab  = (unsigned*)alloc((size_t)E * 4 * 4);
    unsigned* agg1h = (unsigned*)alloc((size_t)N * 16 * 4);
    unsigned* h1h   = (unsigned*)alloc((size_t)N * 64 * 4);
    unsigned* agg2h = (unsigned*)alloc((size_t)N * 64 * 4);
    float* hg  = (float*)alloc((size_t)G * HID * 4);
    uint4* P1a = (uint4*)alloc(512 * 16);
    uint4* P1b = (uint4*)alloc(2048 * 16);
    uint4* P2a = (uint4*)alloc(2048 * 16);
    uint4* P2b = (uint4*)alloc(2048 * 16);
    uint4* P3a = (uint4*)alloc(2048 * 16);
    uint4* P3b = (uint4*)alloc(256 * 16);

    (void)hipMemsetAsync(cnt, 0, (size_t)N * sizeof(int), stream);
    (void)hipMemsetAsync(hg, 0, (size_t)G * HID * sizeof(float), stream);

    // ---- fused prep: cast + wpack + hist ----
    {
        int nx = N * 16, ne2 = E * 4;
        long long total = (long long)nx + ne2 + 8960 + E;
        hipLaunchKernelGGL(prep_kernel, dim3((unsigned)((total + 255) / 256)), dim3(256), 0, stream,
                           x, ea, dstp, xh, eab, W1a, W1b, W2a, W2b, Wl1, Wl2,
                           P1a, P1b, P2a, P2b, P3a, P3b, cnt, nx, ne2, E);
    }
    int nscan = (N + 1023) / 1024;
    hipLaunchKernelGGL(scan1_kernel, dim3(nscan), dim3(256), 0, stream, cnt, off, part, N);
    hipLaunchKernelGGL(scan2_kernel, dim3(1), dim3(256), 0, stream, part, nscan);
    hipLaunchKernelGGL(scan3_kernel, dim3((N + 255) / 256), dim3(256), 0, stream,
                       off, part, curB, curFine, N, E);
    // two-level edge binning (replaces the write-thrashing fill scatter)
    hipLaunchKernelGGL(binA_kernel, dim3((E + 4095) / 4096), dim3(256), 0, stream,
                       dstp, srcp, curB, tmp, E, NB);
    hipLaunchKernelGGL(binB_kernel, dim3(NB), dim3(256), 0, stream,
                       tmp, off, curFine, pair, N);

    // ---- conv1 ----
    hipLaunchKernelGGL(agg1_kernel, dim3((N + 3) / 4), dim3(256), 0, stream,
                       x, xh, (const uint4*)eab, We1, be1, off, pair, agg1h, N);
    hipLaunchKernelGGL((mlp_mfma_kernel<F_NODE, false>), dim3((N + 31) / 32), dim3(256), 0, stream,
                       (const uint4*)agg1h, P1a, b1a, P1b, b1b, (uint4*)h1h,
                       (const int*)nullptr, (float*)nullptr, N);

    // ---- conv2 ----
    hipLaunchKernelGGL(agg2_kernel, dim3((N + 3) / 4), dim3(256), 0, stream,
                       h1h, (const uint4*)eab, We2, be2, off, pair, agg2h, N);
    hipLaunchKernelGGL((mlp_mfma_kernel<HID, true>), dim3((N + 31) / 32), dim3(256), 0, stream,
                       (const uint4*)agg2h, P2a, b2a, P2b, b2b, (uint4*)nullptr,
                       batch, hg, N);

    // ---- head (MFMA) ----
    hipLaunchKernelGGL(head_mfma_kernel, dim3((G + 31) / 32), dim3(256), 0, stream,
                       hg, P3a, bl1, P3b, bl2, out, G);
}

// Round 11
// 368.533 us; speedup vs baseline: 4.7622x; 1.0182x over previous
//
#include <hip/hip_runtime.h>
#include <math.h>

#define F_NODE 32
#define F_EDGE 8
#define HID 128
#define CAPB 6144      // pass-B LDS stage capacity (edges)

typedef __attribute__((ext_vector_type(2))) _Float16 f16x2;
typedef __attribute__((ext_vector_type(8))) _Float16 f16x8;
typedef __attribute__((ext_vector_type(4))) float f32x4;
typedef __attribute__((ext_vector_type(2))) float f32x2;

__device__ __forceinline__ float elu_f(float x) { return x > 0.f ? x : expf(x) - 1.f; }

__device__ __forceinline__ unsigned h2u(f16x2 h) { union { f16x2 h; unsigned u; } x; x.h = h; return x.u; }
__device__ __forceinline__ f16x2 u2h(unsigned u) { union { unsigned u; f16x2 h; } x; x.u = u; return x.h; }
__device__ __forceinline__ unsigned packh2(float lo, float hi) {
    f16x2 v; v.x = (_Float16)lo; v.y = (_Float16)hi; return h2u(v);
}
__device__ __forceinline__ unsigned short f2h_bits(float f) {
    _Float16 h = (_Float16)f; union { _Float16 h; unsigned short u; } x; x.h = h; return x.u;
}
__device__ __forceinline__ float hbits2f(unsigned short b) {
    union { unsigned short u; _Float16 h; } x; x.u = b; return (float)x.h;
}
__device__ __forceinline__ f16x8 frag_from(uint4 v) { union { uint4 u; f16x8 f; } x; x.u = v; return x.f; }
__device__ __forceinline__ f16x2 duph(f16x8 v, int k) { f16x2 d; d.x = v[k]; d.y = v[k]; return d; }

// ================= fused prep: cast x, cast ea, pack weights, histogram =================
__global__ void prep_kernel(const float* __restrict__ x, const float* __restrict__ ea,
                            const int* __restrict__ dst,
                            unsigned* __restrict__ xh, unsigned* __restrict__ eab,
                            const float* __restrict__ W1a, const float* __restrict__ W1b,
                            const float* __restrict__ W2a, const float* __restrict__ W2b,
                            const float* __restrict__ Wl1, const float* __restrict__ Wl2,
                            uint4* __restrict__ P1a, uint4* __restrict__ P1b,
                            uint4* __restrict__ P2a, uint4* __restrict__ P2b,
                            uint4* __restrict__ P3a, uint4* __restrict__ P3b,
                            int* __restrict__ cnt, int nx, int ne2, int E)
{
    int i = blockIdx.x * 256 + threadIdx.x;
    if (i < nx) {
        float2 v = ((const float2*)x)[i];
        xh[i] = packh2(v.x, v.y);
        return;
    }
    i -= nx;
    if (i < ne2) {
        float2 v = ((const float2*)ea)[i];
        eab[i] = packh2(v.x, v.y);
        return;
    }
    i -= ne2;
    if (i < 8960) {
        int f = i;
        if (f >= 8704) {                // P3b: Wl2 [128][12] -> 16 cols padded
            f -= 8704;
            int lane = f & 63;
            int ks = f >> 6;
            int col = lane & 15;
            int k0 = ks * 32 + (lane >> 4) * 8;
            float w[8];
#pragma unroll
            for (int j = 0; j < 8; ++j) w[j] = col < 12 ? Wl2[(size_t)(k0 + j) * 12 + col] : 0.f;
            uint4 v;
            v.x = packh2(w[0], w[1]);
            v.y = packh2(w[2], w[3]);
            v.z = packh2(w[4], w[5]);
            v.w = packh2(w[6], w[7]);
            P3b[f] = v;
            return;
        }
        const float* W; uint4* P; int KS;
        if (f < 512)       { W = W1a; P = P1a; KS = 1; }
        else if (f < 2560) { W = W1b; P = P1b; KS = 4; f -= 512; }
        else if (f < 4608) { W = W2a; P = P2a; KS = 4; f -= 2560; }
        else if (f < 6656) { W = W2b; P = P2b; KS = 4; f -= 4608; }
        else               { W = Wl1; P = P3a; KS = 4; f -= 6656; }
        int lane = f & 63;
        int rem = f >> 6;
        int ks = rem % KS, ct = rem / KS;
        int col = ct * 16 + (lane & 15);
        int k0 = ks * 32 + (lane >> 4) * 8;
        float w[8];
#pragma unroll
        for (int j = 0; j < 8; ++j) w[j] = W[(size_t)(k0 + j) * HID + col];
        uint4 v;
        v.x = packh2(w[0], w[1]);
        v.y = packh2(w[2], w[3]);
        v.z = packh2(w[4], w[5]);
        v.w = packh2(w[6], w[7]);
        P[f] = v;
        return;
    }
    i -= 8960;
    if (i < E) atomicAdd(&cnt[dst[i]], 1);
}

// ================= CSR build: scans =================
__global__ void scan1_kernel(const int* __restrict__ in, int* __restrict__ out,
                             int* __restrict__ part, int n) {
    __shared__ int s[256];
    int t = threadIdx.x;
    int base = blockIdx.x * 1024 + t * 4;
    int v0 = base + 0 < n ? in[base + 0] : 0;
    int v1 = base + 1 < n ? in[base + 1] : 0;
    int v2 = base + 2 < n ? in[base + 2] : 0;
    int v3 = base + 3 < n ? in[base + 3] : 0;
    int tot = v0 + v1 + v2 + v3;
    s[t] = tot;
    __syncthreads();
    for (int off = 1; off < 256; off <<= 1) {
        int val = (t >= off) ? s[t - off] : 0;
        __syncthreads();
        s[t] += val;
        __syncthreads();
    }
    int pre = s[t] - tot;
    if (base + 0 < n) out[base + 0] = pre;
    if (base + 1 < n) out[base + 1] = pre + v0;
    if (base + 2 < n) out[base + 2] = pre + v0 + v1;
    if (base + 3 < n) out[base + 3] = pre + v0 + v1 + v2;
    if (t == 255) part[blockIdx.x] = s[255];
}

__global__ void scan2_kernel(int* part, int nb) {
    __shared__ int s[256];
    int t = threadIdx.x;
    int v = t < nb ? part[t] : 0;
    s[t] = v;
    __syncthreads();
    for (int off = 1; off < 256; off <<= 1) {
        int val = (t >= off) ? s[t - off] : 0;
        __syncthreads();
        s[t] += val;
        __syncthreads();
    }
    if (t < nb) part[t] = s[t] - v;  // exclusive
}

__global__ void scan3_kernel(int* __restrict__ out, const int* __restrict__ part,
                             int* __restrict__ curB, int* __restrict__ curFine,
                             int n, int total) {
    int i = blockIdx.x * blockDim.x + threadIdx.x;
    if (i < n) {
        int v = out[i] + part[i >> 10];
        out[i] = v;
        curFine[i] = v;
        if ((i & 255) == 0) curB[i >> 8] = v;
    }
    if (i == 0) out[n] = total;
}

// ================= pass A: coarse bin into 256-node buckets =================
__global__ __launch_bounds__(256) void binA_kernel(
    const int* __restrict__ dst, const int* __restrict__ src,
    int* __restrict__ curB, int2* __restrict__ tmp, int E, int NB)
{
    __shared__ int hist[512];
    __shared__ int basev[512];
    const int tid = threadIdx.x;
    const int base = blockIdx.x * 4096;
    for (int i = tid; i < NB; i += 256) hist[i] = 0;
    __syncthreads();
    int d[16];
#pragma unroll
    for (int k = 0; k < 16; ++k) {
        int e = base + k * 256 + tid;
        d[k] = (e < E) ? dst[e] : -1;
        if (d[k] >= 0) atomicAdd(&hist[d[k] >> 8], 1);
    }
    __syncthreads();
    for (int i = tid; i < NB; i += 256) {
        int c = hist[i];
        basev[i] = c > 0 ? atomicAdd(&curB[i], c) : 0;
        hist[i] = 0;
    }
    __syncthreads();
#pragma unroll
    for (int k = 0; k < 16; ++k) {
        int e = base + k * 256 + tid;
        if (d[k] >= 0) {
            int b = d[k] >> 8;
            int r = atomicAdd(&hist[b], 1);
            tmp[basev[b] + r] = make_int2(e | ((d[k] & 255) << 22), src[e]);
        }
    }
}

// ================= pass B: fine sort + materialize src[] and easrt[] in edge order =====
__global__ __launch_bounds__(256) void binB_kernel(
    const int2* __restrict__ tmp, const int* __restrict__ off,
    int* __restrict__ curFine, const uint4* __restrict__ eab4,
    int* __restrict__ srcarr, uint4* __restrict__ easrt, int N)
{
    __shared__ int ldsCur[256];
    __shared__ int2 stage[CAPB];   // 48 KB
    const int b = blockIdx.x;
    const int tid = threadIdx.x;
    const int node0 = b << 8;
    const int nend = min(node0 + 256, N);
    const int base = off[node0];
    const int end = off[nend];
    const int S = end - base;
    if (S <= CAPB) {
        int node = node0 + tid;
        ldsCur[tid] = (node < nend ? off[node] : end) - base;
        __syncthreads();
        for (int j = tid; j < S; j += 256) {
            int2 rec = tmp[base + j];
            int dloc = ((unsigned)rec.x) >> 22;
            int slot = atomicAdd(&ldsCur[dloc], 1);
            stage[slot] = make_int2(rec.x & 0x3FFFFF, rec.y);
        }
        __syncthreads();
        for (int j = tid; j < S; j += 256) {
            int2 rec = stage[j];
            srcarr[base + j] = rec.y;
            easrt[base + j] = eab4[rec.x];   // one-time random ea gather
        }
    } else {                       // overflow fallback
        for (int j = tid; j < S; j += 256) {
            int2 rec = tmp[base + j];
            int dloc = ((unsigned)rec.x) >> 22;
            int e = rec.x & 0x3FFFFF;
            int pos = atomicAdd(&curFine[node0 + dloc], 1);
            srcarr[pos] = rec.y;
            easrt[pos] = eab4[e];
        }
    }
}

// ================= conv1 gather-aggregate (f16 gathers, sequential ea) =================
__global__ __launch_bounds__(256) void agg1_kernel(
    const float* __restrict__ x, const unsigned* __restrict__ xh,
    const uint4* __restrict__ easrt,
    const float* __restrict__ We, const float* __restrict__ be,
    const int* __restrict__ off, const int* __restrict__ srcarr,
    unsigned* __restrict__ aggh, int N)
{
    int wave = (blockIdx.x * 256 + threadIdx.x) >> 6;
    if (wave >= N) return;
    int lane = threadIdx.x & 63;
    int fp = lane & 15, eg = lane >> 4;
    int j0 = fp * 2;
    f16x2 w2[F_EDGE];
#pragma unroll
    for (int k = 0; k < F_EDGE; ++k)
        w2[k] = u2h(packh2(We[k * F_NODE + j0], We[k * F_NODE + j0 + 1]));
    f16x2 bias2 = u2h(packh2(be[j0], be[j0 + 1]));
    f16x2 zero2 = u2h(0u);
    int i0 = __builtin_amdgcn_readfirstlane(off[wave]);
    int i1 = __builtin_amdgcn_readfirstlane(off[wave + 1]);
    float acc0 = 0.f, acc1 = 0.f;
    for (int i = i0; i < i1; i += 4) {
        int ii = i + eg;
        if (ii < i1) {
            int s = srcarr[ii];
            f16x8 ev = frag_from(easrt[ii]);
            f16x2 m = bias2 + u2h(xh[(size_t)s * 16 + fp]);
#pragma unroll
            for (int k = 0; k < F_EDGE; ++k)
                m = duph(ev, k) * w2[k] + m;
            m = __builtin_elementwise_max(m, zero2);
            acc0 += (float)m.x;
            acc1 += (float)m.y;
        }
    }
    acc0 += __shfl_xor(acc0, 16, 64);
    acc0 += __shfl_xor(acc0, 32, 64);
    acc1 += __shfl_xor(acc1, 16, 64);
    acc1 += __shfl_xor(acc1, 32, 64);
    if (eg == 0) {
        float2 xo = *(const float2*)&x[(size_t)wave * F_NODE + j0];
        aggh[(size_t)wave * 16 + fp] = packh2(xo.x + acc0, xo.y + acc1);
    }
}

// ================= conv2 gather-aggregate (fp8 gathers, unroll 8) =================
__global__ __launch_bounds__(256) void agg2_kernel(
    const unsigned* __restrict__ hh, const unsigned short* __restrict__ h8,
    const uint4* __restrict__ easrt,
    const float* __restrict__ We, const float* __restrict__ be,
    const int* __restrict__ off, const int* __restrict__ srcarr,
    unsigned* __restrict__ aggh, int N)
{
    int wave = (blockIdx.x * 256 + threadIdx.x) >> 6;
    if (wave >= N) return;
    int lane = threadIdx.x & 63;
    int j0 = lane * 2;
    f16x2 w2[F_EDGE];
#pragma unroll
    for (int k = 0; k < F_EDGE; ++k)
        w2[k] = u2h(packh2(We[k * HID + j0], We[k * HID + j0 + 1]));
    f16x2 bias2 = u2h(packh2(be[j0], be[j0 + 1]));
    f16x2 zero2 = u2h(0u);
    int i0 = __builtin_amdgcn_readfirstlane(off[wave]);
    int i1 = __builtin_amdgcn_readfirstlane(off[wave + 1]);
    float acc0 = 0.f, acc1 = 0.f;
    int i = i0;
    for (; i + 7 < i1; i += 8) {
        int s[8];
        unsigned short u[8];
        f16x8 ev[8];
#pragma unroll
        for (int k = 0; k < 8; ++k) s[k] = srcarr[i + k];
#pragma unroll
        for (int k = 0; k < 8; ++k) u[k] = h8[(size_t)s[k] * 64 + lane];
#pragma unroll
        for (int k = 0; k < 8; ++k) ev[k] = frag_from(easrt[i + k]);
        f16x2 m[8];
#pragma unroll
        for (int k = 0; k < 8; ++k) {
            f32x2 f = __builtin_amdgcn_cvt_pk_f32_fp8((int)u[k], false);
            f16x2 hv; hv.x = (_Float16)f.x; hv.y = (_Float16)f.y;
            m[k] = bias2 + hv;
        }
#pragma unroll
        for (int kk = 0; kk < F_EDGE; ++kk) {
#pragma unroll
            for (int k = 0; k < 8; ++k)
                m[k] = duph(ev[k], kk) * w2[kk] + m[k];
        }
        f16x2 sm = __builtin_elementwise_max(m[0], zero2);
#pragma unroll
        for (int k = 1; k < 8; ++k) sm = sm + __builtin_elementwise_max(m[k], zero2);
        acc0 += (float)sm.x;
        acc1 += (float)sm.y;
    }
    for (; i < i1; ++i) {
        int s0 = srcarr[i];
        f16x8 e0 = frag_from(easrt[i]);
        f32x2 f = __builtin_amdgcn_cvt_pk_f32_fp8((int)h8[(size_t)s0 * 64 + lane], false);
        f16x2 hv; hv.x = (_Float16)f.x; hv.y = (_Float16)f.y;
        f16x2 m0 = bias2 + hv;
#pragma unroll
        for (int k = 0; k < F_EDGE; ++k)
            m0 = duph(e0, k) * w2[k] + m0;
        m0 = __builtin_elementwise_max(m0, zero2);
        acc0 += (float)m0.x;
        acc1 += (float)m0.y;
    }
    f16x2 self = u2h(hh[(size_t)wave * 64 + lane]);   // self term stays f16
    aggh[(size_t)wave * 64 + lane] = packh2((float)self.x + acc0, (float)self.y + acc1);
}

// ================= fused 2-layer node MLP via f16 MFMA =================
__device__ __forceinline__ void put_tile_elu_h(unsigned short* t, f32x4 v, int rbase, int c, int stride) {
#pragma unroll
    for (int j = 0; j < 4; ++j)
        t[(rbase + j) * stride + c] = f2h_bits(elu_f(v[j]));
}
__device__ __forceinline__ void put_tile_relu_h(unsigned short* t, f32x4 v, int rbase, int c, int stride) {
#pragma unroll
    for (int j = 0; j < 4; ++j)
        t[(rbase + j) * stride + c] = f2h_bits(fmaxf(v[j], 0.f));
}

template <int K, bool POOL, bool DUP8>
__global__ __launch_bounds__(256) void mlp_mfma_kernel(
    const uint4* __restrict__ inb,
    const uint4* __restrict__ WaP, const float* __restrict__ ba,
    const uint4* __restrict__ WbP, const float* __restrict__ bb,
    uint4* __restrict__ outb, unsigned* __restrict__ out8,
    const int* __restrict__ batch, float* __restrict__ hg,
    int nrows)
{
    constexpr int KS_A = K / 32;
    constexpr int SA = K + 8;
    constexpr int ST = HID + 8;
    constexpr int STF = HID + 4;
    __shared__ __align__(16) unsigned short a_s[32 * SA];
    __shared__ __align__(16) unsigned short t_s[32 * ST];
    __shared__ float p_s[POOL ? 32 * STF : 1];
    __shared__ int batch_s[POOL ? 32 : 1];

    const int tid = threadIdx.x;
    const int row0 = blockIdx.x * 32;

    constexpr int Q = K / 8;
    for (int idx = tid; idx < 32 * Q; idx += 256) {
        int r = idx / Q, q = idx % Q;
        uint4 v = make_uint4(0, 0, 0, 0);
        if (row0 + r < nrows) v = inb[(size_t)(row0 + r) * Q + q];
        *(uint4*)&a_s[r * SA + q * 8] = v;
    }
    if (POOL && tid < 32)
        batch_s[tid] = (row0 + tid < nrows) ? batch[row0 + tid] : -1;
    __syncthreads();

    const int lane = tid & 63;
    const int w = tid >> 6;
    const int rb = w >> 1;
    const int cg = (w & 1) * 4;
    const int cf = lane & 15;
    const int g = lane >> 4;
    const int arow = rb * 16 + cf;

    f32x4 acc0, acc1, acc2, acc3;
    {
        float c0 = ba[(cg + 0) * 16 + cf], c1 = ba[(cg + 1) * 16 + cf];
        float c2 = ba[(cg + 2) * 16 + cf], c3 = ba[(cg + 3) * 16 + cf];
        acc0 = (f32x4){c0, c0, c0, c0};
        acc1 = (f32x4){c1, c1, c1, c1};
        acc2 = (f32x4){c2, c2, c2, c2};
        acc3 = (f32x4){c3, c3, c3, c3};
    }
#pragma unroll
    for (int ks = 0; ks < KS_A; ++ks) {
        f16x8 a = *(const f16x8*)&a_s[arow * SA + ks * 32 + g * 8];
        acc0 = __builtin_amdgcn_mfma_f32_16x16x32_f16(a, frag_from(WaP[((cg + 0) * KS_A + ks) * 64 + lane]), acc0, 0, 0, 0);
        acc1 = __builtin_amdgcn_mfma_f32_16x16x32_f16(a, frag_from(WaP[((cg + 1) * KS_A + ks) * 64 + lane]), acc1, 0, 0, 0);
        acc2 = __builtin_amdgcn_mfma_f32_16x16x32_f16(a, frag_from(WaP[((cg + 2) * KS_A + ks) * 64 + lane]), acc2, 0, 0, 0);
        acc3 = __builtin_amdgcn_mfma_f32_16x16x32_f16(a, frag_from(WaP[((cg + 3) * KS_A + ks) * 64 + lane]), acc3, 0, 0, 0);
    }
    {
        int rbase = rb * 16 + g * 4;
        put_tile_elu_h(t_s, acc0, rbase, (cg + 0) * 16 + cf, ST);
        put_tile_elu_h(t_s, acc1, rbase, (cg + 1) * 16 + cf, ST);
        put_tile_elu_h(t_s, acc2, rbase, (cg + 2) * 16 + cf, ST);
        put_tile_elu_h(t_s, acc3, rbase, (cg + 3) * 16 + cf, ST);
    }
    __syncthreads();

    {
        float c0 = bb[(cg + 0) * 16 + cf], c1 = bb[(cg + 1) * 16 + cf];
        float c2 = bb[(cg + 2) * 16 + cf], c3 = bb[(cg + 3) * 16 + cf];
        acc0 = (f32x4){c0, c0, c0, c0};
        acc1 = (f32x4){c1, c1, c1, c1};
        acc2 = (f32x4){c2, c2, c2, c2};
        acc3 = (f32x4){c3, c3, c3, c3};
    }
#pragma unroll
    for (int ks = 0; ks < 4; ++ks) {
        f16x8 a = *(const f16x8*)&t_s[arow * ST + ks * 32 + g * 8];
        acc0 = __builtin_amdgcn_mfma_f32_16x16x32_f16(a, frag_from(WbP[((cg + 0) * 4 + ks) * 64 + lane]), acc0, 0, 0, 0);
        acc1 = __builtin_amdgcn_mfma_f32_16x16x32_f16(a, frag_from(WbP[((cg + 1) * 4 + ks) * 64 + lane]), acc1, 0, 0, 0);
        acc2 = __builtin_amdgcn_mfma_f32_16x16x32_f16(a, frag_from(WbP[((cg + 2) * 4 + ks) * 64 + lane]), acc2, 0, 0, 0);
        acc3 = __builtin_amdgcn_mfma_f32_16x16x32_f16(a, frag_from(WbP[((cg + 3) * 4 + ks) * 64 + lane]), acc3, 0, 0, 0);
    }

    if (POOL) {
        int rbase = rb * 16 + g * 4;
#pragma unroll
        for (int j = 0; j < 4; ++j) {
            p_s[(rbase + j) * STF + (cg + 0) * 16 + cf] = elu_f(acc0[j]);
            p_s[(rbase + j) * STF + (cg + 1) * 16 + cf] = elu_f(acc1[j]);
            p_s[(rbase + j) * STF + (cg + 2) * 16 + cf] = elu_f(acc2[j]);
            p_s[(rbase + j) * STF + (cg + 3) * 16 + cf] = elu_f(acc3[j]);
        }
        __syncthreads();
        int f = tid & 127, grp = tid >> 7;
        float acc = 0.f;
        int cur = -1;
#pragma unroll 4
        for (int r = 0; r < 16; ++r) {
            int rr = grp * 16 + r;
            int b = batch_s[rr];
            if (b >= 0) {
                if (b != cur) {
                    if (cur >= 0) atomicAdd(&hg[(size_t)cur * HID + f], acc);
                    acc = 0.f;
                    cur = b;
                }
                acc += p_s[rr * STF + f];
            }
        }
        if (cur >= 0) atomicAdd(&hg[(size_t)cur * HID + f], acc);
    } else {
        __syncthreads();
        int rbase = rb * 16 + g * 4;
        put_tile_elu_h(t_s, acc0, rbase, (cg + 0) * 16 + cf, ST);
        put_tile_elu_h(t_s, acc1, rbase, (cg + 1) * 16 + cf, ST);
        put_tile_elu_h(t_s, acc2, rbase, (cg + 2) * 16 + cf, ST);
        put_tile_elu_h(t_s, acc3, rbase, (cg + 3) * 16 + cf, ST);
        __syncthreads();
        for (int idx = tid; idx < 32 * 16; idx += 256) {
            int r = idx >> 4, q = idx & 15;
            if (row0 + r < nrows)
                outb[(size_t)(row0 + r) * 16 + q] = *(const uint4*)&t_s[r * ST + q * 8];
        }
        if (DUP8) {
            // fp8 e4m3 shadow table for agg2's gathers
            for (int idx = tid; idx < 32 * 32; idx += 256) {
                int r = idx >> 5, q = idx & 31;
                if (row0 + r < nrows) {
                    float f0 = hbits2f(t_s[r * ST + q * 4 + 0]);
                    float f1 = hbits2f(t_s[r * ST + q * 4 + 1]);
                    float f2 = hbits2f(t_s[r * ST + q * 4 + 2]);
                    float f3 = hbits2f(t_s[r * ST + q * 4 + 3]);
                    int u = __builtin_amdgcn_cvt_pk_fp8_f32(f0, f1, 0, false);
                    u = __builtin_amdgcn_cvt_pk_fp8_f32(f2, f3, u, true);
                    out8[(size_t)(row0 + r) * 32 + q] = (unsigned)u;
                }
            }
        }
    }
}

// ================= head via MFMA =================
__global__ __launch_bounds__(256) void head_mfma_kernel(
    const float* __restrict__ hg,
    const uint4* __restrict__ Wl1P, const float* __restrict__ bl1,
    const uint4* __restrict__ Wl2P, const float* __restrict__ bl2,
    float* __restrict__ out, int G)
{
    constexpr int ST = HID + 8;
    __shared__ __align__(16) unsigned short a_s[32 * ST];
    __shared__ __align__(16) unsigned short t_s[32 * ST];

    const int tid = threadIdx.x;
    const int row0 = blockIdx.x * 32;

    for (int idx = tid; idx < 32 * HID; idx += 256) {
        int r = idx >> 7, c = idx & 127;
        float v = (row0 + r < G) ? hg[(size_t)(row0 + r) * HID + c] : 0.f;
        a_s[r * ST + c] = f2h_bits(v);
    }
    __syncthreads();

    const int lane = tid & 63;
    const int w = tid >> 6;
    const int rb = w >> 1;
    const int cg = (w & 1) * 4;
    const int cf = lane & 15;
    const int g = lane >> 4;
    const int arow = rb * 16 + cf;

    f32x4 acc0, acc1, acc2, acc3;
    {
        float c0 = bl1[(cg + 0) * 16 + cf], c1 = bl1[(cg + 1) * 16 + cf];
        float c2 = bl1[(cg + 2) * 16 + cf], c3 = bl1[(cg + 3) * 16 + cf];
        acc0 = (f32x4){c0, c0, c0, c0};
        acc1 = (f32x4){c1, c1, c1, c1};
        acc2 = (f32x4){c2, c2, c2, c2};
        acc3 = (f32x4){c3, c3, c3, c3};
    }
#pragma unroll
    for (int ks = 0; ks < 4; ++ks) {
        f16x8 a = *(const f16x8*)&a_s[arow * ST + ks * 32 + g * 8];
        acc0 = __builtin_amdgcn_mfma_f32_16x16x32_f16(a, frag_from(Wl1P[((cg + 0) * 4 + ks) * 64 + lane]), acc0, 0, 0, 0);
        acc1 = __builtin_amdgcn_mfma_f32_16x16x32_f16(a, frag_from(Wl1P[((cg + 1) * 4 + ks) * 64 + lane]), acc1, 0, 0, 0);
        acc2 = __builtin_amdgcn_mfma_f32_16x16x32_f16(a, frag_from(Wl1P[((cg + 2) * 4 + ks) * 64 + lane]), acc2, 0, 0, 0);
        acc3 = __builtin_amdgcn_mfma_f32_16x16x32_f16(a, frag_from(Wl1P[((cg + 3) * 4 + ks) * 64 + lane]), acc3, 0, 0, 0);
    }
    {
        int rbase = rb * 16 + g * 4;
        put_tile_relu_h(t_s, acc0, rbase, (cg + 0) * 16 + cf, ST);
        put_tile_relu_h(t_s, acc1, rbase, (cg + 1) * 16 + cf, ST);
        put_tile_relu_h(t_s, acc2, rbase, (cg + 2) * 16 + cf, ST);
        put_tile_relu_h(t_s, acc3, rbase, (cg + 3) * 16 + cf, ST);
    }
    __syncthreads();

    if ((w & 1) == 0) {
        float c0 = cf < 12 ? bl2[cf] : 0.f;
        f32x4 acc = (f32x4){c0, c0, c0, c0};
#pragma unroll
        for (int ks = 0; ks < 4; ++ks) {
            f16x8 a = *(const f16x8*)&t_s[arow * ST + ks * 32 + g * 8];
            acc = __builtin_amdgcn_mfma_f32_16x16x32_f16(a, frag_from(Wl2P[ks * 64 + lane]), acc, 0, 0, 0);
        }
        if (cf < 12) {
            int rbase = rb * 16 + g * 4;
#pragma unroll
            for (int j = 0; j < 4; ++j) {
                int row = row0 + rbase + j;
                if (row < G) out[(size_t)row * 12 + cf] = acc[j];
            }
        }
    }
}

extern "C" void kernel_launch(void* const* d_in, const int* in_sizes, int n_in,
                              void* d_out, int out_size, void* d_ws, size_t ws_size,
                              hipStream_t stream)
{
    const float* x    = (const float*)d_in[0];
    const int*   ei   = (const int*)d_in[1];
    const float* ea   = (const float*)d_in[2];
    const int*   batch = (const int*)d_in[3];
    const float* We1 = (const float*)d_in[4];
    const float* be1 = (const float*)d_in[5];
    const float* W1a = (const float*)d_in[6];
    const float* b1a = (const float*)d_in[7];
    const float* W1b = (const float*)d_in[8];
    const float* b1b = (const float*)d_in[9];
    const float* We2 = (const float*)d_in[10];
    const float* be2 = (const float*)d_in[11];
    const float* W2a = (const float*)d_in[12];
    const float* b2a = (const float*)d_in[13];
    const float* W2b = (const float*)d_in[14];
    const float* b2b = (const float*)d_in[15];
    const float* Wl1 = (const float*)d_in[16];
    const float* bl1 = (const float*)d_in[17];
    const float* Wl2 = (const float*)d_in[18];
    const float* bl2 = (const float*)d_in[19];
    float* out = (float*)d_out;

    const int N = in_sizes[0] / F_NODE;
    const int E = in_sizes[1] / 2;
    const int G = out_size / 12;
    const int NB = (N + 255) >> 8;

    const int* srcp = ei;
    const int* dstp = ei + E;

    // ---- workspace layout (with lifetime-based aliasing) ----
    char* wsb = (char*)d_ws;
    auto alloc = [&](size_t bytes) -> char* {
        char* p = wsb;
        wsb += (bytes + 15) & ~(size_t)15;
        return p;
    };
    int* cnt     = (int*)alloc((size_t)N * 4);
    int* off     = (int*)alloc((size_t)(N + 1) * 4);
    int* part    = (int*)alloc(256 * 4);
    int* curB    = (int*)alloc(512 * 4);
    int* curFine = (int*)alloc((size_t)N * 4);
    int2* tmp    = (int2*)alloc((size_t)E * 8);           // dead after binB -> reused as h8
    unsigned short* h8 = (unsigned short*)tmp;            // N*128 fp8 bytes = 12.8MB <= E*8
    int* srcarr  = (int*)alloc((size_t)E * 4);
    uint4* easrt = (uint4*)alloc((size_t)E * 16);
    unsigned* xh   = (unsigned*)alloc((size_t)N * 16 * 4);
    unsigned* eab  = (unsigned*)alloc((size_t)E * 4 * 4); // dead after binB -> reused as agg2h
    unsigned* agg2h = eab;                                // N*64*4 = 25.6MB <= E*16
    unsigned* agg1h = (unsigned*)alloc((size_t)N * 16 * 4);
    unsigned* h1h   = (unsigned*)alloc((size_t)N * 64 * 4);
    float* hg  = (float*)alloc((size_t)G * HID * 4);
    uint4* P1a = (uint4*)alloc(512 * 16);
    uint4* P1b = (uint4*)alloc(2048 * 16);
    uint4* P2a = (uint4*)alloc(2048 * 16);
    uint4* P2b = (uint4*)alloc(2048 * 16);
    uint4* P3a = (uint4*)alloc(2048 * 16);
    uint4* P3b = (uint4*)alloc(256 * 16);

    (void)hipMemsetAsync(cnt, 0, (size_t)N * sizeof(int), stream);
    (void)hipMemsetAsync(hg, 0, (size_t)G * HID * sizeof(float), stream);

    // ---- fused prep: cast + wpack + hist ----
    {
        int nx = N * 16, ne2 = E * 4;
        long long total = (long long)nx + ne2 + 8960 + E;
        hipLaunchKernelGGL(prep_kernel, dim3((unsigned)((total + 255) / 256)), dim3(256), 0, stream,
                           x, ea, dstp, xh, eab, W1a, W1b, W2a, W2b, Wl1, Wl2,
                           P1a, P1b, P2a, P2b, P3a, P3b, cnt, nx, ne2, E);
    }
    int nscan = (N + 1023) / 1024;
    hipLaunchKernelGGL(scan1_kernel, dim3(nscan), dim3(256), 0, stream, cnt, off, part, N);
    hipLaunchKernelGGL(scan2_kernel, dim3(1), dim3(256), 0, stream, part, nscan);
    hipLaunchKernelGGL(scan3_kernel, dim3((N + 255) / 256), dim3(256), 0, stream,
                       off, part, curB, curFine, N, E);
    hipLaunchKernelGGL(binA_kernel, dim3((E + 4095) / 4096), dim3(256), 0, stream,
                       dstp, srcp, curB, tmp, E, NB);
    hipLaunchKernelGGL(binB_kernel, dim3(NB), dim3(256), 0, stream,
                       tmp, off, curFine, (const uint4*)eab, srcarr, easrt, N);

    // ---- conv1 ----
    hipLaunchKernelGGL(agg1_kernel, dim3((N + 3) / 4), dim3(256), 0, stream,
                       x, xh, easrt, We1, be1, off, srcarr, agg1h, N);
    hipLaunchKernelGGL((mlp_mfma_kernel<F_NODE, false, true>), dim3((N + 31) / 32), dim3(256), 0, stream,
                       (const uint4*)agg1h, P1a, b1a, P1b, b1b, (uint4*)h1h, (unsigned*)h8,
                       (const int*)nullptr, (float*)nullptr, N);

    // ---- conv2 ----
    hipLaunchKernelGGL(agg2_kernel, dim3((N + 3) / 4), dim3(256), 0, stream,
                       h1h, h8, easrt, We2, be2, off, srcarr, agg2h, N);
    hipLaunchKernelGGL((mlp_mfma_kernel<HID, true, false>), dim3((N + 31) / 32), dim3(256), 0, stream,
                       (const uint4*)agg2h, P2a, b2a, P2b, b2b, (uint4*)nullptr, (unsigned*)nullptr,
                       batch, hg, N);

    // ---- head (MFMA) ----
    hipLaunchKernelGGL(head_mfma_kernel, dim3((G + 31) / 32), dim3(256), 0, stream,
                       hg, P3a, bl1, P3b, bl2, out, G);
}

// Round 12
// 361.856 us; speedup vs baseline: 4.8500x; 1.0185x over previous
//
#include <hip/hip_runtime.h>
#include <math.h>

#define F_NODE 32
#define F_EDGE 8
#define HID 128
#define CAPB 6144      // pass-B LDS stage capacity (edges)

typedef __attribute__((ext_vector_type(2))) _Float16 f16x2;
typedef __attribute__((ext_vector_type(8))) _Float16 f16x8;
typedef __attribute__((ext_vector_type(4))) float f32x4;
typedef __attribute__((ext_vector_type(2))) float f32x2;

__device__ __forceinline__ float elu_f(float x) { return x > 0.f ? x : expf(x) - 1.f; }

__device__ __forceinline__ unsigned h2u(f16x2 h) { union { f16x2 h; unsigned u; } x; x.h = h; return x.u; }
__device__ __forceinline__ f16x2 u2h(unsigned u) { union { unsigned u; f16x2 h; } x; x.u = u; return x.h; }
__device__ __forceinline__ unsigned packh2(float lo, float hi) {
    f16x2 v; v.x = (_Float16)lo; v.y = (_Float16)hi; return h2u(v);
}
__device__ __forceinline__ unsigned short f2h_bits(float f) {
    _Float16 h = (_Float16)f; union { _Float16 h; unsigned short u; } x; x.h = h; return x.u;
}
__device__ __forceinline__ float hbits2f(unsigned short b) {
    union { unsigned short u; _Float16 h; } x; x.u = b; return (float)x.h;
}
__device__ __forceinline__ f16x8 frag_from(uint4 v) { union { uint4 u; f16x8 f; } x; x.u = v; return x.f; }
__device__ __forceinline__ f16x2 duph(f16x8 v, int k) { f16x2 d; d.x = v[k]; d.y = v[k]; return d; }

// ================= fused prep (grid-stride, vectorized) =================
__global__ __launch_bounds__(256) void prep_kernel(
    const float* __restrict__ x, const float* __restrict__ ea,
    const int* __restrict__ dst,
    uint4* __restrict__ xh4, uint4* __restrict__ eab4,
    const float* __restrict__ W1a, const float* __restrict__ W1b,
    const float* __restrict__ W2a, const float* __restrict__ W2b,
    const float* __restrict__ Wl1, const float* __restrict__ Wl2,
    uint4* __restrict__ P1a, uint4* __restrict__ P1b,
    uint4* __restrict__ P2a, uint4* __restrict__ P2b,
    uint4* __restrict__ P3a, uint4* __restrict__ P3b,
    int* __restrict__ cnt, int nx, int ne2, int E)
{
    const int stride = gridDim.x * 256;
    const int tid = blockIdx.x * 256 + threadIdx.x;
    const float4* x4 = (const float4*)x;
    const float4* ea4 = (const float4*)ea;

    // A: x -> f16 pairs, 4 pairs (1 uint4) per iter
    int nx4 = nx >> 2;
    for (int i = tid; i < nx4; i += stride) {
        float4 a = x4[i * 2], b = x4[i * 2 + 1];
        uint4 v;
        v.x = packh2(a.x, a.y);
        v.y = packh2(a.z, a.w);
        v.z = packh2(b.x, b.y);
        v.w = packh2(b.z, b.w);
        xh4[i] = v;
    }
    // B: ea -> f16 pairs
    int ne8 = ne2 >> 2;
    for (int i = tid; i < ne8; i += stride) {
        float4 a = ea4[i * 2], b = ea4[i * 2 + 1];
        uint4 v;
        v.x = packh2(a.x, a.y);
        v.y = packh2(a.z, a.w);
        v.z = packh2(b.x, b.y);
        v.w = packh2(b.z, b.w);
        eab4[i] = v;
    }
    // C: weight pack (f16 B-fragments)
    for (int f0 = tid; f0 < 8960; f0 += stride) {
        int f = f0;
        if (f >= 8704) {               // P3b: Wl2 [128][12] -> 16 cols padded
            f -= 8704;
            int lane = f & 63;
            int ks = f >> 6;
            int col = lane & 15;
            int k0 = ks * 32 + (lane >> 4) * 8;
            float w[8];
#pragma unroll
            for (int j = 0; j < 8; ++j) w[j] = col < 12 ? Wl2[(size_t)(k0 + j) * 12 + col] : 0.f;
            uint4 v;
            v.x = packh2(w[0], w[1]);
            v.y = packh2(w[2], w[3]);
            v.z = packh2(w[4], w[5]);
            v.w = packh2(w[6], w[7]);
            P3b[f] = v;
            continue;
        }
        const float* W; uint4* P; int KS;
        if (f < 512)       { W = W1a; P = P1a; KS = 1; }
        else if (f < 2560) { W = W1b; P = P1b; KS = 4; f -= 512; }
        else if (f < 4608) { W = W2a; P = P2a; KS = 4; f -= 2560; }
        else if (f < 6656) { W = W2b; P = P2b; KS = 4; f -= 4608; }
        else               { W = Wl1; P = P3a; KS = 4; f -= 6656; }
        int lane = f & 63;
        int rem = f >> 6;
        int ks = rem % KS, ct = rem / KS;
        int col = ct * 16 + (lane & 15);
        int k0 = ks * 32 + (lane >> 4) * 8;
        float w[8];
#pragma unroll
        for (int j = 0; j < 8; ++j) w[j] = W[(size_t)(k0 + j) * HID + col];
        uint4 v;
        v.x = packh2(w[0], w[1]);
        v.y = packh2(w[2], w[3]);
        v.z = packh2(w[4], w[5]);
        v.w = packh2(w[6], w[7]);
        P[f] = v;
    }
    // D: dst histogram, 4 per iter
    int e4 = E >> 2;
    const int4* dst4 = (const int4*)dst;
    for (int i = tid; i < e4; i += stride) {
        int4 d = dst4[i];
        atomicAdd(&cnt[d.x], 1);
        atomicAdd(&cnt[d.y], 1);
        atomicAdd(&cnt[d.z], 1);
        atomicAdd(&cnt[d.w], 1);
    }
    for (int i = e4 * 4 + tid; i < E; i += stride)
        atomicAdd(&cnt[dst[i]], 1);
}

// ================= CSR build: scans =================
__global__ void scan1_kernel(const int* __restrict__ in, int* __restrict__ out,
                             int* __restrict__ part, int n) {
    __shared__ int s[256];
    int t = threadIdx.x;
    int base = blockIdx.x * 1024 + t * 4;
    int v0 = base + 0 < n ? in[base + 0] : 0;
    int v1 = base + 1 < n ? in[base + 1] : 0;
    int v2 = base + 2 < n ? in[base + 2] : 0;
    int v3 = base + 3 < n ? in[base + 3] : 0;
    int tot = v0 + v1 + v2 + v3;
    s[t] = tot;
    __syncthreads();
    for (int off = 1; off < 256; off <<= 1) {
        int val = (t >= off) ? s[t - off] : 0;
        __syncthreads();
        s[t] += val;
        __syncthreads();
    }
    int pre = s[t] - tot;
    if (base + 0 < n) out[base + 0] = pre;
    if (base + 1 < n) out[base + 1] = pre + v0;
    if (base + 2 < n) out[base + 2] = pre + v0 + v1;
    if (base + 3 < n) out[base + 3] = pre + v0 + v1 + v2;
    if (t == 255) part[blockIdx.x] = s[255];
}

__global__ void scan2_kernel(int* part, int nb) {
    __shared__ int s[256];
    int t = threadIdx.x;
    int v = t < nb ? part[t] : 0;
    s[t] = v;
    __syncthreads();
    for (int off = 1; off < 256; off <<= 1) {
        int val = (t >= off) ? s[t - off] : 0;
        __syncthreads();
        s[t] += val;
        __syncthreads();
    }
    if (t < nb) part[t] = s[t] - v;  // exclusive
}

__global__ void scan3_kernel(int* __restrict__ out, const int* __restrict__ part,
                             int* __restrict__ curB, int* __restrict__ curFine,
                             int n, int total) {
    int i = blockIdx.x * blockDim.x + threadIdx.x;
    if (i < n) {
        int v = out[i] + part[i >> 10];
        out[i] = v;
        curFine[i] = v;
        if ((i & 255) == 0) curB[i >> 8] = v;
    }
    if (i == 0) out[n] = total;
}

// ================= pass A: coarse bin into 256-node buckets =================
__global__ __launch_bounds__(256) void binA_kernel(
    const int* __restrict__ dst, const int* __restrict__ src,
    int* __restrict__ curB, int2* __restrict__ tmp, int E, int NB)
{
    __shared__ int hist[512];
    __shared__ int basev[512];
    const int tid = threadIdx.x;
    const int base = blockIdx.x * 4096;
    for (int i = tid; i < NB; i += 256) hist[i] = 0;
    __syncthreads();
    int d[16];
#pragma unroll
    for (int k = 0; k < 16; ++k) {
        int e = base + k * 256 + tid;
        d[k] = (e < E) ? dst[e] : -1;
        if (d[k] >= 0) atomicAdd(&hist[d[k] >> 8], 1);
    }
    __syncthreads();
    for (int i = tid; i < NB; i += 256) {
        int c = hist[i];
        basev[i] = c > 0 ? atomicAdd(&curB[i], c) : 0;
        hist[i] = 0;
    }
    __syncthreads();
#pragma unroll
    for (int k = 0; k < 16; ++k) {
        int e = base + k * 256 + tid;
        if (d[k] >= 0) {
            int b = d[k] >> 8;
            int r = atomicAdd(&hist[b], 1);
            tmp[basev[b] + r] = make_int2(e | ((d[k] & 255) << 22), src[e]);
        }
    }
}

// ================= pass B: fine sort + materialize src[] and easrt[] =================
__global__ __launch_bounds__(256) void binB_kernel(
    const int2* __restrict__ tmp, const int* __restrict__ off,
    int* __restrict__ curFine, const uint4* __restrict__ eab4,
    int* __restrict__ srcarr, uint4* __restrict__ easrt, int N)
{
    __shared__ int ldsCur[256];
    __shared__ int2 stage[CAPB];   // 48 KB
    const int b = blockIdx.x;
    const int tid = threadIdx.x;
    const int node0 = b << 8;
    const int nend = min(node0 + 256, N);
    const int base = off[node0];
    const int end = off[nend];
    const int S = end - base;
    if (S <= CAPB) {
        int node = node0 + tid;
        ldsCur[tid] = (node < nend ? off[node] : end) - base;
        __syncthreads();
        for (int j = tid; j < S; j += 256) {
            int2 rec = tmp[base + j];
            int dloc = ((unsigned)rec.x) >> 22;
            int slot = atomicAdd(&ldsCur[dloc], 1);
            stage[slot] = make_int2(rec.x & 0x3FFFFF, rec.y);
        }
        __syncthreads();
        for (int j = tid; j < S; j += 256) {
            int2 rec = stage[j];
            srcarr[base + j] = rec.y;
            easrt[base + j] = eab4[rec.x];   // one-time random ea gather
        }
    } else {                       // overflow fallback
        for (int j = tid; j < S; j += 256) {
            int2 rec = tmp[base + j];
            int dloc = ((unsigned)rec.x) >> 22;
            int e = rec.x & 0x3FFFFF;
            int pos = atomicAdd(&curFine[node0 + dloc], 1);
            srcarr[pos] = rec.y;
            easrt[pos] = eab4[e];
        }
    }
}

// ================= conv1 gather-aggregate (f16 gathers, sequential ea) =================
__global__ __launch_bounds__(256) void agg1_kernel(
    const float* __restrict__ x, const unsigned* __restrict__ xh,
    const uint4* __restrict__ easrt,
    const float* __restrict__ We, const float* __restrict__ be,
    const int* __restrict__ off, const int* __restrict__ srcarr,
    unsigned* __restrict__ aggh, int N)
{
    int wave = (blockIdx.x * 256 + threadIdx.x) >> 6;
    if (wave >= N) return;
    int lane = threadIdx.x & 63;
    int fp = lane & 15, eg = lane >> 4;
    int j0 = fp * 2;
    f16x2 w2[F_EDGE];
#pragma unroll
    for (int k = 0; k < F_EDGE; ++k)
        w2[k] = u2h(packh2(We[k * F_NODE + j0], We[k * F_NODE + j0 + 1]));
    f16x2 bias2 = u2h(packh2(be[j0], be[j0 + 1]));
    f16x2 zero2 = u2h(0u);
    int i0 = __builtin_amdgcn_readfirstlane(off[wave]);
    int i1 = __builtin_amdgcn_readfirstlane(off[wave + 1]);
    float acc0 = 0.f, acc1 = 0.f;
    for (int i = i0; i < i1; i += 4) {
        int ii = i + eg;
        if (ii < i1) {
            int s = srcarr[ii];
            f16x8 ev = frag_from(easrt[ii]);
            f16x2 m = bias2 + u2h(xh[(size_t)s * 16 + fp]);
#pragma unroll
            for (int k = 0; k < F_EDGE; ++k)
                m = duph(ev, k) * w2[k] + m;
            m = __builtin_elementwise_max(m, zero2);
            acc0 += (float)m.x;
            acc1 += (float)m.y;
        }
    }
    acc0 += __shfl_xor(acc0, 16, 64);
    acc0 += __shfl_xor(acc0, 32, 64);
    acc1 += __shfl_xor(acc1, 16, 64);
    acc1 += __shfl_xor(acc1, 32, 64);
    if (eg == 0) {
        float2 xo = *(const float2*)&x[(size_t)wave * F_NODE + j0];
        aggh[(size_t)wave * 16 + fp] = packh2(xo.x + acc0, xo.y + acc1);
    }
}

// ================= conv2 gather-aggregate (fp8 gathers, unroll 8) =================
__global__ __launch_bounds__(256) void agg2_kernel(
    const unsigned* __restrict__ hh, const unsigned short* __restrict__ h8,
    const uint4* __restrict__ easrt,
    const float* __restrict__ We, const float* __restrict__ be,
    const int* __restrict__ off, const int* __restrict__ srcarr,
    unsigned* __restrict__ aggh, int N)
{
    int wave = (blockIdx.x * 256 + threadIdx.x) >> 6;
    if (wave >= N) return;
    int lane = threadIdx.x & 63;
    int j0 = lane * 2;
    f16x2 w2[F_EDGE];
#pragma unroll
    for (int k = 0; k < F_EDGE; ++k)
        w2[k] = u2h(packh2(We[k * HID + j0], We[k * HID + j0 + 1]));
    f16x2 bias2 = u2h(packh2(be[j0], be[j0 + 1]));
    f16x2 zero2 = u2h(0u);
    int i0 = __builtin_amdgcn_readfirstlane(off[wave]);
    int i1 = __builtin_amdgcn_readfirstlane(off[wave + 1]);
    float acc0 = 0.f, acc1 = 0.f;
    int i = i0;
    for (; i + 7 < i1; i += 8) {
        int s[8];
        unsigned short u[8];
        f16x8 ev[8];
#pragma unroll
        for (int k = 0; k < 8; ++k) s[k] = srcarr[i + k];
#pragma unroll
        for (int k = 0; k < 8; ++k) u[k] = h8[(size_t)s[k] * 64 + lane];
#pragma unroll
        for (int k = 0; k < 8; ++k) ev[k] = frag_from(easrt[i + k]);
        f16x2 m[8];
#pragma unroll
        for (int k = 0; k < 8; ++k) {
            f32x2 f = __builtin_amdgcn_cvt_pk_f32_fp8((int)u[k], false);
            f16x2 hv; hv.x = (_Float16)f.x; hv.y = (_Float16)f.y;
            m[k] = bias2 + hv;
        }
#pragma unroll
        for (int kk = 0; kk < F_EDGE; ++kk) {
#pragma unroll
            for (int k = 0; k < 8; ++k)
                m[k] = duph(ev[k], kk) * w2[kk] + m[k];
        }
        f16x2 sm = __builtin_elementwise_max(m[0], zero2);
#pragma unroll
        for (int k = 1; k < 8; ++k) sm = sm + __builtin_elementwise_max(m[k], zero2);
        acc0 += (float)sm.x;
        acc1 += (float)sm.y;
    }
    for (; i < i1; ++i) {
        int s0 = srcarr[i];
        f16x8 e0 = frag_from(easrt[i]);
        f32x2 f = __builtin_amdgcn_cvt_pk_f32_fp8((int)h8[(size_t)s0 * 64 + lane], false);
        f16x2 hv; hv.x = (_Float16)f.x; hv.y = (_Float16)f.y;
        f16x2 m0 = bias2 + hv;
#pragma unroll
        for (int k = 0; k < F_EDGE; ++k)
            m0 = duph(e0, k) * w2[k] + m0;
        m0 = __builtin_elementwise_max(m0, zero2);
        acc0 += (float)m0.x;
        acc1 += (float)m0.y;
    }
    f16x2 self = u2h(hh[(size_t)wave * 64 + lane]);   // self term stays f16
    aggh[(size_t)wave * 64 + lane] = packh2((float)self.x + acc0, (float)self.y + acc1);
}

// ================= fused 2-layer node MLP via f16 MFMA =================
__device__ __forceinline__ void put_tile_elu_h(unsigned short* t, f32x4 v, int rbase, int c, int stride) {
#pragma unroll
    for (int j = 0; j < 4; ++j)
        t[(rbase + j) * stride + c] = f2h_bits(elu_f(v[j]));
}
__device__ __forceinline__ void put_tile_relu_h(unsigned short* t, f32x4 v, int rbase, int c, int stride) {
#pragma unroll
    for (int j = 0; j < 4; ++j)
        t[(rbase + j) * stride + c] = f2h_bits(fmaxf(v[j], 0.f));
}

template <int K, bool POOL, bool DUP8>
__global__ __launch_bounds__(256) void mlp_mfma_kernel(
    const uint4* __restrict__ inb,
    const uint4* __restrict__ WaP, const float* __restrict__ ba,
    const uint4* __restrict__ WbP, const float* __restrict__ bb,
    uint4* __restrict__ outb, unsigned* __restrict__ out8,
    const int* __restrict__ batch, float* __restrict__ hg,
    int nrows)
{
    constexpr int KS_A = K / 32;
    constexpr int SA = K + 8;
    constexpr int ST = HID + 8;
    constexpr int STF = HID + 4;
    __shared__ __align__(16) unsigned short a_s[32 * SA];
    __shared__ __align__(16) unsigned short t_s[32 * ST];
    __shared__ float p_s[POOL ? 32 * STF : 1];
    __shared__ int batch_s[POOL ? 32 : 1];

    const int tid = threadIdx.x;
    const int row0 = blockIdx.x * 32;

    constexpr int Q = K / 8;
    for (int idx = tid; idx < 32 * Q; idx += 256) {
        int r = idx / Q, q = idx % Q;
        uint4 v = make_uint4(0, 0, 0, 0);
        if (row0 + r < nrows) v = inb[(size_t)(row0 + r) * Q + q];
        *(uint4*)&a_s[r * SA + q * 8] = v;
    }
    if (POOL && tid < 32)
        batch_s[tid] = (row0 + tid < nrows) ? batch[row0 + tid] : -1;
    __syncthreads();

    const int lane = tid & 63;
    const int w = tid >> 6;
    const int rb = w >> 1;
    const int cg = (w & 1) * 4;
    const int cf = lane & 15;
    const int g = lane >> 4;
    const int arow = rb * 16 + cf;

    f32x4 acc0, acc1, acc2, acc3;
    {
        float c0 = ba[(cg + 0) * 16 + cf], c1 = ba[(cg + 1) * 16 + cf];
        float c2 = ba[(cg + 2) * 16 + cf], c3 = ba[(cg + 3) * 16 + cf];
        acc0 = (f32x4){c0, c0, c0, c0};
        acc1 = (f32x4){c1, c1, c1, c1};
        acc2 = (f32x4){c2, c2, c2, c2};
        acc3 = (f32x4){c3, c3, c3, c3};
    }
#pragma unroll
    for (int ks = 0; ks < KS_A; ++ks) {
        f16x8 a = *(const f16x8*)&a_s[arow * SA + ks * 32 + g * 8];
        acc0 = __builtin_amdgcn_mfma_f32_16x16x32_f16(a, frag_from(WaP[((cg + 0) * KS_A + ks) * 64 + lane]), acc0, 0, 0, 0);
        acc1 = __builtin_amdgcn_mfma_f32_16x16x32_f16(a, frag_from(WaP[((cg + 1) * KS_A + ks) * 64 + lane]), acc1, 0, 0, 0);
        acc2 = __builtin_amdgcn_mfma_f32_16x16x32_f16(a, frag_from(WaP[((cg + 2) * KS_A + ks) * 64 + lane]), acc2, 0, 0, 0);
        acc3 = __builtin_amdgcn_mfma_f32_16x16x32_f16(a, frag_from(WaP[((cg + 3) * KS_A + ks) * 64 + lane]), acc3, 0, 0, 0);
    }
    {
        int rbase = rb * 16 + g * 4;
        put_tile_elu_h(t_s, acc0, rbase, (cg + 0) * 16 + cf, ST);
        put_tile_elu_h(t_s, acc1, rbase, (cg + 1) * 16 + cf, ST);
        put_tile_elu_h(t_s, acc2, rbase, (cg + 2) * 16 + cf, ST);
        put_tile_elu_h(t_s, acc3, rbase, (cg + 3) * 16 + cf, ST);
    }
    __syncthreads();

    {
        float c0 = bb[(cg + 0) * 16 + cf], c1 = bb[(cg + 1) * 16 + cf];
        float c2 = bb[(cg + 2) * 16 + cf], c3 = bb[(cg + 3) * 16 + cf];
        acc0 = (f32x4){c0, c0, c0, c0};
        acc1 = (f32x4){c1, c1, c1, c1};
        acc2 = (f32x4){c2, c2, c2, c2};
        acc3 = (f32x4){c3, c3, c3, c3};
    }
#pragma unroll
    for (int ks = 0; ks < 4; ++ks) {
        f16x8 a = *(const f16x8*)&t_s[arow * ST + ks * 32 + g * 8];
        acc0 = __builtin_amdgcn_mfma_f32_16x16x32_f16(a, frag_from(WbP[((cg + 0) * 4 + ks) * 64 + lane]), acc0, 0, 0, 0);
        acc1 = __builtin_amdgcn_mfma_f32_16x16x32_f16(a, frag_from(WbP[((cg + 1) * 4 + ks) * 64 + lane]), acc1, 0, 0, 0);
        acc2 = __builtin_amdgcn_mfma_f32_16x16x32_f16(a, frag_from(WbP[((cg + 2) * 4 + ks) * 64 + lane]), acc2, 0, 0, 0);
        acc3 = __builtin_amdgcn_mfma_f32_16x16x32_f16(a, frag_from(WbP[((cg + 3) * 4 + ks) * 64 + lane]), acc3, 0, 0, 0);
    }

    if (POOL) {
        int rbase = rb * 16 + g * 4;
#pragma unroll
        for (int j = 0; j < 4; ++j) {
            p_s[(rbase + j) * STF + (cg + 0) * 16 + cf] = elu_f(acc0[j]);
            p_s[(rbase + j) * STF + (cg + 1) * 16 + cf] = elu_f(acc1[j]);
            p_s[(rbase + j) * STF + (cg + 2) * 16 + cf] = elu_f(acc2[j]);
            p_s[(rbase + j) * STF + (cg + 3) * 16 + cf] = elu_f(acc3[j]);
        }
        __syncthreads();
        int f = tid & 127, grp = tid >> 7;
        float acc = 0.f;
        int cur = -1;
#pragma unroll 4
        for (int r = 0; r < 16; ++r) {
            int rr = grp * 16 + r;
            int b = batch_s[rr];
            if (b >= 0) {
                if (b != cur) {
                    if (cur >= 0) atomicAdd(&hg[(size_t)cur * HID + f], acc);
                    acc = 0.f;
                    cur = b;
                }
                acc += p_s[rr * STF + f];
            }
        }
        if (cur >= 0) atomicAdd(&hg[(size_t)cur * HID + f], acc);
    } else {
        __syncthreads();
        int rbase = rb * 16 + g * 4;
        put_tile_elu_h(t_s, acc0, rbase, (cg + 0) * 16 + cf, ST);
        put_tile_elu_h(t_s, acc1, rbase, (cg + 1) * 16 + cf, ST);
        put_tile_elu_h(t_s, acc2, rbase, (cg + 2) * 16 + cf, ST);
        put_tile_elu_h(t_s, acc3, rbase, (cg + 3) * 16 + cf, ST);
        __syncthreads();
        for (int idx = tid; idx < 32 * 16; idx += 256) {
            int r = idx >> 4, q = idx & 15;
            if (row0 + r < nrows)
                outb[(size_t)(row0 + r) * 16 + q] = *(const uint4*)&t_s[r * ST + q * 8];
        }
        if (DUP8) {
            for (int idx = tid; idx < 32 * 32; idx += 256) {
                int r = idx >> 5, q = idx & 31;
                if (row0 + r < nrows) {
                    float f0 = hbits2f(t_s[r * ST + q * 4 + 0]);
                    float f1 = hbits2f(t_s[r * ST + q * 4 + 1]);
                    float f2 = hbits2f(t_s[r * ST + q * 4 + 2]);
                    float f3 = hbits2f(t_s[r * ST + q * 4 + 3]);
                    int u = __builtin_amdgcn_cvt_pk_fp8_f32(f0, f1, 0, false);
                    u = __builtin_amdgcn_cvt_pk_fp8_f32(f2, f3, u, true);
                    out8[(size_t)(row0 + r) * 32 + q] = (unsigned)u;
                }
            }
        }
    }
}

// ================= head via MFMA =================
__global__ __launch_bounds__(256) void head_mfma_kernel(
    const float* __restrict__ hg,
    const uint4* __restrict__ Wl1P, const float* __restrict__ bl1,
    const uint4* __restrict__ Wl2P, const float* __restrict__ bl2,
    float* __restrict__ out, int G)
{
    constexpr int ST = HID + 8;
    __shared__ __align__(16) unsigned short a_s[32 * ST];
    __shared__ __align__(16) unsigned short t_s[32 * ST];

    const int tid = threadIdx.x;
    const int row0 = blockIdx.x * 32;

    for (int idx = tid; idx < 32 * HID; idx += 256) {
        int r = idx >> 7, c = idx & 127;
        float v = (row0 + r < G) ? hg[(size_t)(row0 + r) * HID + c] : 0.f;
        a_s[r * ST + c] = f2h_bits(v);
    }
    __syncthreads();

    const int lane = tid & 63;
    const int w = tid >> 6;
    const int rb = w >> 1;
    const int cg = (w & 1) * 4;
    const int cf = lane & 15;
    const int g = lane >> 4;
    const int arow = rb * 16 + cf;

    f32x4 acc0, acc1, acc2, acc3;
    {
        float c0 = bl1[(cg + 0) * 16 + cf], c1 = bl1[(cg + 1) * 16 + cf];
        float c2 = bl1[(cg + 2) * 16 + cf], c3 = bl1[(cg + 3) * 16 + cf];
        acc0 = (f32x4){c0, c0, c0, c0};
        acc1 = (f32x4){c1, c1, c1, c1};
        acc2 = (f32x4){c2, c2, c2, c2};
        acc3 = (f32x4){c3, c3, c3, c3};
    }
#pragma unroll
    for (int ks = 0; ks < 4; ++ks) {
        f16x8 a = *(const f16x8*)&a_s[arow * ST + ks * 32 + g * 8];
        acc0 = __builtin_amdgcn_mfma_f32_16x16x32_f16(a, frag_from(Wl1P[((cg + 0) * 4 + ks) * 64 + lane]), acc0, 0, 0, 0);
        acc1 = __builtin_amdgcn_mfma_f32_16x16x32_f16(a, frag_from(Wl1P[((cg + 1) * 4 + ks) * 64 + lane]), acc1, 0, 0, 0);
        acc2 = __builtin_amdgcn_mfma_f32_16x16x32_f16(a, frag_from(Wl1P[((cg + 2) * 4 + ks) * 64 + lane]), acc2, 0, 0, 0);
        acc3 = __builtin_amdgcn_mfma_f32_16x16x32_f16(a, frag_from(Wl1P[((cg + 3) * 4 + ks) * 64 + lane]), acc3, 0, 0, 0);
    }
    {
        int rbase = rb * 16 + g * 4;
        put_tile_relu_h(t_s, acc0, rbase, (cg + 0) * 16 + cf, ST);
        put_tile_relu_h(t_s, acc1, rbase, (cg + 1) * 16 + cf, ST);
        put_tile_relu_h(t_s, acc2, rbase, (cg + 2) * 16 + cf, ST);
        put_tile_relu_h(t_s, acc3, rbase, (cg + 3) * 16 + cf, ST);
    }
    __syncthreads();

    if ((w & 1) == 0) {
        float c0 = cf < 12 ? bl2[cf] : 0.f;
        f32x4 acc = (f32x4){c0, c0, c0, c0};
#pragma unroll
        for (int ks = 0; ks < 4; ++ks) {
            f16x8 a = *(const f16x8*)&t_s[arow * ST + ks * 32 + g * 8];
            acc = __builtin_amdgcn_mfma_f32_16x16x32_f16(a, frag_from(Wl2P[ks * 64 + lane]), acc, 0, 0, 0);
        }
        if (cf < 12) {
            int rbase = rb * 16 + g * 4;
#pragma unroll
            for (int j = 0; j < 4; ++j) {
                int row = row0 + rbase + j;
                if (row < G) out[(size_t)row * 12 + cf] = acc[j];
            }
        }
    }
}

extern "C" void kernel_launch(void* const* d_in, const int* in_sizes, int n_in,
                              void* d_out, int out_size, void* d_ws, size_t ws_size,
                              hipStream_t stream)
{
    const float* x    = (const float*)d_in[0];
    const int*   ei   = (const int*)d_in[1];
    const float* ea   = (const float*)d_in[2];
    const int*   batch = (const int*)d_in[3];
    const float* We1 = (const float*)d_in[4];
    const float* be1 = (const float*)d_in[5];
    const float* W1a = (const float*)d_in[6];
    const float* b1a = (const float*)d_in[7];
    const float* W1b = (const float*)d_in[8];
    const float* b1b = (const float*)d_in[9];
    const float* We2 = (const float*)d_in[10];
    const float* be2 = (const float*)d_in[11];
    const float* W2a = (const float*)d_in[12];
    const float* b2a = (const float*)d_in[13];
    const float* W2b = (const float*)d_in[14];
    const float* b2b = (const float*)d_in[15];
    const float* Wl1 = (const float*)d_in[16];
    const float* bl1 = (const float*)d_in[17];
    const float* Wl2 = (const float*)d_in[18];
    const float* bl2 = (const float*)d_in[19];
    float* out = (float*)d_out;

    const int N = in_sizes[0] / F_NODE;
    const int E = in_sizes[1] / 2;
    const int G = out_size / 12;
    const int NB = (N + 255) >> 8;

    const int* srcp = ei;
    const int* dstp = ei + E;

    // ---- workspace layout (with lifetime-based aliasing) ----
    char* wsb = (char*)d_ws;
    auto alloc = [&](size_t bytes) -> char* {
        char* p = wsb;
        wsb += (bytes + 15) & ~(size_t)15;
        return p;
    };
    int* cnt     = (int*)alloc((size_t)N * 4);
    int* off     = (int*)alloc((size_t)(N + 1) * 4);
    int* part    = (int*)alloc(256 * 4);
    int* curB    = (int*)alloc(512 * 4);
    int* curFine = (int*)alloc((size_t)N * 4);
    int2* tmp    = (int2*)alloc((size_t)E * 8);           // dead after binB -> reused as h8
    unsigned short* h8 = (unsigned short*)tmp;            // N*128 fp8 bytes <= E*8
    int* srcarr  = (int*)alloc((size_t)E * 4);
    uint4* easrt = (uint4*)alloc((size_t)E * 16);
    unsigned* xh   = (unsigned*)alloc((size_t)N * 16 * 4);
    unsigned* eab  = (unsigned*)alloc((size_t)E * 4 * 4); // dead after binB -> reused as agg2h
    unsigned* agg2h = eab;
    unsigned* agg1h = (unsigned*)alloc((size_t)N * 16 * 4);
    unsigned* h1h   = (unsigned*)alloc((size_t)N * 64 * 4);
    float* hg  = (float*)alloc((size_t)G * HID * 4);
    uint4* P1a = (uint4*)alloc(512 * 16);
    uint4* P1b = (uint4*)alloc(2048 * 16);
    uint4* P2a = (uint4*)alloc(2048 * 16);
    uint4* P2b = (uint4*)alloc(2048 * 16);
    uint4* P3a = (uint4*)alloc(2048 * 16);
    uint4* P3b = (uint4*)alloc(256 * 16);

    (void)hipMemsetAsync(cnt, 0, (size_t)N * sizeof(int), stream);
    (void)hipMemsetAsync(hg, 0, (size_t)G * HID * sizeof(float), stream);

    // ---- fused prep: cast + wpack + hist (grid-stride, vectorized) ----
    hipLaunchKernelGGL(prep_kernel, dim3(2048), dim3(256), 0, stream,
                       x, ea, dstp, (uint4*)xh, (uint4*)eab, W1a, W1b, W2a, W2b, Wl1, Wl2,
                       P1a, P1b, P2a, P2b, P3a, P3b, cnt, N * 16, E * 4, E);
    int nscan = (N + 1023) / 1024;
    hipLaunchKernelGGL(scan1_kernel, dim3(nscan), dim3(256), 0, stream, cnt, off, part, N);
    hipLaunchKernelGGL(scan2_kernel, dim3(1), dim3(256), 0, stream, part, nscan);
    hipLaunchKernelGGL(scan3_kernel, dim3((N + 255) / 256), dim3(256), 0, stream,
                       off, part, curB, curFine, N, E);
    hipLaunchKernelGGL(binA_kernel, dim3((E + 4095) / 4096), dim3(256), 0, stream,
                       dstp, srcp, curB, tmp, E, NB);
    hipLaunchKernelGGL(binB_kernel, dim3(NB), dim3(256), 0, stream,
                       tmp, off, curFine, (const uint4*)eab, srcarr, easrt, N);

    // ---- conv1 ----
    hipLaunchKernelGGL(agg1_kernel, dim3((N + 3) / 4), dim3(256), 0, stream,
                       x, xh, easrt, We1, be1, off, srcarr, agg1h, N);
    hipLaunchKernelGGL((mlp_mfma_kernel<F_NODE, false, true>), dim3((N + 31) / 32), dim3(256), 0, stream,
                       (const uint4*)agg1h, P1a, b1a, P1b, b1b, (uint4*)h1h, (unsigned*)h8,
                       (const int*)nullptr, (float*)nullptr, N);

    // ---- conv2 ----
    hipLaunchKernelGGL(agg2_kernel, dim3((N + 3) / 4), dim3(256), 0, stream,
                       h1h, h8, easrt, We2, be2, off, srcarr, agg2h, N);
    hipLaunchKernelGGL((mlp_mfma_kernel<HID, true, false>), dim3((N + 31) / 32), dim3(256), 0, stream,
                       (const uint4*)agg2h, P2a, b2a, P2b, b2b, (uint4*)nullptr, (unsigned*)nullptr,
                       batch, hg, N);

    // ---- head (MFMA) ----
    hipLaunchKernelGGL(head_mfma_kernel, dim3((G + 31) / 32), dim3(256), 0, stream,
                       hg, P3a, bl1, P3b, bl2, out, G);
}

// Round 13
// 359.635 us; speedup vs baseline: 4.8800x; 1.0062x over previous
//
#include <hip/hip_runtime.h>
#include <math.h>

#define F_NODE 32
#define F_EDGE 8
#define HID 128

typedef __attribute__((ext_vector_type(2))) _Float16 f16x2;
typedef __attribute__((ext_vector_type(8))) _Float16 f16x8;
typedef __attribute__((ext_vector_type(4))) float f32x4;
typedef __attribute__((ext_vector_type(2))) float f32x2;

__device__ __forceinline__ float elu_f(float x) { return x > 0.f ? x : expf(x) - 1.f; }

__device__ __forceinline__ unsigned h2u(f16x2 h) { union { f16x2 h; unsigned u; } x; x.h = h; return x.u; }
__device__ __forceinline__ f16x2 u2h(unsigned u) { union { unsigned u; f16x2 h; } x; x.u = u; return x.h; }
__device__ __forceinline__ unsigned packh2(float lo, float hi) {
    f16x2 v; v.x = (_Float16)lo; v.y = (_Float16)hi; return h2u(v);
}
__device__ __forceinline__ unsigned short f2h_bits(float f) {
    _Float16 h = (_Float16)f; union { _Float16 h; unsigned short u; } x; x.h = h; return x.u;
}
__device__ __forceinline__ float hbits2f(unsigned short b) {
    union { unsigned short u; _Float16 h; } x; x.u = b; return (float)x.h;
}
__device__ __forceinline__ f16x8 frag_from(uint4 v) { union { uint4 u; f16x8 f; } x; x.u = v; return x.f; }
__device__ __forceinline__ f16x2 duph(f16x8 v, int k) { f16x2 d; d.x = v[k]; d.y = v[k]; return d; }

// ================= fused prep (grid-stride): casts + wpack + COARSE hist =================
__global__ __launch_bounds__(256) void prep_kernel(
    const float* __restrict__ x, const float* __restrict__ ea,
    const int* __restrict__ dst,
    uint4* __restrict__ xh4, uint4* __restrict__ eab4,
    const float* __restrict__ W1a, const float* __restrict__ W1b,
    const float* __restrict__ W2a, const float* __restrict__ W2b,
    const float* __restrict__ Wl1, const float* __restrict__ Wl2,
    uint4* __restrict__ P1a, uint4* __restrict__ P1b,
    uint4* __restrict__ P2a, uint4* __restrict__ P2b,
    uint4* __restrict__ P3a, uint4* __restrict__ P3b,
    int* __restrict__ cbkt, int nx, int ne2, int E, int NB)
{
    const int stride = gridDim.x * 256;
    const int tid = blockIdx.x * 256 + threadIdx.x;
    const float4* x4 = (const float4*)x;
    const float4* ea4 = (const float4*)ea;

    __shared__ int chist[512];
    for (int i = threadIdx.x; i < 512; i += 256) chist[i] = 0;
    __syncthreads();

    // A: x -> f16 pairs (1 uint4 per iter)
    int nx4 = nx >> 2;
    for (int i = tid; i < nx4; i += stride) {
        float4 a = x4[i * 2], b = x4[i * 2 + 1];
        uint4 v;
        v.x = packh2(a.x, a.y);
        v.y = packh2(a.z, a.w);
        v.z = packh2(b.x, b.y);
        v.w = packh2(b.z, b.w);
        xh4[i] = v;
    }
    // B: ea -> f16 pairs
    int ne8 = ne2 >> 2;
    for (int i = tid; i < ne8; i += stride) {
        float4 a = ea4[i * 2], b = ea4[i * 2 + 1];
        uint4 v;
        v.x = packh2(a.x, a.y);
        v.y = packh2(a.z, a.w);
        v.z = packh2(b.x, b.y);
        v.w = packh2(b.z, b.w);
        eab4[i] = v;
    }
    // C: weight pack (f16 B-fragments)
    for (int f0 = tid; f0 < 8960; f0 += stride) {
        int f = f0;
        if (f >= 8704) {               // P3b: Wl2 [128][12] -> 16 cols padded
            f -= 8704;
            int lane = f & 63;
            int ks = f >> 6;
            int col = lane & 15;
            int k0 = ks * 32 + (lane >> 4) * 8;
            float w[8];
#pragma unroll
            for (int j = 0; j < 8; ++j) w[j] = col < 12 ? Wl2[(size_t)(k0 + j) * 12 + col] : 0.f;
            uint4 v;
            v.x = packh2(w[0], w[1]);
            v.y = packh2(w[2], w[3]);
            v.z = packh2(w[4], w[5]);
            v.w = packh2(w[6], w[7]);
            P3b[f] = v;
            continue;
        }
        const float* W; uint4* P; int KS;
        if (f < 512)       { W = W1a; P = P1a; KS = 1; }
        else if (f < 2560) { W = W1b; P = P1b; KS = 4; f -= 512; }
        else if (f < 4608) { W = W2a; P = P2a; KS = 4; f -= 2560; }
        else if (f < 6656) { W = W2b; P = P2b; KS = 4; f -= 4608; }
        else               { W = Wl1; P = P3a; KS = 4; f -= 6656; }
        int lane = f & 63;
        int rem = f >> 6;
        int ks = rem % KS, ct = rem / KS;
        int col = ct * 16 + (lane & 15);
        int k0 = ks * 32 + (lane >> 4) * 8;
        float w[8];
#pragma unroll
        for (int j = 0; j < 8; ++j) w[j] = W[(size_t)(k0 + j) * HID + col];
        uint4 v;
        v.x = packh2(w[0], w[1]);
        v.y = packh2(w[2], w[3]);
        v.z = packh2(w[4], w[5]);
        v.w = packh2(w[6], w[7]);
        P[f] = v;
    }
    // D: coarse dst histogram (LDS-aggregated)
    int e4 = E >> 2;
    const int4* dst4 = (const int4*)dst;
    for (int i = tid; i < e4; i += stride) {
        int4 d = dst4[i];
        atomicAdd(&chist[d.x >> 8], 1);
        atomicAdd(&chist[d.y >> 8], 1);
        atomicAdd(&chist[d.z >> 8], 1);
        atomicAdd(&chist[d.w >> 8], 1);
    }
    for (int i = e4 * 4 + tid; i < E; i += stride)
        atomicAdd(&chist[dst[i] >> 8], 1);
    __syncthreads();
    for (int i = threadIdx.x; i < NB; i += 256) {
        int c = chist[i];
        if (c) atomicAdd(&cbkt[i], c);
    }
}

// ================= coarse bucket prefix (1 block) =================
__global__ void scanB_kernel(const int* __restrict__ cbkt,
                             int* __restrict__ bucketOff, int* __restrict__ curB,
                             int NB, int E) {
    if (threadIdx.x == 0 && blockIdx.x == 0) {
        int acc = 0;
        for (int i = 0; i < NB; ++i) {
            bucketOff[i] = acc;
            curB[i] = acc;
            acc += cbkt[i];
        }
        bucketOff[NB] = E;
    }
}

// ================= pass A: coarse bin into 256-node buckets =================
__global__ __launch_bounds__(256) void binA_kernel(
    const int* __restrict__ dst, const int* __restrict__ src,
    int* __restrict__ curB, int2* __restrict__ tmp, int E, int NB)
{
    __shared__ int hist[512];
    __shared__ int basev[512];
    const int tid = threadIdx.x;
    const int base = blockIdx.x * 4096;
    for (int i = tid; i < NB; i += 256) hist[i] = 0;
    __syncthreads();
    int d[16];
#pragma unroll
    for (int k = 0; k < 16; ++k) {
        int e = base + k * 256 + tid;
        d[k] = (e < E) ? dst[e] : -1;
        if (d[k] >= 0) atomicAdd(&hist[d[k] >> 8], 1);
    }
    __syncthreads();
    for (int i = tid; i < NB; i += 256) {
        int c = hist[i];
        basev[i] = c > 0 ? atomicAdd(&curB[i], c) : 0;
        hist[i] = 0;
    }
    __syncthreads();
#pragma unroll
    for (int k = 0; k < 16; ++k) {
        int e = base + k * 256 + tid;
        if (d[k] >= 0) {
            int b = d[k] >> 8;
            int r = atomicAdd(&hist[b], 1);
            tmp[basev[b] + r] = make_int2(e | ((d[k] & 255) << 22), src[e]);
        }
    }
}

// ================= pass B: per-node offsets in LDS + scatter + write off[] =====
__global__ __launch_bounds__(256) void binB_kernel(
    const int2* __restrict__ tmp, const int* __restrict__ bucketOff,
    const uint4* __restrict__ eab4,
    int* __restrict__ off, int* __restrict__ srcarr, uint4* __restrict__ easrt,
    int N, int E, int NB)
{
    __shared__ int hist[256];
    __shared__ int ss[256];
    const int b = blockIdx.x;
    const int tid = threadIdx.x;
    const int node0 = b << 8;
    const int base = bucketOff[b];
    const int end = bucketOff[b + 1];
    const int S = end - base;

    hist[tid] = 0;
    __syncthreads();
    for (int j = tid; j < S; j += 256) {
        int2 rec = tmp[base + j];
        atomicAdd(&hist[((unsigned)rec.x) >> 22], 1);
    }
    __syncthreads();
    // exclusive prefix sum over 256 counts
    int v = hist[tid];
    ss[tid] = v;
    __syncthreads();
    for (int o = 1; o < 256; o <<= 1) {
        int val = (tid >= o) ? ss[tid - o] : 0;
        __syncthreads();
        ss[tid] += val;
        __syncthreads();
    }
    int excl = ss[tid] - v;
    int node = node0 + tid;
    if (node < N) off[node] = base + excl;
    if (b == NB - 1 && tid == 0) off[N] = E;
    hist[tid] = excl;     // reuse as cursor
    __syncthreads();
    // scatter into final positions (writes land within this bucket's window)
    for (int j = tid; j < S; j += 256) {
        int2 rec = tmp[base + j];
        int dloc = ((unsigned)rec.x) >> 22;
        int slot = base + atomicAdd(&hist[dloc], 1);
        srcarr[slot] = rec.y;
        easrt[slot] = eab4[rec.x & 0x3FFFFF];   // one-time random ea gather
    }
}

// ================= conv1 gather-aggregate (f16 gathers, sequential ea) =================
__global__ __launch_bounds__(256) void agg1_kernel(
    const float* __restrict__ x, const unsigned* __restrict__ xh,
    const uint4* __restrict__ easrt,
    const float* __restrict__ We, const float* __restrict__ be,
    const int* __restrict__ off, const int* __restrict__ srcarr,
    unsigned* __restrict__ aggh, int N)
{
    int wave = (blockIdx.x * 256 + threadIdx.x) >> 6;
    if (wave >= N) return;
    int lane = threadIdx.x & 63;
    int fp = lane & 15, eg = lane >> 4;
    int j0 = fp * 2;
    f16x2 w2[F_EDGE];
#pragma unroll
    for (int k = 0; k < F_EDGE; ++k)
        w2[k] = u2h(packh2(We[k * F_NODE + j0], We[k * F_NODE + j0 + 1]));
    f16x2 bias2 = u2h(packh2(be[j0], be[j0 + 1]));
    f16x2 zero2 = u2h(0u);
    int i0 = __builtin_amdgcn_readfirstlane(off[wave]);
    int i1 = __builtin_amdgcn_readfirstlane(off[wave + 1]);
    float acc0 = 0.f, acc1 = 0.f;
    for (int i = i0; i < i1; i += 4) {
        int ii = i + eg;
        if (ii < i1) {
            int s = srcarr[ii];
            f16x8 ev = frag_from(easrt[ii]);
            f16x2 m = bias2 + u2h(xh[(size_t)s * 16 + fp]);
#pragma unroll
            for (int k = 0; k < F_EDGE; ++k)
                m = duph(ev, k) * w2[k] + m;
            m = __builtin_elementwise_max(m, zero2);
            acc0 += (float)m.x;
            acc1 += (float)m.y;
        }
    }
    acc0 += __shfl_xor(acc0, 16, 64);
    acc0 += __shfl_xor(acc0, 32, 64);
    acc1 += __shfl_xor(acc1, 16, 64);
    acc1 += __shfl_xor(acc1, 32, 64);
    if (eg == 0) {
        float2 xo = *(const float2*)&x[(size_t)wave * F_NODE + j0];
        aggh[(size_t)wave * 16 + fp] = packh2(xo.x + acc0, xo.y + acc1);
    }
}

// ================= conv2 gather-aggregate (fp8 gathers, unroll 8) =================
__global__ __launch_bounds__(256) void agg2_kernel(
    const unsigned* __restrict__ hh, const unsigned short* __restrict__ h8,
    const uint4* __restrict__ easrt,
    const float* __restrict__ We, const float* __restrict__ be,
    const int* __restrict__ off, const int* __restrict__ srcarr,
    unsigned* __restrict__ aggh, int N)
{
    int wave = (blockIdx.x * 256 + threadIdx.x) >> 6;
    if (wave >= N) return;
    int lane = threadIdx.x & 63;
    int j0 = lane * 2;
    f16x2 w2[F_EDGE];
#pragma unroll
    for (int k = 0; k < F_EDGE; ++k)
        w2[k] = u2h(packh2(We[k * HID + j0], We[k * HID + j0 + 1]));
    f16x2 bias2 = u2h(packh2(be[j0], be[j0 + 1]));
    f16x2 zero2 = u2h(0u);
    int i0 = __builtin_amdgcn_readfirstlane(off[wave]);
    int i1 = __builtin_amdgcn_readfirstlane(off[wave + 1]);
    float acc0 = 0.f, acc1 = 0.f;
    int i = i0;
    for (; i + 7 < i1; i += 8) {
        int s[8];
        unsigned short u[8];
        f16x8 ev[8];
#pragma unroll
        for (int k = 0; k < 8; ++k) s[k] = srcarr[i + k];
#pragma unroll
        for (int k = 0; k < 8; ++k) u[k] = h8[(size_t)s[k] * 64 + lane];
#pragma unroll
        for (int k = 0; k < 8; ++k) ev[k] = frag_from(easrt[i + k]);
        f16x2 m[8];
#pragma unroll
        for (int k = 0; k < 8; ++k) {
            f32x2 f = __builtin_amdgcn_cvt_pk_f32_fp8((int)u[k], false);
            f16x2 hv; hv.x = (_Float16)f.x; hv.y = (_Float16)f.y;
            m[k] = bias2 + hv;
        }
#pragma unroll
        for (int kk = 0; kk < F_EDGE; ++kk) {
#pragma unroll
            for (int k = 0; k < 8; ++k)
                m[k] = duph(ev[k], kk) * w2[kk] + m[k];
        }
        f16x2 sm = __builtin_elementwise_max(m[0], zero2);
#pragma unroll
        for (int k = 1; k < 8; ++k) sm = sm + __builtin_elementwise_max(m[k], zero2);
        acc0 += (float)sm.x;
        acc1 += (float)sm.y;
    }
    for (; i < i1; ++i) {
        int s0 = srcarr[i];
        f16x8 e0 = frag_from(easrt[i]);
        f32x2 f = __builtin_amdgcn_cvt_pk_f32_fp8((int)h8[(size_t)s0 * 64 + lane], false);
        f16x2 hv; hv.x = (_Float16)f.x; hv.y = (_Float16)f.y;
        f16x2 m0 = bias2 + hv;
#pragma unroll
        for (int k = 0; k < F_EDGE; ++k)
            m0 = duph(e0, k) * w2[k] + m0;
        m0 = __builtin_elementwise_max(m0, zero2);
        acc0 += (float)m0.x;
        acc1 += (float)m0.y;
    }
    f16x2 self = u2h(hh[(size_t)wave * 64 + lane]);
    aggh[(size_t)wave * 64 + lane] = packh2((float)self.x + acc0, (float)self.y + acc1);
}

// ================= fused 2-layer node MLP via f16 MFMA =================
__device__ __forceinline__ void put_tile_elu_h(unsigned short* t, f32x4 v, int rbase, int c, int stride) {
#pragma unroll
    for (int j = 0; j < 4; ++j)
        t[(rbase + j) * stride + c] = f2h_bits(elu_f(v[j]));
}
__device__ __forceinline__ void put_tile_relu_h(unsigned short* t, f32x4 v, int rbase, int c, int stride) {
#pragma unroll
    for (int j = 0; j < 4; ++j)
        t[(rbase + j) * stride + c] = f2h_bits(fmaxf(v[j], 0.f));
}

template <int K, bool POOL, bool DUP8>
__global__ __launch_bounds__(256) void mlp_mfma_kernel(
    const uint4* __restrict__ inb,
    const uint4* __restrict__ WaP, const float* __restrict__ ba,
    const uint4* __restrict__ WbP, const float* __restrict__ bb,
    uint4* __restrict__ outb, unsigned* __restrict__ out8,
    const int* __restrict__ batch, float* __restrict__ hg,
    int nrows)
{
    constexpr int KS_A = K / 32;
    constexpr int SA = K + 8;
    constexpr int ST = HID + 8;
    constexpr int STF = HID + 4;
    __shared__ __align__(16) unsigned short a_s[32 * SA];
    __shared__ __align__(16) unsigned short t_s[32 * ST];
    __shared__ float p_s[POOL ? 32 * STF : 1];
    __shared__ int batch_s[POOL ? 32 : 1];

    const int tid = threadIdx.x;
    const int row0 = blockIdx.x * 32;

    constexpr int Q = K / 8;
    for (int idx = tid; idx < 32 * Q; idx += 256) {
        int r = idx / Q, q = idx % Q;
        uint4 v = make_uint4(0, 0, 0, 0);
        if (row0 + r < nrows) v = inb[(size_t)(row0 + r) * Q + q];
        *(uint4*)&a_s[r * SA + q * 8] = v;
    }
    if (POOL && tid < 32)
        batch_s[tid] = (row0 + tid < nrows) ? batch[row0 + tid] : -1;
    __syncthreads();

    const int lane = tid & 63;
    const int w = tid >> 6;
    const int rb = w >> 1;
    const int cg = (w & 1) * 4;
    const int cf = lane & 15;
    const int g = lane >> 4;
    const int arow = rb * 16 + cf;

    f32x4 acc0, acc1, acc2, acc3;
    {
        float c0 = ba[(cg + 0) * 16 + cf], c1 = ba[(cg + 1) * 16 + cf];
        float c2 = ba[(cg + 2) * 16 + cf], c3 = ba[(cg + 3) * 16 + cf];
        acc0 = (f32x4){c0, c0, c0, c0};
        acc1 = (f32x4){c1, c1, c1, c1};
        acc2 = (f32x4){c2, c2, c2, c2};
        acc3 = (f32x4){c3, c3, c3, c3};
    }
#pragma unroll
    for (int ks = 0; ks < KS_A; ++ks) {
        f16x8 a = *(const f16x8*)&a_s[arow * SA + ks * 32 + g * 8];
        acc0 = __builtin_amdgcn_mfma_f32_16x16x32_f16(a, frag_from(WaP[((cg + 0) * KS_A + ks) * 64 + lane]), acc0, 0, 0, 0);
        acc1 = __builtin_amdgcn_mfma_f32_16x16x32_f16(a, frag_from(WaP[((cg + 1) * KS_A + ks) * 64 + lane]), acc1, 0, 0, 0);
        acc2 = __builtin_amdgcn_mfma_f32_16x16x32_f16(a, frag_from(WaP[((cg + 2) * KS_A + ks) * 64 + lane]), acc2, 0, 0, 0);
        acc3 = __builtin_amdgcn_mfma_f32_16x16x32_f16(a, frag_from(WaP[((cg + 3) * KS_A + ks) * 64 + lane]), acc3, 0, 0, 0);
    }
    {
        int rbase = rb * 16 + g * 4;
        put_tile_elu_h(t_s, acc0, rbase, (cg + 0) * 16 + cf, ST);
        put_tile_elu_h(t_s, acc1, rbase, (cg + 1) * 16 + cf, ST);
        put_tile_elu_h(t_s, acc2, rbase, (cg + 2) * 16 + cf, ST);
        put_tile_elu_h(t_s, acc3, rbase, (cg + 3) * 16 + cf, ST);
    }
    __syncthreads();

    {
        float c0 = bb[(cg + 0) * 16 + cf], c1 = bb[(cg + 1) * 16 + cf];
        float c2 = bb[(cg + 2) * 16 + cf], c3 = bb[(cg + 3) * 16 + cf];
        acc0 = (f32x4){c0, c0, c0, c0};
        acc1 = (f32x4){c1, c1, c1, c1};
        acc2 = (f32x4){c2, c2, c2, c2};
        acc3 = (f32x4){c3, c3, c3, c3};
    }
#pragma unroll
    for (int ks = 0; ks < 4; ++ks) {
        f16x8 a = *(const f16x8*)&t_s[arow * ST + ks * 32 + g * 8];
        acc0 = __builtin_amdgcn_mfma_f32_16x16x32_f16(a, frag_from(WbP[((cg + 0) * 4 + ks) * 64 + lane]), acc0, 0, 0, 0);
        acc1 = __builtin_amdgcn_mfma_f32_16x16x32_f16(a, frag_from(WbP[((cg + 1) * 4 + ks) * 64 + lane]), acc1, 0, 0, 0);
        acc2 = __builtin_amdgcn_mfma_f32_16x16x32_f16(a, frag_from(WbP[((cg + 2) * 4 + ks) * 64 + lane]), acc2, 0, 0, 0);
        acc3 = __builtin_amdgcn_mfma_f32_16x16x32_f16(a, frag_from(WbP[((cg + 3) * 4 + ks) * 64 + lane]), acc3, 0, 0, 0);
    }

    if (POOL) {
        int rbase = rb * 16 + g * 4;
#pragma unroll
        for (int j = 0; j < 4; ++j) {
            p_s[(rbase + j) * STF + (cg + 0) * 16 + cf] = elu_f(acc0[j]);
            p_s[(rbase + j) * STF + (cg + 1) * 16 + cf] = elu_f(acc1[j]);
            p_s[(rbase + j) * STF + (cg + 2) * 16 + cf] = elu_f(acc2[j]);
            p_s[(rbase + j) * STF + (cg + 3) * 16 + cf] = elu_f(acc3[j]);
        }
        __syncthreads();
        int f = tid & 127, grp = tid >> 7;
        float acc = 0.f;
        int cur = -1;
#pragma unroll 4
        for (int r = 0; r < 16; ++r) {
            int rr = grp * 16 + r;
            int b = batch_s[rr];
            if (b >= 0) {
                if (b != cur) {
                    if (cur >= 0) atomicAdd(&hg[(size_t)cur * HID + f], acc);
                    acc = 0.f;
                    cur = b;
                }
                acc += p_s[rr * STF + f];
            }
        }
        if (cur >= 0) atomicAdd(&hg[(size_t)cur * HID + f], acc);
    } else {
        __syncthreads();
        int rbase = rb * 16 + g * 4;
        put_tile_elu_h(t_s, acc0, rbase, (cg + 0) * 16 + cf, ST);
        put_tile_elu_h(t_s, acc1, rbase, (cg + 1) * 16 + cf, ST);
        put_tile_elu_h(t_s, acc2, rbase, (cg + 2) * 16 + cf, ST);
        put_tile_elu_h(t_s, acc3, rbase, (cg + 3) * 16 + cf, ST);
        __syncthreads();
        for (int idx = tid; idx < 32 * 16; idx += 256) {
            int r = idx >> 4, q = idx & 15;
            if (row0 + r < nrows)
                outb[(size_t)(row0 + r) * 16 + q] = *(const uint4*)&t_s[r * ST + q * 8];
        }
        if (DUP8) {
            for (int idx = tid; idx < 32 * 32; idx += 256) {
                int r = idx >> 5, q = idx & 31;
                if (row0 + r < nrows) {
                    float f0 = hbits2f(t_s[r * ST + q * 4 + 0]);
                    float f1 = hbits2f(t_s[r * ST + q * 4 + 1]);
                    float f2 = hbits2f(t_s[r * ST + q * 4 + 2]);
                    float f3 = hbits2f(t_s[r * ST + q * 4 + 3]);
                    int u = __builtin_amdgcn_cvt_pk_fp8_f32(f0, f1, 0, false);
                    u = __builtin_amdgcn_cvt_pk_fp8_f32(f2, f3, u, true);
                    out8[(size_t)(row0 + r) * 32 + q] = (unsigned)u;
                }
            }
        }
    }
}

// ================= head via MFMA =================
__global__ __launch_bounds__(256) void head_mfma_kernel(
    const float* __restrict__ hg,
    const uint4* __restrict__ Wl1P, const float* __restrict__ bl1,
    const uint4* __restrict__ Wl2P, const float* __restrict__ bl2,
    float* __restrict__ out, int G)
{
    constexpr int ST = HID + 8;
    __shared__ __align__(16) unsigned short a_s[32 * ST];
    __shared__ __align__(16) unsigned short t_s[32 * ST];

    const int tid = threadIdx.x;
    const int row0 = blockIdx.x * 32;

    for (int idx = tid; idx < 32 * HID; idx += 256) {
        int r = idx >> 7, c = idx & 127;
        float v = (row0 + r < G) ? hg[(size_t)(row0 + r) * HID + c] : 0.f;
        a_s[r * ST + c] = f2h_bits(v);
    }
    __syncthreads();

    const int lane = tid & 63;
    const int w = tid >> 6;
    const int rb = w >> 1;
    const int cg = (w & 1) * 4;
    const int cf = lane & 15;
    const int g = lane >> 4;
    const int arow = rb * 16 + cf;

    f32x4 acc0, acc1, acc2, acc3;
    {
        float c0 = bl1[(cg + 0) * 16 + cf], c1 = bl1[(cg + 1) * 16 + cf];
        float c2 = bl1[(cg + 2) * 16 + cf], c3 = bl1[(cg + 3) * 16 + cf];
        acc0 = (f32x4){c0, c0, c0, c0};
        acc1 = (f32x4){c1, c1, c1, c1};
        acc2 = (f32x4){c2, c2, c2, c2};
        acc3 = (f32x4){c3, c3, c3, c3};
    }
#pragma unroll
    for (int ks = 0; ks < 4; ++ks) {
        f16x8 a = *(const f16x8*)&a_s[arow * ST + ks * 32 + g * 8];
        acc0 = __builtin_amdgcn_mfma_f32_16x16x32_f16(a, frag_from(Wl1P[((cg + 0) * 4 + ks) * 64 + lane]), acc0, 0, 0, 0);
        acc1 = __builtin_amdgcn_mfma_f32_16x16x32_f16(a, frag_from(Wl1P[((cg + 1) * 4 + ks) * 64 + lane]), acc1, 0, 0, 0);
        acc2 = __builtin_amdgcn_mfma_f32_16x16x32_f16(a, frag_from(Wl1P[((cg + 2) * 4 + ks) * 64 + lane]), acc2, 0, 0, 0);
        acc3 = __builtin_amdgcn_mfma_f32_16x16x32_f16(a, frag_from(Wl1P[((cg + 3) * 4 + ks) * 64 + lane]), acc3, 0, 0, 0);
    }
    {
        int rbase = rb * 16 + g * 4;
        put_tile_relu_h(t_s, acc0, rbase, (cg + 0) * 16 + cf, ST);
        put_tile_relu_h(t_s, acc1, rbase, (cg + 1) * 16 + cf, ST);
        put_tile_relu_h(t_s, acc2, rbase, (cg + 2) * 16 + cf, ST);
        put_tile_relu_h(t_s, acc3, rbase, (cg + 3) * 16 + cf, ST);
    }
    __syncthreads();

    if ((w & 1) == 0) {
        float c0 = cf < 12 ? bl2[cf] : 0.f;
        f32x4 acc = (f32x4){c0, c0, c0, c0};
#pragma unroll
        for (int ks = 0; ks < 4; ++ks) {
            f16x8 a = *(const f16x8*)&t_s[arow * ST + ks * 32 + g * 8];
            acc = __builtin_amdgcn_mfma_f32_16x16x32_f16(a, frag_from(Wl2P[ks * 64 + lane]), acc, 0, 0, 0);
        }
        if (cf < 12) {
            int rbase = rb * 16 + g * 4;
#pragma unroll
            for (int j = 0; j < 4; ++j) {
                int row = row0 + rbase + j;
                if (row < G) out[(size_t)row * 12 + cf] = acc[j];
            }
        }
    }
}

extern "C" void kernel_launch(void* const* d_in, const int* in_sizes, int n_in,
                              void* d_out, int out_size, void* d_ws, size_t ws_size,
                              hipStream_t stream)
{
    const float* x    = (const float*)d_in[0];
    const int*   ei   = (const int*)d_in[1];
    const float* ea   = (const float*)d_in[2];
    const int*   batch = (const int*)d_in[3];
    const float* We1 = (const float*)d_in[4];
    const float* be1 = (const float*)d_in[5];
    const float* W1a = (const float*)d_in[6];
    const float* b1a = (const float*)d_in[7];
    const float* W1b = (const float*)d_in[8];
    const float* b1b = (const float*)d_in[9];
    const float* We2 = (const float*)d_in[10];
    const float* be2 = (const float*)d_in[11];
    const float* W2a = (const float*)d_in[12];
    const float* b2a = (const float*)d_in[13];
    const float* W2b = (const float*)d_in[14];
    const float* b2b = (const float*)d_in[15];
    const float* Wl1 = (const float*)d_in[16];
    const float* bl1 = (const float*)d_in[17];
    const float* Wl2 = (const float*)d_in[18];
    const float* bl2 = (const float*)d_in[19];
    float* out = (float*)d_out;

    const int N = in_sizes[0] / F_NODE;
    const int E = in_sizes[1] / 2;
    const int G = out_size / 12;
    const int NB = (N + 255) >> 8;

    const int* srcp = ei;
    const int* dstp = ei + E;

    // ---- workspace layout (lifetime-based aliasing) ----
    char* wsb = (char*)d_ws;
    auto alloc = [&](size_t bytes) -> char* {
        char* p = wsb;
        wsb += (bytes + 15) & ~(size_t)15;
        return p;
    };
    int* cbkt      = (int*)alloc(512 * 4);
    int* bucketOff = (int*)alloc(513 * 4);
    int* curB      = (int*)alloc(512 * 4);
    int* off       = (int*)alloc((size_t)(N + 1) * 4);
    int2* tmp      = (int2*)alloc((size_t)E * 8);          // dead after binB -> reused as h8
    unsigned short* h8 = (unsigned short*)tmp;             // N*128 fp8 bytes <= E*8
    int* srcarr    = (int*)alloc((size_t)E * 4);
    uint4* easrt   = (uint4*)alloc((size_t)E * 16);
    unsigned* xh   = (unsigned*)alloc((size_t)N * 16 * 4);
    unsigned* eab  = (unsigned*)alloc((size_t)E * 4 * 4);  // dead after binB -> reused as agg2h
    unsigned* agg2h = eab;
    unsigned* agg1h = (unsigned*)alloc((size_t)N * 16 * 4);
    unsigned* h1h   = (unsigned*)alloc((size_t)N * 64 * 4);
    float* hg  = (float*)alloc((size_t)G * HID * 4);
    uint4* P1a = (uint4*)alloc(512 * 16);
    uint4* P1b = (uint4*)alloc(2048 * 16);
    uint4* P2a = (uint4*)alloc(2048 * 16);
    uint4* P2b = (uint4*)alloc(2048 * 16);
    uint4* P3a = (uint4*)alloc(2048 * 16);
    uint4* P3b = (uint4*)alloc(256 * 16);

    (void)hipMemsetAsync(cbkt, 0, 512 * sizeof(int), stream);
    (void)hipMemsetAsync(hg, 0, (size_t)G * HID * sizeof(float), stream);

    // ---- prep: casts + wpack + coarse hist ----
    hipLaunchKernelGGL(prep_kernel, dim3(2048), dim3(256), 0, stream,
                       x, ea, dstp, (uint4*)xh, (uint4*)eab, W1a, W1b, W2a, W2b, Wl1, Wl2,
                       P1a, P1b, P2a, P2b, P3a, P3b, cbkt, N * 16, E * 4, E, NB);
    hipLaunchKernelGGL(scanB_kernel, dim3(1), dim3(64), 0, stream, cbkt, bucketOff, curB, NB, E);
    hipLaunchKernelGGL(binA_kernel, dim3((E + 4095) / 4096), dim3(256), 0, stream,
                       dstp, srcp, curB, tmp, E, NB);
    hipLaunchKernelGGL(binB_kernel, dim3(NB), dim3(256), 0, stream,
                       tmp, bucketOff, (const uint4*)eab, off, srcarr, easrt, N, E, NB);

    // ---- conv1 ----
    hipLaunchKernelGGL(agg1_kernel, dim3((N + 3) / 4), dim3(256), 0, stream,
                       x, xh, easrt, We1, be1, off, srcarr, agg1h, N);
    hipLaunchKernelGGL((mlp_mfma_kernel<F_NODE, false, true>), dim3((N + 31) / 32), dim3(256), 0, stream,
                       (const uint4*)agg1h, P1a, b1a, P1b, b1b, (uint4*)h1h, (unsigned*)h8,
                       (const int*)nullptr, (float*)nullptr, N);

    // ---- conv2 ----
    hipLaunchKernelGGL(agg2_kernel, dim3((N + 3) / 4), dim3(256), 0, stream,
                       h1h, h8, easrt, We2, be2, off, srcarr, agg2h, N);
    hipLaunchKernelGGL((mlp_mfma_kernel<HID, true, false>), dim3((N + 31) / 32), dim3(256), 0, stream,
                       (const uint4*)agg2h, P2a, b2a, P2b, b2b, (uint4*)nullptr, (unsigned*)nullptr,
                       batch, hg, N);

    // ---- head (MFMA) ----
    hipLaunchKernelGGL(head_mfma_kernel, dim3((G + 31) / 32), dim3(256), 0, stream,
                       hg, P3a, bl1, P3b, bl2, out, G);
}

// Round 14
// 340.400 us; speedup vs baseline: 5.1557x; 1.0565x over previous
//
#include <hip/hip_runtime.h>
#include <math.h>

#define F_NODE 32
#define F_EDGE 8
#define HID 128

typedef __attribute__((ext_vector_type(2))) _Float16 f16x2;
typedef __attribute__((ext_vector_type(8))) _Float16 f16x8;
typedef __attribute__((ext_vector_type(4))) float f32x4;
typedef __attribute__((ext_vector_type(2))) float f32x2;

__device__ __forceinline__ float elu_f(float x) { return x > 0.f ? x : expf(x) - 1.f; }

__device__ __forceinline__ unsigned h2u(f16x2 h) { union { f16x2 h; unsigned u; } x; x.h = h; return x.u; }
__device__ __forceinline__ f16x2 u2h(unsigned u) { union { unsigned u; f16x2 h; } x; x.u = u; return x.h; }
__device__ __forceinline__ unsigned packh2(float lo, float hi) {
    f16x2 v; v.x = (_Float16)lo; v.y = (_Float16)hi; return h2u(v);
}
__device__ __forceinline__ unsigned short f2h_bits(float f) {
    _Float16 h = (_Float16)f; union { _Float16 h; unsigned short u; } x; x.h = h; return x.u;
}
__device__ __forceinline__ float hbits2f(unsigned short b) {
    union { unsigned short u; _Float16 h; } x; x.u = b; return (float)x.h;
}
__device__ __forceinline__ f16x8 frag_from(uint4 v) { union { uint4 u; f16x8 f; } x; x.u = v; return x.f; }
__device__ __forceinline__ f16x2 duph(f16x8 v, int k) { f16x2 d; d.x = v[k]; d.y = v[k]; return d; }

// ================= fused prep (grid-stride): casts + wpack + COARSE hist =================
__global__ __launch_bounds__(256) void prep_kernel(
    const float* __restrict__ x, const float* __restrict__ ea,
    const int* __restrict__ dst,
    uint4* __restrict__ xh4, uint4* __restrict__ eab4,
    const float* __restrict__ W1a, const float* __restrict__ W1b,
    const float* __restrict__ W2a, const float* __restrict__ W2b,
    const float* __restrict__ Wl1, const float* __restrict__ Wl2,
    uint4* __restrict__ P1a, uint4* __restrict__ P1b,
    uint4* __restrict__ P2a, uint4* __restrict__ P2b,
    uint4* __restrict__ P3a, uint4* __restrict__ P3b,
    int* __restrict__ cbkt, int nx, int ne2, int E, int NB)
{
    const int stride = gridDim.x * 256;
    const int tid = blockIdx.x * 256 + threadIdx.x;
    const float4* x4 = (const float4*)x;
    const float4* ea4 = (const float4*)ea;

    __shared__ int chist[512];
    for (int i = threadIdx.x; i < 512; i += 256) chist[i] = 0;
    __syncthreads();

    // A: x -> f16 pairs (1 uint4 per iter)
    int nx4 = nx >> 2;
    for (int i = tid; i < nx4; i += stride) {
        float4 a = x4[i * 2], b = x4[i * 2 + 1];
        uint4 v;
        v.x = packh2(a.x, a.y);
        v.y = packh2(a.z, a.w);
        v.z = packh2(b.x, b.y);
        v.w = packh2(b.z, b.w);
        xh4[i] = v;
    }
    // B: ea -> f16 pairs
    int ne8 = ne2 >> 2;
    for (int i = tid; i < ne8; i += stride) {
        float4 a = ea4[i * 2], b = ea4[i * 2 + 1];
        uint4 v;
        v.x = packh2(a.x, a.y);
        v.y = packh2(a.z, a.w);
        v.z = packh2(b.x, b.y);
        v.w = packh2(b.z, b.w);
        eab4[i] = v;
    }
    // C: weight pack (f16 B-fragments)
    for (int f0 = tid; f0 < 8960; f0 += stride) {
        int f = f0;
        if (f >= 8704) {               // P3b: Wl2 [128][12] -> 16 cols padded
            f -= 8704;
            int lane = f & 63;
            int ks = f >> 6;
            int col = lane & 15;
            int k0 = ks * 32 + (lane >> 4) * 8;
            float w[8];
#pragma unroll
            for (int j = 0; j < 8; ++j) w[j] = col < 12 ? Wl2[(size_t)(k0 + j) * 12 + col] : 0.f;
            uint4 v;
            v.x = packh2(w[0], w[1]);
            v.y = packh2(w[2], w[3]);
            v.z = packh2(w[4], w[5]);
            v.w = packh2(w[6], w[7]);
            P3b[f] = v;
            continue;
        }
        const float* W; uint4* P; int KS;
        if (f < 512)       { W = W1a; P = P1a; KS = 1; }
        else if (f < 2560) { W = W1b; P = P1b; KS = 4; f -= 512; }
        else if (f < 4608) { W = W2a; P = P2a; KS = 4; f -= 2560; }
        else if (f < 6656) { W = W2b; P = P2b; KS = 4; f -= 4608; }
        else               { W = Wl1; P = P3a; KS = 4; f -= 6656; }
        int lane = f & 63;
        int rem = f >> 6;
        int ks = rem % KS, ct = rem / KS;
        int col = ct * 16 + (lane & 15);
        int k0 = ks * 32 + (lane >> 4) * 8;
        float w[8];
#pragma unroll
        for (int j = 0; j < 8; ++j) w[j] = W[(size_t)(k0 + j) * HID + col];
        uint4 v;
        v.x = packh2(w[0], w[1]);
        v.y = packh2(w[2], w[3]);
        v.z = packh2(w[4], w[5]);
        v.w = packh2(w[6], w[7]);
        P[f] = v;
    }
    // D: coarse dst histogram (LDS-aggregated)
    int e4 = E >> 2;
    const int4* dst4 = (const int4*)dst;
    for (int i = tid; i < e4; i += stride) {
        int4 d = dst4[i];
        atomicAdd(&chist[d.x >> 8], 1);
        atomicAdd(&chist[d.y >> 8], 1);
        atomicAdd(&chist[d.z >> 8], 1);
        atomicAdd(&chist[d.w >> 8], 1);
    }
    for (int i = e4 * 4 + tid; i < E; i += stride)
        atomicAdd(&chist[dst[i] >> 8], 1);
    __syncthreads();
    for (int i = threadIdx.x; i < NB; i += 256) {
        int c = chist[i];
        if (c) atomicAdd(&cbkt[i], c);
    }
}

// ================= coarse bucket prefix (1 block, parallel scan) =================
__global__ __launch_bounds__(256) void scanB_kernel(const int* __restrict__ cbkt,
                             int* __restrict__ bucketOff, int* __restrict__ curB,
                             int NB, int E) {
    __shared__ int s[256];
    int t = threadIdx.x;
    int v0 = (2 * t     < NB) ? cbkt[2 * t]     : 0;
    int v1 = (2 * t + 1 < NB) ? cbkt[2 * t + 1] : 0;
    int tot = v0 + v1;
    s[t] = tot;
    __syncthreads();
    for (int o = 1; o < 256; o <<= 1) {
        int val = (t >= o) ? s[t - o] : 0;
        __syncthreads();
        s[t] += val;
        __syncthreads();
    }
    int excl = s[t] - tot;
    if (2 * t < NB)     { bucketOff[2 * t] = excl;          curB[2 * t] = excl; }
    if (2 * t + 1 < NB) { bucketOff[2 * t + 1] = excl + v0; curB[2 * t + 1] = excl + v0; }
    if (t == 0) bucketOff[NB] = E;
}

// ================= pass A: coarse bin into 256-node buckets =================
__global__ __launch_bounds__(256) void binA_kernel(
    const int* __restrict__ dst, const int* __restrict__ src,
    int* __restrict__ curB, int2* __restrict__ tmp, int E, int NB)
{
    __shared__ int hist[512];
    __shared__ int basev[512];
    const int tid = threadIdx.x;
    const int base = blockIdx.x * 4096;
    for (int i = tid; i < NB; i += 256) hist[i] = 0;
    __syncthreads();
    int d[16];
#pragma unroll
    for (int k = 0; k < 16; ++k) {
        int e = base + k * 256 + tid;
        d[k] = (e < E) ? dst[e] : -1;
        if (d[k] >= 0) atomicAdd(&hist[d[k] >> 8], 1);
    }
    __syncthreads();
    for (int i = tid; i < NB; i += 256) {
        int c = hist[i];
        basev[i] = c > 0 ? atomicAdd(&curB[i], c) : 0;
        hist[i] = 0;
    }
    __syncthreads();
#pragma unroll
    for (int k = 0; k < 16; ++k) {
        int e = base + k * 256 + tid;
        if (d[k] >= 0) {
            int b = d[k] >> 8;
            int r = atomicAdd(&hist[b], 1);
            tmp[basev[b] + r] = make_int2(e | ((d[k] & 255) << 22), src[e]);
        }
    }
}

// ================= pass B: per-node offsets in LDS + scatter + write off[] =====
__global__ __launch_bounds__(256) void binB_kernel(
    const int2* __restrict__ tmp, const int* __restrict__ bucketOff,
    const uint4* __restrict__ eab4,
    int* __restrict__ off, int* __restrict__ srcarr, uint4* __restrict__ easrt,
    int N, int E, int NB)
{
    __shared__ int hist[256];
    __shared__ int ss[256];
    const int b = blockIdx.x;
    const int tid = threadIdx.x;
    const int node0 = b << 8;
    const int base = bucketOff[b];
    const int end = bucketOff[b + 1];
    const int S = end - base;

    hist[tid] = 0;
    __syncthreads();
    for (int j = tid; j < S; j += 256) {
        int2 rec = tmp[base + j];
        atomicAdd(&hist[((unsigned)rec.x) >> 22], 1);
    }
    __syncthreads();
    int v = hist[tid];
    ss[tid] = v;
    __syncthreads();
    for (int o = 1; o < 256; o <<= 1) {
        int val = (tid >= o) ? ss[tid - o] : 0;
        __syncthreads();
        ss[tid] += val;
        __syncthreads();
    }
    int excl = ss[tid] - v;
    int node = node0 + tid;
    if (node < N) off[node] = base + excl;
    if (b == NB - 1 && tid == 0) off[N] = E;
    hist[tid] = excl;     // reuse as cursor
    __syncthreads();
    for (int j = tid; j < S; j += 256) {
        int2 rec = tmp[base + j];
        int dloc = ((unsigned)rec.x) >> 22;
        int slot = base + atomicAdd(&hist[dloc], 1);
        srcarr[slot] = rec.y;
        easrt[slot] = eab4[rec.x & 0x3FFFFF];   // one-time random ea gather
    }
}

// ================= conv1 gather-aggregate (f16 gathers, sequential ea) =================
__global__ __launch_bounds__(256) void agg1_kernel(
    const float* __restrict__ x, const unsigned* __restrict__ xh,
    const uint4* __restrict__ easrt,
    const float* __restrict__ We, const float* __restrict__ be,
    const int* __restrict__ off, const int* __restrict__ srcarr,
    unsigned* __restrict__ aggh, int N)
{
    int wave = (blockIdx.x * 256 + threadIdx.x) >> 6;
    if (wave >= N) return;
    int lane = threadIdx.x & 63;
    int fp = lane & 15, eg = lane >> 4;
    int j0 = fp * 2;
    f16x2 w2[F_EDGE];
#pragma unroll
    for (int k = 0; k < F_EDGE; ++k)
        w2[k] = u2h(packh2(We[k * F_NODE + j0], We[k * F_NODE + j0 + 1]));
    f16x2 bias2 = u2h(packh2(be[j0], be[j0 + 1]));
    f16x2 zero2 = u2h(0u);
    int i0 = __builtin_amdgcn_readfirstlane(off[wave]);
    int i1 = __builtin_amdgcn_readfirstlane(off[wave + 1]);
    float acc0 = 0.f, acc1 = 0.f;
    for (int i = i0; i < i1; i += 4) {
        int ii = i + eg;
        if (ii < i1) {
            int s = srcarr[ii];
            f16x8 ev = frag_from(easrt[ii]);
            f16x2 m = bias2 + u2h(xh[(size_t)s * 16 + fp]);
#pragma unroll
            for (int k = 0; k < F_EDGE; ++k)
                m = duph(ev, k) * w2[k] + m;
            m = __builtin_elementwise_max(m, zero2);
            acc0 += (float)m.x;
            acc1 += (float)m.y;
        }
    }
    acc0 += __shfl_xor(acc0, 16, 64);
    acc0 += __shfl_xor(acc0, 32, 64);
    acc1 += __shfl_xor(acc1, 16, 64);
    acc1 += __shfl_xor(acc1, 32, 64);
    if (eg == 0) {
        float2 xo = *(const float2*)&x[(size_t)wave * F_NODE + j0];
        aggh[(size_t)wave * 16 + fp] = packh2(xo.x + acc0, xo.y + acc1);
    }
}

// ================= conv2 gather-aggregate (fp8 gathers, unroll 8) =================
__global__ __launch_bounds__(256) void agg2_kernel(
    const unsigned* __restrict__ hh, const unsigned short* __restrict__ h8,
    const uint4* __restrict__ easrt,
    const float* __restrict__ We, const float* __restrict__ be,
    const int* __restrict__ off, const int* __restrict__ srcarr,
    unsigned* __restrict__ aggh, int N)
{
    int wave = (blockIdx.x * 256 + threadIdx.x) >> 6;
    if (wave >= N) return;
    int lane = threadIdx.x & 63;
    int j0 = lane * 2;
    f16x2 w2[F_EDGE];
#pragma unroll
    for (int k = 0; k < F_EDGE; ++k)
        w2[k] = u2h(packh2(We[k * HID + j0], We[k * HID + j0 + 1]));
    f16x2 bias2 = u2h(packh2(be[j0], be[j0 + 1]));
    f16x2 zero2 = u2h(0u);
    int i0 = __builtin_amdgcn_readfirstlane(off[wave]);
    int i1 = __builtin_amdgcn_readfirstlane(off[wave + 1]);
    float acc0 = 0.f, acc1 = 0.f;
    int i = i0;
    for (; i + 7 < i1; i += 8) {
        int s[8];
        unsigned short u[8];
        f16x8 ev[8];
#pragma unroll
        for (int k = 0; k < 8; ++k) s[k] = srcarr[i + k];
#pragma unroll
        for (int k = 0; k < 8; ++k) u[k] = h8[(size_t)s[k] * 64 + lane];
#pragma unroll
        for (int k = 0; k < 8; ++k) ev[k] = frag_from(easrt[i + k]);
        f16x2 m[8];
#pragma unroll
        for (int k = 0; k < 8; ++k) {
            f32x2 f = __builtin_amdgcn_cvt_pk_f32_fp8((int)u[k], false);
            f16x2 hv; hv.x = (_Float16)f.x; hv.y = (_Float16)f.y;
            m[k] = bias2 + hv;
        }
#pragma unroll
        for (int kk = 0; kk < F_EDGE; ++kk) {
#pragma unroll
            for (int k = 0; k < 8; ++k)
                m[k] = duph(ev[k], kk) * w2[kk] + m[k];
        }
        f16x2 sm = __builtin_elementwise_max(m[0], zero2);
#pragma unroll
        for (int k = 1; k < 8; ++k) sm = sm + __builtin_elementwise_max(m[k], zero2);
        acc0 += (float)sm.x;
        acc1 += (float)sm.y;
    }
    for (; i < i1; ++i) {
        int s0 = srcarr[i];
        f16x8 e0 = frag_from(easrt[i]);
        f32x2 f = __builtin_amdgcn_cvt_pk_f32_fp8((int)h8[(size_t)s0 * 64 + lane], false);
        f16x2 hv; hv.x = (_Float16)f.x; hv.y = (_Float16)f.y;
        f16x2 m0 = bias2 + hv;
#pragma unroll
        for (int k = 0; k < F_EDGE; ++k)
            m0 = duph(e0, k) * w2[k] + m0;
        m0 = __builtin_elementwise_max(m0, zero2);
        acc0 += (float)m0.x;
        acc1 += (float)m0.y;
    }
    f16x2 self = u2h(hh[(size_t)wave * 64 + lane]);
    aggh[(size_t)wave * 64 + lane] = packh2((float)self.x + acc0, (float)self.y + acc1);
}

// ================= fused 2-layer node MLP via f16 MFMA =================
__device__ __forceinline__ void put_tile_elu_h(unsigned short* t, f32x4 v, int rbase, int c, int stride) {
#pragma unroll
    for (int j = 0; j < 4; ++j)
        t[(rbase + j) * stride + c] = f2h_bits(elu_f(v[j]));
}
__device__ __forceinline__ void put_tile_relu_h(unsigned short* t, f32x4 v, int rbase, int c, int stride) {
#pragma unroll
    for (int j = 0; j < 4; ++j)
        t[(rbase + j) * stride + c] = f2h_bits(fmaxf(v[j], 0.f));
}

template <int K, bool POOL, bool DUP8>
__global__ __launch_bounds__(256) void mlp_mfma_kernel(
    const uint4* __restrict__ inb,
    const uint4* __restrict__ WaP, const float* __restrict__ ba,
    const uint4* __restrict__ WbP, const float* __restrict__ bb,
    uint4* __restrict__ outb, unsigned* __restrict__ out8,
    const int* __restrict__ batch, float* __restrict__ hg,
    int nrows)
{
    constexpr int KS_A = K / 32;
    constexpr int SA = K + 8;
    constexpr int ST = HID + 8;
    constexpr int STF = HID + 4;
    __shared__ __align__(16) unsigned short a_s[32 * SA];
    __shared__ __align__(16) unsigned short t_s[32 * ST];
    __shared__ float p_s[POOL ? 32 * STF : 1];
    __shared__ int batch_s[POOL ? 32 : 1];

    const int tid = threadIdx.x;
    const int row0 = blockIdx.x * 32;

    constexpr int Q = K / 8;
    for (int idx = tid; idx < 32 * Q; idx += 256) {
        int r = idx / Q, q = idx % Q;
        uint4 v = make_uint4(0, 0, 0, 0);
        if (row0 + r < nrows) v = inb[(size_t)(row0 + r) * Q + q];
        *(uint4*)&a_s[r * SA + q * 8] = v;
    }
    if (POOL && tid < 32)
        batch_s[tid] = (row0 + tid < nrows) ? batch[row0 + tid] : -1;
    __syncthreads();

    const int lane = tid & 63;
    const int w = tid >> 6;
    const int rb = w >> 1;
    const int cg = (w & 1) * 4;
    const int cf = lane & 15;
    const int g = lane >> 4;
    const int arow = rb * 16 + cf;

    f32x4 acc0, acc1, acc2, acc3;
    {
        float c0 = ba[(cg + 0) * 16 + cf], c1 = ba[(cg + 1) * 16 + cf];
        float c2 = ba[(cg + 2) * 16 + cf], c3 = ba[(cg + 3) * 16 + cf];
        acc0 = (f32x4){c0, c0, c0, c0};
        acc1 = (f32x4){c1, c1, c1, c1};
        acc2 = (f32x4){c2, c2, c2, c2};
        acc3 = (f32x4){c3, c3, c3, c3};
    }
#pragma unroll
    for (int ks = 0; ks < KS_A; ++ks) {
        f16x8 a = *(const f16x8*)&a_s[arow * SA + ks * 32 + g * 8];
        acc0 = __builtin_amdgcn_mfma_f32_16x16x32_f16(a, frag_from(WaP[((cg + 0) * KS_A + ks) * 64 + lane]), acc0, 0, 0, 0);
        acc1 = __builtin_amdgcn_mfma_f32_16x16x32_f16(a, frag_from(WaP[((cg + 1) * KS_A + ks) * 64 + lane]), acc1, 0, 0, 0);
        acc2 = __builtin_amdgcn_mfma_f32_16x16x32_f16(a, frag_from(WaP[((cg + 2) * KS_A + ks) * 64 + lane]), acc2, 0, 0, 0);
        acc3 = __builtin_amdgcn_mfma_f32_16x16x32_f16(a, frag_from(WaP[((cg + 3) * KS_A + ks) * 64 + lane]), acc3, 0, 0, 0);
    }
    {
        int rbase = rb * 16 + g * 4;
        put_tile_elu_h(t_s, acc0, rbase, (cg + 0) * 16 + cf, ST);
        put_tile_elu_h(t_s, acc1, rbase, (cg + 1) * 16 + cf, ST);
        put_tile_elu_h(t_s, acc2, rbase, (cg + 2) * 16 + cf, ST);
        put_tile_elu_h(t_s, acc3, rbase, (cg + 3) * 16 + cf, ST);
    }
    __syncthreads();

    {
        float c0 = bb[(cg + 0) * 16 + cf], c1 = bb[(cg + 1) * 16 + cf];
        float c2 = bb[(cg + 2) * 16 + cf], c3 = bb[(cg + 3) * 16 + cf];
        acc0 = (f32x4){c0, c0, c0, c0};
        acc1 = (f32x4){c1, c1, c1, c1};
        acc2 = (f32x4){c2, c2, c2, c2};
        acc3 = (f32x4){c3, c3, c3, c3};
    }
#pragma unroll
    for (int ks = 0; ks < 4; ++ks) {
        f16x8 a = *(const f16x8*)&t_s[arow * ST + ks * 32 + g * 8];
        acc0 = __builtin_amdgcn_mfma_f32_16x16x32_f16(a, frag_from(WbP[((cg + 0) * 4 + ks) * 64 + lane]), acc0, 0, 0, 0);
        acc1 = __builtin_amdgcn_mfma_f32_16x16x32_f16(a, frag_from(WbP[((cg + 1) * 4 + ks) * 64 + lane]), acc1, 0, 0, 0);
        acc2 = __builtin_amdgcn_mfma_f32_16x16x32_f16(a, frag_from(WbP[((cg + 2) * 4 + ks) * 64 + lane]), acc2, 0, 0, 0);
        acc3 = __builtin_amdgcn_mfma_f32_16x16x32_f16(a, frag_from(WbP[((cg + 3) * 4 + ks) * 64 + lane]), acc3, 0, 0, 0);
    }

    if (POOL) {
        int rbase = rb * 16 + g * 4;
#pragma unroll
        for (int j = 0; j < 4; ++j) {
            p_s[(rbase + j) * STF + (cg + 0) * 16 + cf] = elu_f(acc0[j]);
            p_s[(rbase + j) * STF + (cg + 1) * 16 + cf] = elu_f(acc1[j]);
            p_s[(rbase + j) * STF + (cg + 2) * 16 + cf] = elu_f(acc2[j]);
            p_s[(rbase + j) * STF + (cg + 3) * 16 + cf] = elu_f(acc3[j]);
        }
        __syncthreads();
        int f = tid & 127, grp = tid >> 7;
        float acc = 0.f;
        int cur = -1;
#pragma unroll 4
        for (int r = 0; r < 16; ++r) {
            int rr = grp * 16 + r;
            int b = batch_s[rr];
            if (b >= 0) {
                if (b != cur) {
                    if (cur >= 0) atomicAdd(&hg[(size_t)cur * HID + f], acc);
                    acc = 0.f;
                    cur = b;
                }
                acc += p_s[rr * STF + f];
            }
        }
        if (cur >= 0) atomicAdd(&hg[(size_t)cur * HID + f], acc);
    } else {
        __syncthreads();
        int rbase = rb * 16 + g * 4;
        put_tile_elu_h(t_s, acc0, rbase, (cg + 0) * 16 + cf, ST);
        put_tile_elu_h(t_s, acc1, rbase, (cg + 1) * 16 + cf, ST);
        put_tile_elu_h(t_s, acc2, rbase, (cg + 2) * 16 + cf, ST);
        put_tile_elu_h(t_s, acc3, rbase, (cg + 3) * 16 + cf, ST);
        __syncthreads();
        for (int idx = tid; idx < 32 * 16; idx += 256) {
            int r = idx >> 4, q = idx & 15;
            if (row0 + r < nrows)
                outb[(size_t)(row0 + r) * 16 + q] = *(const uint4*)&t_s[r * ST + q * 8];
        }
        if (DUP8) {
            for (int idx = tid; idx < 32 * 32; idx += 256) {
                int r = idx >> 5, q = idx & 31;
                if (row0 + r < nrows) {
                    float f0 = hbits2f(t_s[r * ST + q * 4 + 0]);
                    float f1 = hbits2f(t_s[r * ST + q * 4 + 1]);
                    float f2 = hbits2f(t_s[r * ST + q * 4 + 2]);
                    float f3 = hbits2f(t_s[r * ST + q * 4 + 3]);
                    int u = __builtin_amdgcn_cvt_pk_fp8_f32(f0, f1, 0, false);
                    u = __builtin_amdgcn_cvt_pk_fp8_f32(f2, f3, u, true);
                    out8[(size_t)(row0 + r) * 32 + q] = (unsigned)u;
                }
            }
        }
    }
}

// ================= head via MFMA =================
__global__ __launch_bounds__(256) void head_mfma_kernel(
    const float* __restrict__ hg,
    const uint4* __restrict__ Wl1P, const float* __restrict__ bl1,
    const uint4* __restrict__ Wl2P, const float* __restrict__ bl2,
    float* __restrict__ out, int G)
{
    constexpr int ST = HID + 8;
    __shared__ __align__(16) unsigned short a_s[32 * ST];
    __shared__ __align__(16) unsigned short t_s[32 * ST];

    const int tid = threadIdx.x;
    const int row0 = blockIdx.x * 32;

    for (int idx = tid; idx < 32 * HID; idx += 256) {
        int r = idx >> 7, c = idx & 127;
        float v = (row0 + r < G) ? hg[(size_t)(row0 + r) * HID + c] : 0.f;
        a_s[r * ST + c] = f2h_bits(v);
    }
    __syncthreads();

    const int lane = tid & 63;
    const int w = tid >> 6;
    const int rb = w >> 1;
    const int cg = (w & 1) * 4;
    const int cf = lane & 15;
    const int g = lane >> 4;
    const int arow = rb * 16 + cf;

    f32x4 acc0, acc1, acc2, acc3;
    {
        float c0 = bl1[(cg + 0) * 16 + cf], c1 = bl1[(cg + 1) * 16 + cf];
        float c2 = bl1[(cg + 2) * 16 + cf], c3 = bl1[(cg + 3) * 16 + cf];
        acc0 = (f32x4){c0, c0, c0, c0};
        acc1 = (f32x4){c1, c1, c1, c1};
        acc2 = (f32x4){c2, c2, c2, c2};
        acc3 = (f32x4){c3, c3, c3, c3};
    }
#pragma unroll
    for (int ks = 0; ks < 4; ++ks) {
        f16x8 a = *(const f16x8*)&a_s[arow * ST + ks * 32 + g * 8];
        acc0 = __builtin_amdgcn_mfma_f32_16x16x32_f16(a, frag_from(Wl1P[((cg + 0) * 4 + ks) * 64 + lane]), acc0, 0, 0, 0);
        acc1 = __builtin_amdgcn_mfma_f32_16x16x32_f16(a, frag_from(Wl1P[((cg + 1) * 4 + ks) * 64 + lane]), acc1, 0, 0, 0);
        acc2 = __builtin_amdgcn_mfma_f32_16x16x32_f16(a, frag_from(Wl1P[((cg + 2) * 4 + ks) * 64 + lane]), acc2, 0, 0, 0);
        acc3 = __builtin_amdgcn_mfma_f32_16x16x32_f16(a, frag_from(Wl1P[((cg + 3) * 4 + ks) * 64 + lane]), acc3, 0, 0, 0);
    }
    {
        int rbase = rb * 16 + g * 4;
        put_tile_relu_h(t_s, acc0, rbase, (cg + 0) * 16 + cf, ST);
        put_tile_relu_h(t_s, acc1, rbase, (cg + 1) * 16 + cf, ST);
        put_tile_relu_h(t_s, acc2, rbase, (cg + 2) * 16 + cf, ST);
        put_tile_relu_h(t_s, acc3, rbase, (cg + 3) * 16 + cf, ST);
    }
    __syncthreads();

    if ((w & 1) == 0) {
        float c0 = cf < 12 ? bl2[cf] : 0.f;
        f32x4 acc = (f32x4){c0, c0, c0, c0};
#pragma unroll
        for (int ks = 0; ks < 4; ++ks) {
            f16x8 a = *(const f16x8*)&t_s[arow * ST + ks * 32 + g * 8];
            acc = __builtin_amdgcn_mfma_f32_16x16x32_f16(a, frag_from(Wl2P[ks * 64 + lane]), acc, 0, 0, 0);
        }
        if (cf < 12) {
            int rbase = rb * 16 + g * 4;
#pragma unroll
            for (int j = 0; j < 4; ++j) {
                int row = row0 + rbase + j;
                if (row < G) out[(size_t)row * 12 + cf] = acc[j];
            }
        }
    }
}

extern "C" void kernel_launch(void* const* d_in, const int* in_sizes, int n_in,
                              void* d_out, int out_size, void* d_ws, size_t ws_size,
                              hipStream_t stream)
{
    const float* x    = (const float*)d_in[0];
    const int*   ei   = (const int*)d_in[1];
    const float* ea   = (const float*)d_in[2];
    const int*   batch = (const int*)d_in[3];
    const float* We1 = (const float*)d_in[4];
    const float* be1 = (const float*)d_in[5];
    const float* W1a = (const float*)d_in[6];
    const float* b1a = (const float*)d_in[7];
    const float* W1b = (const float*)d_in[8];
    const float* b1b = (const float*)d_in[9];
    const float* We2 = (const float*)d_in[10];
    const float* be2 = (const float*)d_in[11];
    const float* W2a = (const float*)d_in[12];
    const float* b2a = (const float*)d_in[13];
    const float* W2b = (const float*)d_in[14];
    const float* b2b = (const float*)d_in[15];
    const float* Wl1 = (const float*)d_in[16];
    const float* bl1 = (const float*)d_in[17];
    const float* Wl2 = (const float*)d_in[18];
    const float* bl2 = (const float*)d_in[19];
    float* out = (float*)d_out;

    const int N = in_sizes[0] / F_NODE;
    const int E = in_sizes[1] / 2;
    const int G = out_size / 12;
    const int NB = (N + 255) >> 8;

    const int* srcp = ei;
    const int* dstp = ei + E;

    // ---- workspace layout (lifetime-based aliasing) ----
    char* wsb = (char*)d_ws;
    auto alloc = [&](size_t bytes) -> char* {
        char* p = wsb;
        wsb += (bytes + 15) & ~(size_t)15;
        return p;
    };
    int* cbkt      = (int*)alloc(512 * 4);
    int* bucketOff = (int*)alloc(513 * 4);
    int* curB      = (int*)alloc(512 * 4);
    int* off       = (int*)alloc((size_t)(N + 1) * 4);
    int2* tmp      = (int2*)alloc((size_t)E * 8);          // dead after binB -> reused as h8
    unsigned short* h8 = (unsigned short*)tmp;             // N*128 fp8 bytes <= E*8
    int* srcarr    = (int*)alloc((size_t)E * 4);
    uint4* easrt   = (uint4*)alloc((size_t)E * 16);
    unsigned* xh   = (unsigned*)alloc((size_t)N * 16 * 4);
    unsigned* eab  = (unsigned*)alloc((size_t)E * 4 * 4);  // dead after binB -> reused as agg2h
    unsigned* agg2h = eab;
    unsigned* agg1h = (unsigned*)alloc((size_t)N * 16 * 4);
    unsigned* h1h   = (unsigned*)alloc((size_t)N * 64 * 4);
    float* hg  = (float*)alloc((size_t)G * HID * 4);
    uint4* P1a = (uint4*)alloc(512 * 16);
    uint4* P1b = (uint4*)alloc(2048 * 16);
    uint4* P2a = (uint4*)alloc(2048 * 16);
    uint4* P2b = (uint4*)alloc(2048 * 16);
    uint4* P3a = (uint4*)alloc(2048 * 16);
    uint4* P3b = (uint4*)alloc(256 * 16);

    (void)hipMemsetAsync(cbkt, 0, 512 * sizeof(int), stream);
    (void)hipMemsetAsync(hg, 0, (size_t)G * HID * sizeof(float), stream);

    // ---- prep: casts + wpack + coarse hist ----
    hipLaunchKernelGGL(prep_kernel, dim3(2048), dim3(256), 0, stream,
                       x, ea, dstp, (uint4*)xh, (uint4*)eab, W1a, W1b, W2a, W2b, Wl1, Wl2,
                       P1a, P1b, P2a, P2b, P3a, P3b, cbkt, N * 16, E * 4, E, NB);
    hipLaunchKernelGGL(scanB_kernel, dim3(1), dim3(256), 0, stream, cbkt, bucketOff, curB, NB, E);
    hipLaunchKernelGGL(binA_kernel, dim3((E + 4095) / 4096), dim3(256), 0, stream,
                       dstp, srcp, curB, tmp, E, NB);
    hipLaunchKernelGGL(binB_kernel, dim3(NB), dim3(256), 0, stream,
                       tmp, bucketOff, (const uint4*)eab, off, srcarr, easrt, N, E, NB);

    // ---- conv1 ----
    hipLaunchKernelGGL(agg1_kernel, dim3((N + 3) / 4), dim3(256), 0, stream,
                       x, xh, easrt, We1, be1, off, srcarr, agg1h, N);
    hipLaunchKernelGGL((mlp_mfma_kernel<F_NODE, false, true>), dim3((N + 31) / 32), dim3(256), 0, stream,
                       (const uint4*)agg1h, P1a, b1a, P1b, b1b, (uint4*)h1h, (unsigned*)h8,
                       (const int*)nullptr, (float*)nullptr, N);

    // ---- conv2 ----
    hipLaunchKernelGGL(agg2_kernel, dim3((N + 3) / 4), dim3(256), 0, stream,
                       h1h, h8, easrt, We2, be2, off, srcarr, agg2h, N);
    hipLaunchKernelGGL((mlp_mfma_kernel<HID, true, false>), dim3((N + 31) / 32), dim3(256), 0, stream,
                       (const uint4*)agg2h, P2a, b2a, P2b, b2b, (uint4*)nullptr, (unsigned*)nullptr,
                       batch, hg, N);

    // ---- head (MFMA) ----
    hipLaunchKernelGGL(head_mfma_kernel, dim3((G + 31) / 32), dim3(256), 0, stream,
                       hg, P3a, bl1, P3b, bl2, out, G);
}